// Round 1
// baseline (1224.713 us; speedup 1.0000x reference)
//
#include <hip/hip_runtime.h>
#include <math.h>

// Problem constants (also derived from in_sizes at launch).
static constexpr int HID = 64;

// ---------------------------------------------------------------------------
// int64-vs-int32 edge_index detection: OR of odd words of the first 8192
// elements. int64 (little-endian) => hi words all zero => flag==0.
__global__ void k_flag(const unsigned int* __restrict__ w, int nSample,
                       unsigned int* __restrict__ flag) {
  __shared__ unsigned int red[256];
  unsigned int v = 0;
  for (int i = threadIdx.x; i < nSample; i += 256) v |= w[2 * i + 1];
  red[threadIdx.x] = v;
  __syncthreads();
  for (int s = 128; s > 0; s >>= 1) {
    if (threadIdx.x < s) red[threadIdx.x] |= red[threadIdx.x + s];
    __syncthreads();
  }
  if (threadIdx.x == 0) flag[0] = red[0];  // nonzero => int32 layout
}

// Decode edge_index into int32 src/tgt and accumulate in-degree (float).
__global__ void k_decode(const unsigned int* __restrict__ w,
                         const unsigned int* __restrict__ flag, int E,
                         int* __restrict__ src, int* __restrict__ tgt,
                         float* __restrict__ cnt) {
  int e = blockIdx.x * 256 + threadIdx.x;
  if (e >= E) return;
  int s, t;
  if (flag[0]) {          // int32: [src[0..E), tgt[0..E)]
    s = (int)w[e];
    t = (int)w[E + e];
  } else {                // int64: low words at 2*elem
    s = (int)w[2 * e];
    t = (int)w[2 * (E + e)];
  }
  src[e] = s;
  tgt[e] = t;
  atomicAdd(cnt + t, 1.0f);
}

// ---------------------------------------------------------------------------
// Y0 = X @ W0, Y1 = X @ W1.  X:[N,K], W0/W1:[K,64].  Block: 256 thr,
// 32 rows x 128 cols per block, K staged in 64-chunks.
template <int K>
__global__ __launch_bounds__(256) void k_gemm(
    const float* __restrict__ X, const float* __restrict__ W0,
    const float* __restrict__ W1, float* __restrict__ Y0,
    float* __restrict__ Y1, int N) {
  __shared__ float Wl[64][128];   // 32 KB
  __shared__ float Xs[32][64];    // 8 KB
  const int tid = threadIdx.x;
  const int tx = tid & 31;        // col group: cols tx*4..tx*4+3
  const int ty = tid >> 5;        // row slot: rows ty + 8*i
  const int row0 = blockIdx.x * 32;

  float acc[4][4];
#pragma unroll
  for (int i = 0; i < 4; ++i)
#pragma unroll
    for (int c = 0; c < 4; ++c) acc[i][c] = 0.0f;

  for (int kc = 0; kc < K; kc += 64) {
    // stage W chunk: 64 rows x 128 cols = 2048 float4, 8 per thread
#pragma unroll
    for (int q = 0; q < 8; ++q) {
      int f = tid + 256 * q;
      int kk = f >> 5, c4 = f & 31;
      const float* sw = (c4 < 16) ? (W0 + (size_t)(kc + kk) * 64 + c4 * 4)
                                  : (W1 + (size_t)(kc + kk) * 64 + (c4 - 16) * 4);
      float4 v = *(const float4*)sw;
      *(float4*)&Wl[kk][c4 * 4] = v;
    }
    // stage X tile: 32 rows x 64 k = 512 float4, 2 per thread
#pragma unroll
    for (int q = 0; q < 2; ++q) {
      int f = tid + 256 * q;
      int r = f >> 4, k4 = f & 15;
      float4 v = *(const float4*)(X + (size_t)(row0 + r) * K + kc + k4 * 4);
      *(float4*)&Xs[r][k4 * 4] = v;
    }
    __syncthreads();
    for (int kk = 0; kk < 64; ++kk) {
      float4 wv = *(const float4*)&Wl[kk][tx * 4];
      float xv[4];
#pragma unroll
      for (int i = 0; i < 4; ++i) xv[i] = Xs[ty + 8 * i][kk];
#pragma unroll
      for (int i = 0; i < 4; ++i) {
        acc[i][0] = fmaf(xv[i], wv.x, acc[i][0]);
        acc[i][1] = fmaf(xv[i], wv.y, acc[i][1]);
        acc[i][2] = fmaf(xv[i], wv.z, acc[i][2]);
        acc[i][3] = fmaf(xv[i], wv.w, acc[i][3]);
      }
    }
    __syncthreads();
  }
#pragma unroll
  for (int i = 0; i < 4; ++i) {
    int r = row0 + ty + 8 * i;
    float4 v = make_float4(acc[i][0], acc[i][1], acc[i][2], acc[i][3]);
    if (tx < 16)
      *(float4*)(Y0 + (size_t)r * 64 + tx * 4) = v;
    else
      *(float4*)(Y1 + (size_t)r * 64 + (tx - 16) * 4) = v;
  }
}

// ---------------------------------------------------------------------------
// S[tgt[e]][j] += Y[src[e]][j]  (wave = one edge, lane = feature)
__global__ void k_scatter(const float* __restrict__ Y, const int* __restrict__ src,
                          const int* __restrict__ tgt, float* __restrict__ S,
                          int E) {
  int gid = blockIdx.x * 256 + threadIdx.x;
  int e = gid >> 6;
  if (e >= E) return;
  int j = gid & 63;
  int s = src[e], t = tgt[e];
  atomicAdd(S + (size_t)t * 64 + j, Y[(size_t)s * 64 + j]);
}

// h = relu(S/max(cnt,1) + bias + Yr); also re-zero S for the next layer.
__global__ void k_postagg(const float* __restrict__ S, const float* __restrict__ cnt,
                          const float* __restrict__ bias,
                          const float* __restrict__ Yr, float* __restrict__ Hout,
                          float* __restrict__ Szero, int N) {
  int gid = blockIdx.x * 256 + threadIdx.x;
  if (gid >= N * 64) return;
  int i = gid >> 6, j = gid & 63;
  float c = fmaxf(cnt[i], 1.0f);
  float v = S[gid] / c + bias[j] + Yr[gid];
  Hout[gid] = fmaxf(v, 0.0f);
  Szero[gid] = 0.0f;
}

// ---------------------------------------------------------------------------
// Fused per-edge pipeline: edge MLP + endpoint gather + output MLP + sigmoid.
// One thread per edge; weight reads are wave-uniform (scalarized to s_load).
__global__ __launch_bounds__(256, 1) void k_edge(
    const float* __restrict__ eattr, const int* __restrict__ src,
    const int* __restrict__ tgt, const float* __restrict__ H2,
    const float* __restrict__ We1, const float* __restrict__ be1,
    const float* __restrict__ We2, const float* __restrict__ be2,
    const float* __restrict__ Wo1, const float* __restrict__ bo1,
    const float* __restrict__ Wo2, const float* __restrict__ bo2,
    float* __restrict__ out, int E) {
  int e = blockIdx.x * 256 + threadIdx.x;
  if (e >= E) return;

  // load edge_attr row (16 f32, coalesced float4)
  float a[16];
  {
    const float4* ap = (const float4*)(eattr + (size_t)e * 16);
#pragma unroll
    for (int q = 0; q < 4; ++q) {
      float4 v = ap[q];
      a[4 * q + 0] = v.x; a[4 * q + 1] = v.y;
      a[4 * q + 2] = v.z; a[4 * q + 3] = v.w;
    }
  }

  // t1 = relu(a @ We1 + be1)
  float t1[64];
#pragma unroll
  for (int j = 0; j < 64; ++j) t1[j] = be1[j];
  for (int k = 0; k < 16; ++k) {
    float av = a[k];
#pragma unroll
    for (int j = 0; j < 64; ++j) t1[j] = fmaf(av, We1[k * 64 + j], t1[j]);
  }
#pragma unroll
  for (int j = 0; j < 64; ++j) t1[j] = fmaxf(t1[j], 0.0f);

  // t2 init folds be2 + h2[src] + h2[tgt] so gathers issue before the matvec
  int s = src[e], t = tgt[e];
  float t2[64];
  {
    const float4* hs = (const float4*)(H2 + (size_t)s * 64);
    const float4* ht = (const float4*)(H2 + (size_t)t * 64);
#pragma unroll
    for (int q = 0; q < 16; ++q) {
      float4 v1 = hs[q];
      float4 v2 = ht[q];
      t2[4 * q + 0] = be2[4 * q + 0] + v1.x + v2.x;
      t2[4 * q + 1] = be2[4 * q + 1] + v1.y + v2.y;
      t2[4 * q + 2] = be2[4 * q + 2] + v1.z + v2.z;
      t2[4 * q + 3] = be2[4 * q + 3] + v1.w + v2.w;
    }
  }
  // t2 += t1 @ We2
  for (int k = 0; k < 64; ++k) {
    float av = t1[k];
#pragma unroll
    for (int j = 0; j < 64; ++j) t2[j] = fmaf(av, We2[k * 64 + j], t2[j]);
  }

  // t3 = relu(t2 @ Wo1 + bo1)   (reuse t1 storage)
#pragma unroll
  for (int j = 0; j < 64; ++j) t1[j] = bo1[j];
  for (int k = 0; k < 64; ++k) {
    float av = t2[k];
#pragma unroll
    for (int j = 0; j < 64; ++j) t1[j] = fmaf(av, Wo1[k * 64 + j], t1[j]);
  }

  // o = relu(t3) . Wo2 + bo2;  sigmoid
  float o = bo2[0];
#pragma unroll
  for (int j = 0; j < 64; ++j) o = fmaf(fmaxf(t1[j], 0.0f), Wo2[j], o);
  out[e] = 1.0f / (1.0f + __expf(-o));
}

// ---------------------------------------------------------------------------
extern "C" void kernel_launch(void* const* d_in, const int* in_sizes, int n_in,
                              void* d_out, int out_size, void* d_ws, size_t ws_size,
                              hipStream_t stream) {
  const float* x     = (const float*)d_in[0];
  const unsigned int* eidx = (const unsigned int*)d_in[1];
  const float* eattr = (const float*)d_in[2];
  const float* We1 = (const float*)d_in[3];
  const float* be1 = (const float*)d_in[4];
  const float* We2 = (const float*)d_in[5];
  const float* be2 = (const float*)d_in[6];
  const float* Wl0 = (const float*)d_in[7];
  const float* bl0 = (const float*)d_in[8];
  const float* Wr0 = (const float*)d_in[9];
  const float* Wl1 = (const float*)d_in[10];
  const float* bl1 = (const float*)d_in[11];
  const float* Wr1 = (const float*)d_in[12];
  const float* Wo1 = (const float*)d_in[13];
  const float* bo1 = (const float*)d_in[14];
  const float* Wo2 = (const float*)d_in[15];
  const float* bo2 = (const float*)d_in[16];

  const int N = in_sizes[0] / 128;   // 100000
  const int E = in_sizes[2] / 16;    // 1000000
  float* out = (float*)d_out;

  // Workspace layout (bytes), all 256-aligned.
  char* ws = (char*)d_ws;
  size_t off = 0;
  auto alloc = [&](size_t bytes) {
    char* p = ws + off;
    off += (bytes + 255) & ~(size_t)255;
    return p;
  };
  unsigned int* flag = (unsigned int*)alloc(256);
  int* src  = (int*)alloc((size_t)E * 4);
  int* tgt  = (int*)alloc((size_t)E * 4);
  float* cnt = (float*)alloc((size_t)N * 4);
  float* S   = (float*)alloc((size_t)N * 64 * 4);
  float* Hb  = (float*)alloc((size_t)N * 64 * 4);
  float* Yl  = (float*)alloc((size_t)N * 64 * 4);
  float* Yr  = (float*)alloc((size_t)N * 64 * 4);
  (void)ws_size; (void)n_in; (void)out_size;

  hipMemsetAsync(cnt, 0, (size_t)N * 4, stream);
  hipMemsetAsync(S, 0, (size_t)N * 64 * 4, stream);

  k_flag<<<1, 256, 0, stream>>>(eidx, 8192, flag);
  k_decode<<<(E + 255) / 256, 256, 0, stream>>>(eidx, flag, E, src, tgt, cnt);

  // Layer 0:  y = x @ [Wl0 | Wr0]
  k_gemm<128><<<N / 32, 256, 0, stream>>>(x, Wl0, Wr0, Yl, Yr, N);
  k_scatter<<<(E * 64 + 255) / 256, 256, 0, stream>>>(Yl, src, tgt, S, E);
  k_postagg<<<(N * 64 + 255) / 256, 256, 0, stream>>>(S, cnt, bl0, Yr, Hb, S, N);

  // Layer 1:  y = h @ [Wl1 | Wr1]
  k_gemm<64><<<N / 32, 256, 0, stream>>>(Hb, Wl1, Wr1, Yl, Yr, N);
  k_scatter<<<(E * 64 + 255) / 256, 256, 0, stream>>>(Yl, src, tgt, S, E);
  k_postagg<<<(N * 64 + 255) / 256, 256, 0, stream>>>(S, cnt, bl1, Yr, Hb, S, N);

  // Fused edge pipeline
  k_edge<<<(E + 255) / 256, 256, 0, stream>>>(
      eattr, src, tgt, Hb, We1, be1, We2, be2, Wo1, bo1, Wo2, bo2, out, E);
}

// Round 2
// 1184.991 us; speedup vs baseline: 1.0335x; 1.0335x over previous
//
#include <hip/hip_runtime.h>
#include <math.h>

// ---------------------------------------------------------------------------
// int64-vs-int32 edge_index detection: OR of odd words of the first 8192
// elements. int64 (little-endian) => hi words all zero => flag==0.
__global__ void k_flag(const unsigned int* __restrict__ w, int nSample,
                       unsigned int* __restrict__ flag) {
  __shared__ unsigned int red[256];
  unsigned int v = 0;
  for (int i = threadIdx.x; i < nSample; i += 256) v |= w[2 * i + 1];
  red[threadIdx.x] = v;
  __syncthreads();
  for (int s = 128; s > 0; s >>= 1) {
    if (threadIdx.x < s) red[threadIdx.x] |= red[threadIdx.x + s];
    __syncthreads();
  }
  if (threadIdx.x == 0) flag[0] = red[0];  // nonzero => int32 layout
}

// Decode edge_index into int32 src/tgt and accumulate in-degree (float).
__global__ void k_decode(const unsigned int* __restrict__ w,
                         const unsigned int* __restrict__ flag, int E,
                         int* __restrict__ src, int* __restrict__ tgt,
                         float* __restrict__ cnt) {
  int e = blockIdx.x * 256 + threadIdx.x;
  if (e >= E) return;
  int s, t;
  if (flag[0]) {          // int32: [src[0..E), tgt[0..E)]
    s = (int)w[e];
    t = (int)w[E + e];
  } else {                // int64: low words at 2*elem
    s = (int)w[2 * e];
    t = (int)w[2 * (E + e)];
  }
  src[e] = s;
  tgt[e] = t;
  atomicAdd(cnt + t, 1.0f);
}

// ---------------------------------------------------------------------------
// Y0 = X @ W0, Y1 = X @ W1.  X:[N,K], W0/W1:[K,64].  Block: 256 thr,
// 32 rows x 128 cols per block, K staged in 64-chunks.
template <int K>
__global__ __launch_bounds__(256) void k_gemm(
    const float* __restrict__ X, const float* __restrict__ W0,
    const float* __restrict__ W1, float* __restrict__ Y0,
    float* __restrict__ Y1, int N) {
  __shared__ float Wl[64][128];   // 32 KB
  __shared__ float Xs[32][64];    // 8 KB
  const int tid = threadIdx.x;
  const int tx = tid & 31;        // col group: cols tx*4..tx*4+3
  const int ty = tid >> 5;        // row slot: rows ty + 8*i
  const int row0 = blockIdx.x * 32;

  float acc[4][4];
#pragma unroll
  for (int i = 0; i < 4; ++i)
#pragma unroll
    for (int c = 0; c < 4; ++c) acc[i][c] = 0.0f;

  for (int kc = 0; kc < K; kc += 64) {
    // stage W chunk: 64 rows x 128 cols = 2048 float4, 8 per thread
#pragma unroll
    for (int q = 0; q < 8; ++q) {
      int f = tid + 256 * q;
      int kk = f >> 5, c4 = f & 31;
      const float* sw = (c4 < 16) ? (W0 + (size_t)(kc + kk) * 64 + c4 * 4)
                                  : (W1 + (size_t)(kc + kk) * 64 + (c4 - 16) * 4);
      float4 v = *(const float4*)sw;
      *(float4*)&Wl[kk][c4 * 4] = v;
    }
    // stage X tile: 32 rows x 64 k = 512 float4, 2 per thread
#pragma unroll
    for (int q = 0; q < 2; ++q) {
      int f = tid + 256 * q;
      int r = f >> 4, k4 = f & 15;
      float4 v = *(const float4*)(X + (size_t)(row0 + r) * K + kc + k4 * 4);
      *(float4*)&Xs[r][k4 * 4] = v;
    }
    __syncthreads();
    for (int kk = 0; kk < 64; ++kk) {
      float4 wv = *(const float4*)&Wl[kk][tx * 4];
      float xv[4];
#pragma unroll
      for (int i = 0; i < 4; ++i) xv[i] = Xs[ty + 8 * i][kk];
#pragma unroll
      for (int i = 0; i < 4; ++i) {
        acc[i][0] = fmaf(xv[i], wv.x, acc[i][0]);
        acc[i][1] = fmaf(xv[i], wv.y, acc[i][1]);
        acc[i][2] = fmaf(xv[i], wv.z, acc[i][2]);
        acc[i][3] = fmaf(xv[i], wv.w, acc[i][3]);
      }
    }
    __syncthreads();
  }
#pragma unroll
  for (int i = 0; i < 4; ++i) {
    int r = row0 + ty + 8 * i;
    float4 v = make_float4(acc[i][0], acc[i][1], acc[i][2], acc[i][3]);
    if (tx < 16)
      *(float4*)(Y0 + (size_t)r * 64 + tx * 4) = v;
    else
      *(float4*)(Y1 + (size_t)r * 64 + (tx - 16) * 4) = v;
  }
}

// ---------------------------------------------------------------------------
// S[tgt[e]][j] += Y[src[e]][j]  (wave = one edge, lane = feature)
__global__ void k_scatter(const float* __restrict__ Y, const int* __restrict__ src,
                          const int* __restrict__ tgt, float* __restrict__ S,
                          int E) {
  int gid = blockIdx.x * 256 + threadIdx.x;
  int e = gid >> 6;
  if (e >= E) return;
  int j = gid & 63;
  int s = src[e], t = tgt[e];
  atomicAdd(S + (size_t)t * 64 + j, Y[(size_t)s * 64 + j]);
}

// h = relu(S/max(cnt,1) + bias + Yr); also re-zero S for the next layer.
__global__ void k_postagg(const float* __restrict__ S, const float* __restrict__ cnt,
                          const float* __restrict__ bias,
                          const float* __restrict__ Yr, float* __restrict__ Hout,
                          float* __restrict__ Szero, int N) {
  int gid = blockIdx.x * 256 + threadIdx.x;
  if (gid >= N * 64) return;
  int i = gid >> 6, j = gid & 63;
  float c = fmaxf(cnt[i], 1.0f);
  float v = S[gid] / c + bias[j] + Yr[gid];
  Hout[gid] = fmaxf(v, 0.0f);
  Szero[gid] = 0.0f;
}

// ---------------------------------------------------------------------------
// Fused per-edge pipeline: edge MLP + endpoint gather + output MLP + sigmoid.
// One thread per edge. ALL inner loops fully unrolled so the per-thread
// arrays a[16]/t1[64]/t2[64] live in registers (dynamic indexing spilled them
// to scratch in R1: VGPR=60, WRITE_SIZE=1.4 GB).
__global__ __launch_bounds__(256, 1) void k_edge(
    const float* __restrict__ eattr, const int* __restrict__ src,
    const int* __restrict__ tgt, const float* __restrict__ H2,
    const float* __restrict__ We1, const float* __restrict__ be1,
    const float* __restrict__ We2, const float* __restrict__ be2,
    const float* __restrict__ Wo1, const float* __restrict__ bo1,
    const float* __restrict__ Wo2, const float* __restrict__ bo2,
    float* __restrict__ out, int E) {
  int e = blockIdx.x * 256 + threadIdx.x;
  if (e >= E) return;

  // load edge_attr row (16 f32, coalesced float4)
  float a[16];
  {
    const float4* ap = (const float4*)(eattr + (size_t)e * 16);
#pragma unroll
    for (int q = 0; q < 4; ++q) {
      float4 v = ap[q];
      a[4 * q + 0] = v.x; a[4 * q + 1] = v.y;
      a[4 * q + 2] = v.z; a[4 * q + 3] = v.w;
    }
  }

  // t1 = relu(a @ We1 + be1)
  float t1[64];
#pragma unroll
  for (int j = 0; j < 64; ++j) t1[j] = be1[j];
#pragma unroll
  for (int k = 0; k < 16; ++k) {
    float av = a[k];
#pragma unroll
    for (int j = 0; j < 64; ++j) t1[j] = fmaf(av, We1[k * 64 + j], t1[j]);
  }
#pragma unroll
  for (int j = 0; j < 64; ++j) t1[j] = fmaxf(t1[j], 0.0f);

  // t2 init folds be2 + h2[src] + h2[tgt] so gathers issue before the matvec
  int s = src[e], t = tgt[e];
  float t2[64];
  {
    const float4* hs = (const float4*)(H2 + (size_t)s * 64);
    const float4* ht = (const float4*)(H2 + (size_t)t * 64);
#pragma unroll
    for (int q = 0; q < 16; ++q) {
      float4 v1 = hs[q];
      float4 v2 = ht[q];
      t2[4 * q + 0] = be2[4 * q + 0] + v1.x + v2.x;
      t2[4 * q + 1] = be2[4 * q + 1] + v1.y + v2.y;
      t2[4 * q + 2] = be2[4 * q + 2] + v1.z + v2.z;
      t2[4 * q + 3] = be2[4 * q + 3] + v1.w + v2.w;
    }
  }
  // t2 += t1 @ We2
#pragma unroll
  for (int k = 0; k < 64; ++k) {
    float av = t1[k];
#pragma unroll
    for (int j = 0; j < 64; ++j) t2[j] = fmaf(av, We2[k * 64 + j], t2[j]);
  }

  // t3 = relu(t2 @ Wo1 + bo1)   (reuse t1 storage)
#pragma unroll
  for (int j = 0; j < 64; ++j) t1[j] = bo1[j];
#pragma unroll
  for (int k = 0; k < 64; ++k) {
    float av = t2[k];
#pragma unroll
    for (int j = 0; j < 64; ++j) t1[j] = fmaf(av, Wo1[k * 64 + j], t1[j]);
  }

  // o = relu(t3) . Wo2 + bo2;  sigmoid
  float o = bo2[0];
#pragma unroll
  for (int j = 0; j < 64; ++j) o = fmaf(fmaxf(t1[j], 0.0f), Wo2[j], o);
  out[e] = 1.0f / (1.0f + __expf(-o));
}

// ---------------------------------------------------------------------------
extern "C" void kernel_launch(void* const* d_in, const int* in_sizes, int n_in,
                              void* d_out, int out_size, void* d_ws, size_t ws_size,
                              hipStream_t stream) {
  const float* x     = (const float*)d_in[0];
  const unsigned int* eidx = (const unsigned int*)d_in[1];
  const float* eattr = (const float*)d_in[2];
  const float* We1 = (const float*)d_in[3];
  const float* be1 = (const float*)d_in[4];
  const float* We2 = (const float*)d_in[5];
  const float* be2 = (const float*)d_in[6];
  const float* Wl0 = (const float*)d_in[7];
  const float* bl0 = (const float*)d_in[8];
  const float* Wr0 = (const float*)d_in[9];
  const float* Wl1 = (const float*)d_in[10];
  const float* bl1 = (const float*)d_in[11];
  const float* Wr1 = (const float*)d_in[12];
  const float* Wo1 = (const float*)d_in[13];
  const float* bo1 = (const float*)d_in[14];
  const float* Wo2 = (const float*)d_in[15];
  const float* bo2 = (const float*)d_in[16];

  const int N = in_sizes[0] / 128;   // 100000
  const int E = in_sizes[2] / 16;    // 1000000
  float* out = (float*)d_out;

  // Workspace layout (bytes), all 256-aligned.
  char* ws = (char*)d_ws;
  size_t off = 0;
  auto alloc = [&](size_t bytes) {
    char* p = ws + off;
    off += (bytes + 255) & ~(size_t)255;
    return p;
  };
  unsigned int* flag = (unsigned int*)alloc(256);
  int* src  = (int*)alloc((size_t)E * 4);
  int* tgt  = (int*)alloc((size_t)E * 4);
  float* cnt = (float*)alloc((size_t)N * 4);
  float* S   = (float*)alloc((size_t)N * 64 * 4);
  float* Hb  = (float*)alloc((size_t)N * 64 * 4);
  float* Yl  = (float*)alloc((size_t)N * 64 * 4);
  float* Yr  = (float*)alloc((size_t)N * 64 * 4);
  (void)ws_size; (void)n_in; (void)out_size;

  hipMemsetAsync(cnt, 0, (size_t)N * 4, stream);
  hipMemsetAsync(S, 0, (size_t)N * 64 * 4, stream);

  k_flag<<<1, 256, 0, stream>>>(eidx, 8192, flag);
  k_decode<<<(E + 255) / 256, 256, 0, stream>>>(eidx, flag, E, src, tgt, cnt);

  // Layer 0:  y = x @ [Wl0 | Wr0]   (project-then-aggregate: mean is linear)
  k_gemm<128><<<N / 32, 256, 0, stream>>>(x, Wl0, Wr0, Yl, Yr, N);
  k_scatter<<<(E * 64 + 255) / 256, 256, 0, stream>>>(Yl, src, tgt, S, E);
  k_postagg<<<(N * 64 + 255) / 256, 256, 0, stream>>>(S, cnt, bl0, Yr, Hb, S, N);

  // Layer 1:  y = h @ [Wl1 | Wr1]
  k_gemm<64><<<N / 32, 256, 0, stream>>>(Hb, Wl1, Wr1, Yl, Yr, N);
  k_scatter<<<(E * 64 + 255) / 256, 256, 0, stream>>>(Yl, src, tgt, S, E);
  k_postagg<<<(N * 64 + 255) / 256, 256, 0, stream>>>(S, cnt, bl1, Yr, Hb, S, N);

  // Fused edge pipeline
  k_edge<<<(E + 255) / 256, 256, 0, stream>>>(
      eattr, src, tgt, Hb, We1, be1, We2, be2, Wo1, bo1, Wo2, bo2, out, E);
}

// Round 3
// 837.833 us; speedup vs baseline: 1.4618x; 1.4144x over previous
//
#include <hip/hip_runtime.h>
#include <math.h>

// ---------------------------------------------------------------------------
// int64-vs-int32 edge_index detection: OR of odd words of the first 8192
// elements. int64 (little-endian) => hi words all zero => flag==0.
__global__ void k_flag(const unsigned int* __restrict__ w, int nSample,
                       unsigned int* __restrict__ flag) {
  __shared__ unsigned int red[256];
  unsigned int v = 0;
  for (int i = threadIdx.x; i < nSample; i += 256) v |= w[2 * i + 1];
  red[threadIdx.x] = v;
  __syncthreads();
  for (int s = 128; s > 0; s >>= 1) {
    if (threadIdx.x < s) red[threadIdx.x] |= red[threadIdx.x + s];
    __syncthreads();
  }
  if (threadIdx.x == 0) flag[0] = red[0];  // nonzero => int32 layout
}

// Decode edge_index into int32 src/tgt and accumulate in-degree (int).
__global__ void k_decode(const unsigned int* __restrict__ w,
                         const unsigned int* __restrict__ flag, int E,
                         int* __restrict__ src, int* __restrict__ tgt,
                         int* __restrict__ deg) {
  int e = blockIdx.x * 256 + threadIdx.x;
  if (e >= E) return;
  int s, t;
  if (flag[0]) {          // int32: [src[0..E), tgt[0..E)]
    s = (int)w[e];
    t = (int)w[E + e];
  } else {                // int64: low words at 2*elem
    s = (int)w[2 * e];
    t = (int)w[2 * (E + e)];
  }
  src[e] = s;
  tgt[e] = t;
  atomicAdd(deg + t, 1);
}

// Exclusive scan of deg[N] -> rowptr[N+1]. One block, 1024 threads,
// contiguous chunk per thread + block scan of chunk sums.
__global__ __launch_bounds__(1024) void k_scan(const int* __restrict__ deg,
                                               int* __restrict__ rowptr, int N) {
  __shared__ int buf[1024];
  int tid = threadIdx.x;
  int chunk = (N + 1023) / 1024;
  int lo = tid * chunk;
  int hi = lo + chunk; if (hi > N) hi = N;
  int s = 0;
  for (int i = lo; i < hi; ++i) s += deg[i];
  buf[tid] = s;
  __syncthreads();
  for (int off = 1; off < 1024; off <<= 1) {
    int t = (tid >= off) ? buf[tid - off] : 0;
    __syncthreads();
    buf[tid] += t;
    __syncthreads();
  }
  int run = buf[tid] - s;  // exclusive prefix of this chunk
  for (int i = lo; i < hi; ++i) { rowptr[i] = run; run += deg[i]; }
  if (tid == 1023) rowptr[N] = buf[1023];
}

// CSR fill: cursor pre-initialized to rowptr (d2d copy).
__global__ void k_fill(const int* __restrict__ src, const int* __restrict__ tgt,
                       int* __restrict__ cursor, int* __restrict__ csrc, int E) {
  int e = blockIdx.x * 256 + threadIdx.x;
  if (e >= E) return;
  int pos = atomicAdd(cursor + tgt[e], 1);
  csrc[pos] = src[e];
}

// ---------------------------------------------------------------------------
// Y0 = X @ W0, Y1 = X @ W1.  X:[N,K], W0/W1:[K,64].  Block: 256 thr,
// 32 rows x 128 cols per block, K staged in 64-chunks.
template <int K>
__global__ __launch_bounds__(256) void k_gemm(
    const float* __restrict__ X, const float* __restrict__ W0,
    const float* __restrict__ W1, float* __restrict__ Y0,
    float* __restrict__ Y1, int N) {
  __shared__ float Wl[64][128];   // 32 KB
  __shared__ float Xs[32][64];    // 8 KB
  const int tid = threadIdx.x;
  const int tx = tid & 31;        // col group: cols tx*4..tx*4+3
  const int ty = tid >> 5;        // row slot: rows ty + 8*i
  const int row0 = blockIdx.x * 32;

  float acc[4][4];
#pragma unroll
  for (int i = 0; i < 4; ++i)
#pragma unroll
    for (int c = 0; c < 4; ++c) acc[i][c] = 0.0f;

  for (int kc = 0; kc < K; kc += 64) {
#pragma unroll
    for (int q = 0; q < 8; ++q) {
      int f = tid + 256 * q;
      int kk = f >> 5, c4 = f & 31;
      const float* sw = (c4 < 16) ? (W0 + (size_t)(kc + kk) * 64 + c4 * 4)
                                  : (W1 + (size_t)(kc + kk) * 64 + (c4 - 16) * 4);
      float4 v = *(const float4*)sw;
      *(float4*)&Wl[kk][c4 * 4] = v;
    }
#pragma unroll
    for (int q = 0; q < 2; ++q) {
      int f = tid + 256 * q;
      int r = f >> 4, k4 = f & 15;
      float4 v = *(const float4*)(X + (size_t)(row0 + r) * K + kc + k4 * 4);
      *(float4*)&Xs[r][k4 * 4] = v;
    }
    __syncthreads();
    for (int kk = 0; kk < 64; ++kk) {
      float4 wv = *(const float4*)&Wl[kk][tx * 4];
      float xv[4];
#pragma unroll
      for (int i = 0; i < 4; ++i) xv[i] = Xs[ty + 8 * i][kk];
#pragma unroll
      for (int i = 0; i < 4; ++i) {
        acc[i][0] = fmaf(xv[i], wv.x, acc[i][0]);
        acc[i][1] = fmaf(xv[i], wv.y, acc[i][1]);
        acc[i][2] = fmaf(xv[i], wv.z, acc[i][2]);
        acc[i][3] = fmaf(xv[i], wv.w, acc[i][3]);
      }
    }
    __syncthreads();
  }
#pragma unroll
  for (int i = 0; i < 4; ++i) {
    int r = row0 + ty + 8 * i;
    float4 v = make_float4(acc[i][0], acc[i][1], acc[i][2], acc[i][3]);
    if (tx < 16)
      *(float4*)(Y0 + (size_t)r * 64 + tx * 4) = v;
    else
      *(float4*)(Y1 + (size_t)r * 64 + (tx - 16) * 4) = v;
  }
}

// Single-output GEMM: Y = X @ W.  X:[N,64], W:[64,64]. 64 rows/block.
__global__ __launch_bounds__(256) void k_gemm1(const float* __restrict__ X,
                                               const float* __restrict__ W,
                                               float* __restrict__ Y, int N) {
  __shared__ float sW[64][68];
  __shared__ float sX[64][68];
  const int tid = threadIdx.x;
  const int tx = tid & 15, ty = tid >> 4;
  const int row0 = blockIdx.x * 64;
#pragma unroll
  for (int q = 0; q < 4; ++q) {
    int f = tid + 256 * q;
    int r = f >> 4, c4 = f & 15;
    *(float4*)&sW[r][c4 * 4] = *(const float4*)(W + (size_t)r * 64 + c4 * 4);
    int xr = row0 + r; if (xr >= N) xr = N - 1;
    *(float4*)&sX[r][c4 * 4] = *(const float4*)(X + (size_t)xr * 64 + c4 * 4);
  }
  __syncthreads();
  float acc[4][4];
#pragma unroll
  for (int i = 0; i < 4; ++i)
#pragma unroll
    for (int c = 0; c < 4; ++c) acc[i][c] = 0.0f;
  for (int k4 = 0; k4 < 64; k4 += 4) {
    float4 arow[4];
#pragma unroll
    for (int i = 0; i < 4; ++i) arow[i] = *(const float4*)&sX[ty * 4 + i][k4];
#pragma unroll
    for (int kk = 0; kk < 4; ++kk) {
      float4 wv = *(const float4*)&sW[k4 + kk][tx * 4];
#pragma unroll
      for (int i = 0; i < 4; ++i) {
        float a = (&arow[i].x)[kk];
        acc[i][0] = fmaf(a, wv.x, acc[i][0]);
        acc[i][1] = fmaf(a, wv.y, acc[i][1]);
        acc[i][2] = fmaf(a, wv.z, acc[i][2]);
        acc[i][3] = fmaf(a, wv.w, acc[i][3]);
      }
    }
  }
#pragma unroll
  for (int i = 0; i < 4; ++i) {
    int r = row0 + ty * 4 + i;
    if (r < N)
      *(float4*)(Y + (size_t)r * 64 + tx * 4) =
          make_float4(acc[i][0], acc[i][1], acc[i][2], acc[i][3]);
  }
}

// W25 = We2 @ Wo1 (64x64), cvec = be2 @ Wo1 + bo1. One block.
__global__ void k_prep(const float* __restrict__ We2, const float* __restrict__ Wo1,
                       const float* __restrict__ be2, const float* __restrict__ bo1,
                       float* __restrict__ W25, float* __restrict__ cvec) {
  int tid = threadIdx.x;
  for (int idx = tid; idx < 4096; idx += 256) {
    int r = idx >> 6, c = idx & 63;
    float s = 0.f;
    for (int k = 0; k < 64; ++k) s = fmaf(We2[r * 64 + k], Wo1[k * 64 + c], s);
    W25[idx] = s;
  }
  if (tid < 64) {
    float s = bo1[tid];
    for (int k = 0; k < 64; ++k) s = fmaf(be2[k], Wo1[k * 64 + tid], s);
    cvec[tid] = s;
  }
}

// CSR aggregate fused with epilogue: H = relu(sum/deg + bias + Yr).
// Wave per node, lane = feature.
__global__ __launch_bounds__(256) void k_agg(
    const float* __restrict__ Y, const int* __restrict__ rowptr,
    const int* __restrict__ csrc, const float* __restrict__ bias,
    const float* __restrict__ Yr, float* __restrict__ H, int N) {
  int node = (blockIdx.x * 256 + threadIdx.x) >> 6;
  int j = threadIdx.x & 63;
  if (node >= N) return;
  int beg = rowptr[node], end = rowptr[node + 1];
  float a0 = 0.f, a1 = 0.f;
  int e = beg;
  for (; e + 2 <= end; e += 2) {
    int s0 = csrc[e], s1 = csrc[e + 1];
    a0 += Y[(size_t)s0 * 64 + j];
    a1 += Y[(size_t)s1 * 64 + j];
  }
  if (e < end) a0 += Y[(size_t)csrc[e] * 64 + j];
  float cdeg = (float)(end - beg);
  if (cdeg < 1.f) cdeg = 1.f;
  float v = (a0 + a1) / cdeg + bias[j] + Yr[(size_t)node * 64 + j];
  H[(size_t)node * 64 + j] = fmaxf(v, 0.f);
}

// ---------------------------------------------------------------------------
// Tiled edge pipeline. Per 64-edge tile:
//   t1 = relu(EA @ We1 + be1)                       (64x16x64 GEMM, LDS)
//   t3 = relu(G[src]+G[tgt] + t1 @ W25 + c)          (64x64x64 GEMM, acc-init
//                                                    from global G gathers)
//   out = sigmoid(t3 . Wo2 + bo2)                    (shfl_xor reduce)
// Weights staged in LDS once per block; grid-stride over tiles.
__global__ __launch_bounds__(256) void k_edge2(
    const float* __restrict__ eattr, const int* __restrict__ src,
    const int* __restrict__ tgt, const float* __restrict__ G,
    const float* __restrict__ We1, const float* __restrict__ be1,
    const float* __restrict__ W25, const float* __restrict__ cvec,
    const float* __restrict__ Wo2, const float* __restrict__ bo2,
    float* __restrict__ out, int E, int nTiles) {
  __shared__ float sWe1[16][64];   // 4 KB
  __shared__ float sW25[64][68];   // 17 KB
  __shared__ float sEA[64][16];    // 4 KB
  __shared__ float sT1[64][68];    // 17 KB
  __shared__ float sBe1[64], sC[64];
  __shared__ int sSrc[64], sTgt[64];

  const int tid = threadIdx.x;
  const int tx = tid & 15, ty = tid >> 4;

  // stage persistent weights
  {
    int r = tid >> 4, c4 = tid & 15;
    *(float4*)&sWe1[r][c4 * 4] = *(const float4*)(We1 + (size_t)r * 64 + c4 * 4);
  }
#pragma unroll
  for (int q = 0; q < 4; ++q) {
    int f = tid + 256 * q;
    int r = f >> 4, c4 = f & 15;
    *(float4*)&sW25[r][c4 * 4] = *(const float4*)(W25 + (size_t)r * 64 + c4 * 4);
  }
  if (tid < 64) { sBe1[tid] = be1[tid]; sC[tid] = cvec[tid]; }
  const float b_out = bo2[0];
  const float4 wo2v = *(const float4*)(Wo2 + tx * 4);

  for (int t = blockIdx.x; t < nTiles; t += gridDim.x) {
    const int base = t * 64;
    __syncthreads();   // protect LDS tile buffers from previous iteration
    // stage EA tile (64x16) + src/tgt
    {
      int r = tid >> 2, q4 = tid & 3;
      int rr = base + r; if (rr >= E) rr = E - 1;
      *(float4*)&sEA[r][q4 * 4] = *(const float4*)(eattr + (size_t)rr * 16 + q4 * 4);
    }
    if (tid < 64) {
      int rr = base + tid; if (rr >= E) rr = E - 1;
      sSrc[tid] = src[rr];
    } else if (tid < 128) {
      int rr = base + tid - 64; if (rr >= E) rr = E - 1;
      sTgt[tid - 64] = tgt[rr];
    }
    __syncthreads();

    // G gathers for acc init (issued early to overlap GEMM1)
    float4 gacc[4];
#pragma unroll
    for (int i = 0; i < 4; ++i) {
      int r = ty * 4 + i;
      float4 gs = *(const float4*)(G + (size_t)sSrc[r] * 64 + tx * 4);
      float4 gt = *(const float4*)(G + (size_t)sTgt[r] * 64 + tx * 4);
      gacc[i] = make_float4(gs.x + gt.x, gs.y + gt.y, gs.z + gt.z, gs.w + gt.w);
    }

    // GEMM1: t1 = EA @ We1 + be1 (K=16)
    float t1[4][4];
    {
      float4 bv = *(const float4*)&sBe1[tx * 4];
#pragma unroll
      for (int i = 0; i < 4; ++i) {
        t1[i][0] = bv.x; t1[i][1] = bv.y; t1[i][2] = bv.z; t1[i][3] = bv.w;
      }
    }
#pragma unroll
    for (int k = 0; k < 16; ++k) {
      float4 wv = *(const float4*)&sWe1[k][tx * 4];
#pragma unroll
      for (int i = 0; i < 4; ++i) {
        float a = sEA[ty * 4 + i][k];
        t1[i][0] = fmaf(a, wv.x, t1[i][0]);
        t1[i][1] = fmaf(a, wv.y, t1[i][1]);
        t1[i][2] = fmaf(a, wv.z, t1[i][2]);
        t1[i][3] = fmaf(a, wv.w, t1[i][3]);
      }
    }
#pragma unroll
    for (int i = 0; i < 4; ++i)
      *(float4*)&sT1[ty * 4 + i][tx * 4] =
          make_float4(fmaxf(t1[i][0], 0.f), fmaxf(t1[i][1], 0.f),
                      fmaxf(t1[i][2], 0.f), fmaxf(t1[i][3], 0.f));
    __syncthreads();

    // GEMM2: acc = gacc + c + T1 @ W25 (K=64, chunks of 4)
    float acc[4][4];
    {
      float4 cv = *(const float4*)&sC[tx * 4];
#pragma unroll
      for (int i = 0; i < 4; ++i) {
        acc[i][0] = gacc[i].x + cv.x; acc[i][1] = gacc[i].y + cv.y;
        acc[i][2] = gacc[i].z + cv.z; acc[i][3] = gacc[i].w + cv.w;
      }
    }
    for (int k4 = 0; k4 < 64; k4 += 4) {
      float4 arow[4];
#pragma unroll
      for (int i = 0; i < 4; ++i) arow[i] = *(const float4*)&sT1[ty * 4 + i][k4];
#pragma unroll
      for (int kk = 0; kk < 4; ++kk) {
        float4 wv = *(const float4*)&sW25[k4 + kk][tx * 4];
#pragma unroll
        for (int i = 0; i < 4; ++i) {
          float a = (&arow[i].x)[kk];
          acc[i][0] = fmaf(a, wv.x, acc[i][0]);
          acc[i][1] = fmaf(a, wv.y, acc[i][1]);
          acc[i][2] = fmaf(a, wv.z, acc[i][2]);
          acc[i][3] = fmaf(a, wv.w, acc[i][3]);
        }
      }
    }

    // epilogue: p[i] = sum_c relu(acc[i][c]) * Wo2[c]; reduce over tx lanes
    float p[4];
#pragma unroll
    for (int i = 0; i < 4; ++i)
      p[i] = fmaxf(acc[i][0], 0.f) * wo2v.x + fmaxf(acc[i][1], 0.f) * wo2v.y +
             fmaxf(acc[i][2], 0.f) * wo2v.z + fmaxf(acc[i][3], 0.f) * wo2v.w;
#pragma unroll
    for (int m = 1; m <= 8; m <<= 1) {
#pragma unroll
      for (int i = 0; i < 4; ++i) p[i] += __shfl_xor(p[i], m, 64);
    }
    if (tx == 0) {
#pragma unroll
      for (int i = 0; i < 4; ++i) {
        int r = base + ty * 4 + i;
        if (r < E) out[r] = 1.f / (1.f + __expf(-(p[i] + b_out)));
      }
    }
  }
}

// ---------------------------------------------------------------------------
extern "C" void kernel_launch(void* const* d_in, const int* in_sizes, int n_in,
                              void* d_out, int out_size, void* d_ws, size_t ws_size,
                              hipStream_t stream) {
  const float* x     = (const float*)d_in[0];
  const unsigned int* eidx = (const unsigned int*)d_in[1];
  const float* eattr = (const float*)d_in[2];
  const float* We1 = (const float*)d_in[3];
  const float* be1 = (const float*)d_in[4];
  const float* We2 = (const float*)d_in[5];
  const float* be2 = (const float*)d_in[6];
  const float* Wl0 = (const float*)d_in[7];
  const float* bl0 = (const float*)d_in[8];
  const float* Wr0 = (const float*)d_in[9];
  const float* Wl1 = (const float*)d_in[10];
  const float* bl1 = (const float*)d_in[11];
  const float* Wr1 = (const float*)d_in[12];
  const float* Wo1 = (const float*)d_in[13];
  const float* bo1 = (const float*)d_in[14];
  const float* Wo2 = (const float*)d_in[15];
  const float* bo2 = (const float*)d_in[16];

  const int N = in_sizes[0] / 128;   // 100000
  const int E = in_sizes[2] / 16;    // 1000000
  float* out = (float*)d_out;

  char* ws = (char*)d_ws;
  size_t off = 0;
  auto alloc = [&](size_t bytes) {
    char* p = ws + off;
    off += (bytes + 255) & ~(size_t)255;
    return p;
  };
  unsigned int* flag = (unsigned int*)alloc(256);
  int* src    = (int*)alloc((size_t)E * 4);
  int* tgt    = (int*)alloc((size_t)E * 4);
  int* deg    = (int*)alloc((size_t)N * 4);
  int* rowptr = (int*)alloc((size_t)(N + 1) * 4);
  int* cursor = (int*)alloc((size_t)N * 4);
  int* csrc   = (int*)alloc((size_t)E * 4);
  float* Hb   = (float*)alloc((size_t)N * 64 * 4);
  float* Yl   = (float*)alloc((size_t)N * 64 * 4);
  float* Yr   = (float*)alloc((size_t)N * 64 * 4);
  float* G    = (float*)alloc((size_t)N * 64 * 4);
  float* W25  = (float*)alloc(64 * 64 * 4);
  float* cvec = (float*)alloc(64 * 4);
  (void)ws_size; (void)n_in; (void)out_size;

  hipMemsetAsync(deg, 0, (size_t)N * 4, stream);

  k_flag<<<1, 256, 0, stream>>>(eidx, 8192, flag);
  k_decode<<<(E + 255) / 256, 256, 0, stream>>>(eidx, flag, E, src, tgt, deg);
  k_scan<<<1, 1024, 0, stream>>>(deg, rowptr, N);
  hipMemcpyAsync(cursor, rowptr, (size_t)N * 4, hipMemcpyDeviceToDevice, stream);
  k_fill<<<(E + 255) / 256, 256, 0, stream>>>(src, tgt, cursor, csrc, E);
  k_prep<<<1, 256, 0, stream>>>(We2, Wo1, be2, bo1, W25, cvec);

  // Layer 0 (project-then-aggregate: mean is linear)
  k_gemm<128><<<N / 32, 256, 0, stream>>>(x, Wl0, Wr0, Yl, Yr, N);
  k_agg<<<(N + 3) / 4, 256, 0, stream>>>(Yl, rowptr, csrc, bl0, Yr, Hb, N);

  // Layer 1
  k_gemm<64><<<N / 32, 256, 0, stream>>>(Hb, Wl1, Wr1, Yl, Yr, N);
  k_agg<<<(N + 3) / 4, 256, 0, stream>>>(Yl, rowptr, csrc, bl1, Yr, Hb, N);

  // G = H2 @ Wo1
  k_gemm1<<<(N + 63) / 64, 256, 0, stream>>>(Hb, Wo1, G, N);

  // Fused edge pipeline (tiled GEMM form)
  const int nTiles = (E + 63) / 64;
  k_edge2<<<768, 256, 0, stream>>>(eattr, src, tgt, G, We1, be1, W25, cvec,
                                   Wo2, bo2, out, E, nTiles);
}

// Round 5
// 837.469 us; speedup vs baseline: 1.4624x; 1.0004x over previous
//
#include <hip/hip_runtime.h>
#include <math.h>

typedef __attribute__((ext_vector_type(8))) short short8;
typedef __attribute__((ext_vector_type(4))) float f32x4;

static __device__ __forceinline__ unsigned short f2bf(float f) {
  union { float f; unsigned int u; } x; x.f = f;
  unsigned int r = x.u + 0x7fffu + ((x.u >> 16) & 1u);  // RNE
  return (unsigned short)(r >> 16);
}

// ---------------------------------------------------------------------------
// int64-vs-int32 edge_index detection: OR of odd words of the first 8192
// elements. int64 (little-endian) => hi words all zero => flag==0.
__global__ void k_flag(const unsigned int* __restrict__ w, int nSample,
                       unsigned int* __restrict__ flag) {
  __shared__ unsigned int red[256];
  unsigned int v = 0;
  for (int i = threadIdx.x; i < nSample; i += 256) v |= w[2 * i + 1];
  red[threadIdx.x] = v;
  __syncthreads();
  for (int s = 128; s > 0; s >>= 1) {
    if (threadIdx.x < s) red[threadIdx.x] |= red[threadIdx.x + s];
    __syncthreads();
  }
  if (threadIdx.x == 0) flag[0] = red[0];  // nonzero => int32 layout
}

// Decode edge_index into int32 src/tgt and accumulate in-degree (int).
__global__ void k_decode(const unsigned int* __restrict__ w,
                         const unsigned int* __restrict__ flag, int E,
                         int* __restrict__ src, int* __restrict__ tgt,
                         int* __restrict__ deg) {
  int e = blockIdx.x * 256 + threadIdx.x;
  if (e >= E) return;
  int s, t;
  if (flag[0]) {          // int32: [src[0..E), tgt[0..E)]
    s = (int)w[e];
    t = (int)w[E + e];
  } else {                // int64: low words at 2*elem
    s = (int)w[2 * e];
    t = (int)w[2 * (E + e)];
  }
  src[e] = s;
  tgt[e] = t;
  atomicAdd(deg + t, 1);
}

// Exclusive scan of deg[N] -> rowptr[N+1] AND cursor[N] (fill cursors).
__global__ __launch_bounds__(1024) void k_scan(const int* __restrict__ deg,
                                               int* __restrict__ rowptr,
                                               int* __restrict__ cursor, int N) {
  __shared__ int buf[1024];
  int tid = threadIdx.x;
  int chunk = (N + 1023) / 1024;
  int lo = tid * chunk;
  int hi = lo + chunk; if (hi > N) hi = N;
  int s = 0;
  for (int i = lo; i < hi; ++i) s += deg[i];
  buf[tid] = s;
  __syncthreads();
  for (int off = 1; off < 1024; off <<= 1) {
    int t = (tid >= off) ? buf[tid - off] : 0;
    __syncthreads();
    buf[tid] += t;
    __syncthreads();
  }
  int run = buf[tid] - s;  // exclusive prefix of this chunk
  for (int i = lo; i < hi; ++i) {
    rowptr[i] = run; cursor[i] = run; run += deg[i];
  }
  if (tid == 1023) rowptr[N] = buf[1023];
}

// CSR fill: cursor pre-initialized to rowptr.
__global__ void k_fill(const int* __restrict__ src, const int* __restrict__ tgt,
                       int* __restrict__ cursor, int* __restrict__ csrc, int E) {
  int e = blockIdx.x * 256 + threadIdx.x;
  if (e >= E) return;
  int pos = atomicAdd(cursor + tgt[e], 1);
  csrc[pos] = src[e];
}

// ---------------------------------------------------------------------------
// Y0 = X @ W0, Y1 = X @ W1.  X:[N,K], W0/W1:[K,64].  Block: 256 thr,
// 32 rows x 128 cols per block. Inner loop: float4-k4 form (all LDS reads
// are b128).
template <int K>
__global__ __launch_bounds__(256) void k_gemm(
    const float* __restrict__ X, const float* __restrict__ W0,
    const float* __restrict__ W1, float* __restrict__ Y0,
    float* __restrict__ Y1, int N) {
  __shared__ float Wl[64][128];   // 32 KB
  __shared__ float Xs[32][64];    // 8 KB
  const int tid = threadIdx.x;
  const int tx = tid & 31;        // col group: cols tx*4..tx*4+3
  const int ty = tid >> 5;        // row slot: rows ty + 8*i
  const int row0 = blockIdx.x * 32;

  float acc[4][4];
#pragma unroll
  for (int i = 0; i < 4; ++i)
#pragma unroll
    for (int c = 0; c < 4; ++c) acc[i][c] = 0.0f;

  for (int kc = 0; kc < K; kc += 64) {
#pragma unroll
    for (int q = 0; q < 8; ++q) {
      int f = tid + 256 * q;
      int kk = f >> 5, c4 = f & 31;
      const float* sw = (c4 < 16) ? (W0 + (size_t)(kc + kk) * 64 + c4 * 4)
                                  : (W1 + (size_t)(kc + kk) * 64 + (c4 - 16) * 4);
      float4 v = *(const float4*)sw;
      *(float4*)&Wl[kk][c4 * 4] = v;
    }
#pragma unroll
    for (int q = 0; q < 2; ++q) {
      int f = tid + 256 * q;
      int r = f >> 4, k4 = f & 15;
      float4 v = *(const float4*)(X + (size_t)(row0 + r) * K + kc + k4 * 4);
      *(float4*)&Xs[r][k4 * 4] = v;
    }
    __syncthreads();
    for (int k4 = 0; k4 < 64; k4 += 4) {
      float4 arow[4];
#pragma unroll
      for (int i = 0; i < 4; ++i) arow[i] = *(const float4*)&Xs[ty + 8 * i][k4];
#pragma unroll
      for (int kk = 0; kk < 4; ++kk) {
        float4 wv = *(const float4*)&Wl[k4 + kk][tx * 4];
#pragma unroll
        for (int i = 0; i < 4; ++i) {
          float a = (&arow[i].x)[kk];
          acc[i][0] = fmaf(a, wv.x, acc[i][0]);
          acc[i][1] = fmaf(a, wv.y, acc[i][1]);
          acc[i][2] = fmaf(a, wv.z, acc[i][2]);
          acc[i][3] = fmaf(a, wv.w, acc[i][3]);
        }
      }
    }
    __syncthreads();
  }
#pragma unroll
  for (int i = 0; i < 4; ++i) {
    int r = row0 + ty + 8 * i;
    float4 v = make_float4(acc[i][0], acc[i][1], acc[i][2], acc[i][3]);
    if (tx < 16)
      *(float4*)(Y0 + (size_t)r * 64 + tx * 4) = v;
    else
      *(float4*)(Y1 + (size_t)r * 64 + (tx - 16) * 4) = v;
  }
}

// Single-output GEMM: Y = X @ W.  X:[N,64], W:[64,64]. 64 rows/block.
__global__ __launch_bounds__(256) void k_gemm1(const float* __restrict__ X,
                                               const float* __restrict__ W,
                                               float* __restrict__ Y, int N) {
  __shared__ float sW[64][68];
  __shared__ float sX[64][68];
  const int tid = threadIdx.x;
  const int tx = tid & 15, ty = tid >> 4;
  const int row0 = blockIdx.x * 64;
#pragma unroll
  for (int q = 0; q < 4; ++q) {
    int f = tid + 256 * q;
    int r = f >> 4, c4 = f & 15;
    *(float4*)&sW[r][c4 * 4] = *(const float4*)(W + (size_t)r * 64 + c4 * 4);
    int xr = row0 + r; if (xr >= N) xr = N - 1;
    *(float4*)&sX[r][c4 * 4] = *(const float4*)(X + (size_t)xr * 64 + c4 * 4);
  }
  __syncthreads();
  float acc[4][4];
#pragma unroll
  for (int i = 0; i < 4; ++i)
#pragma unroll
    for (int c = 0; c < 4; ++c) acc[i][c] = 0.0f;
  for (int k4 = 0; k4 < 64; k4 += 4) {
    float4 arow[4];
#pragma unroll
    for (int i = 0; i < 4; ++i) arow[i] = *(const float4*)&sX[ty * 4 + i][k4];
#pragma unroll
    for (int kk = 0; kk < 4; ++kk) {
      float4 wv = *(const float4*)&sW[k4 + kk][tx * 4];
#pragma unroll
      for (int i = 0; i < 4; ++i) {
        float a = (&arow[i].x)[kk];
        acc[i][0] = fmaf(a, wv.x, acc[i][0]);
        acc[i][1] = fmaf(a, wv.y, acc[i][1]);
        acc[i][2] = fmaf(a, wv.z, acc[i][2]);
        acc[i][3] = fmaf(a, wv.w, acc[i][3]);
      }
    }
  }
#pragma unroll
  for (int i = 0; i < 4; ++i) {
    int r = row0 + ty * 4 + i;
    if (r < N)
      *(float4*)(Y + (size_t)r * 64 + tx * 4) =
          make_float4(acc[i][0], acc[i][1], acc[i][2], acc[i][3]);
  }
}

// W25T (bf16, [n][k] n-major) = (We2 @ Wo1)^T; We1T (bf16, [n][k], K padded
// 16->32 with zeros); cvec = be2 @ Wo1 + bo1. One block.
__global__ void k_prep(const float* __restrict__ We2, const float* __restrict__ Wo1,
                       const float* __restrict__ be2, const float* __restrict__ bo1,
                       const float* __restrict__ We1,
                       unsigned short* __restrict__ W25T,
                       unsigned short* __restrict__ We1T,
                       float* __restrict__ cvec) {
  int tid = threadIdx.x;
  for (int idx = tid; idx < 4096; idx += 256) {
    int n = idx >> 6, k = idx & 63;
    float s = 0.f;
    for (int m = 0; m < 64; ++m) s = fmaf(We2[k * 64 + m], Wo1[m * 64 + n], s);
    W25T[n * 64 + k] = f2bf(s);
  }
  for (int idx = tid; idx < 2048; idx += 256) {
    int n = idx >> 5, k = idx & 31;
    We1T[n * 32 + k] = (k < 16) ? f2bf(We1[k * 64 + n]) : (unsigned short)0;
  }
  if (tid < 64) {
    float s = bo1[tid];
    for (int m = 0; m < 64; ++m) s = fmaf(be2[m], Wo1[m * 64 + tid], s);
    cvec[tid] = s;
  }
}

// CSR aggregate fused with epilogue: H = relu(sum/deg + bias + Yr).
// Wave per node, lane = feature; 4-way unroll.
__global__ __launch_bounds__(256) void k_agg(
    const float* __restrict__ Y, const int* __restrict__ rowptr,
    const int* __restrict__ csrc, const float* __restrict__ bias,
    const float* __restrict__ Yr, float* __restrict__ H, int N) {
  int node = (blockIdx.x * 256 + threadIdx.x) >> 6;
  int j = threadIdx.x & 63;
  if (node >= N) return;
  int beg = rowptr[node], end = rowptr[node + 1];
  float a0 = 0.f, a1 = 0.f, a2 = 0.f, a3 = 0.f;
  int e = beg;
  for (; e + 4 <= end; e += 4) {
    int s0 = csrc[e], s1 = csrc[e + 1], s2 = csrc[e + 2], s3 = csrc[e + 3];
    a0 += Y[(size_t)s0 * 64 + j];
    a1 += Y[(size_t)s1 * 64 + j];
    a2 += Y[(size_t)s2 * 64 + j];
    a3 += Y[(size_t)s3 * 64 + j];
  }
  for (; e < end; ++e) a0 += Y[(size_t)csrc[e] * 64 + j];
  float cdeg = (float)(end - beg);
  if (cdeg < 1.f) cdeg = 1.f;
  float v = ((a0 + a1) + (a2 + a3)) / cdeg + bias[j] + Yr[(size_t)node * 64 + j];
  H[(size_t)node * 64 + j] = fmaxf(v, 0.f);
}

// ---------------------------------------------------------------------------
// MFMA edge pipeline. Each WAVE independently processes 16-edge tiles
// (no block barriers in the loop). Per tile:
//   t1 = relu(EA @ We1 + be1)        1 mfma_16x16x32 per 16-col tile (K pad 32)
//   acc = cvec + G[src]+G[tgt] + t1 @ W25     2 mfma per 16-col tile (K=64)
//   out = sigmoid(relu(acc) . Wo2 + bo2)      shfl reduce over 16 lanes
// B-fragments (We1T, W25T bf16) persistent in REGISTERS; t1 C->A layout
// transform via per-wave LDS roundtrip.
// MFMA layouts (gfx950, verified): A[m=lane&15][k=(lane>>4)*8+j],
// B[k=(lane>>4)*8+j][n=lane&15], C/D col=lane&15, row=(lane>>4)*4+reg.
// R4 BUG FIXED: sT1 row stride was 40 (< 64 features) -> rows overlapped,
// corrupting GEMM2's A operand for k>=40. Now stride 72 ushorts (144 B:
// keeps every short8 read 16B-aligned; banks ~2-way only).
#define T1_STRIDE 72
#define EA_STRIDE 40
#define WAVE_LDS (EA_STRIDE * 16 + T1_STRIDE * 16)   // 1792 ushorts
__global__ __launch_bounds__(256) void k_edge3(
    const float* __restrict__ eattr, const int* __restrict__ src,
    const int* __restrict__ tgt, const float* __restrict__ G,
    const unsigned short* __restrict__ We1T,
    const unsigned short* __restrict__ W25T,
    const float* __restrict__ cvec, const float* __restrict__ be1,
    const float* __restrict__ Wo2, const float* __restrict__ bo2,
    float* __restrict__ out, int E, int nT, int nWaves) {
  __shared__ unsigned short lds[4 * WAVE_LDS];
  const int tid = threadIdx.x;
  const int wid = tid >> 6, lane = tid & 63;
  const int m = lane & 15, q = lane >> 4;
  unsigned short* sEA = lds + wid * WAVE_LDS;
  unsigned short* sT1 = sEA + EA_STRIDE * 16;

  // persistent B-fragments + per-lane constants
  short8 bWe1[4], bW25[4][2];
  float cv[4], wo2v[4], be1v[4];
#pragma unroll
  for (int nt = 0; nt < 4; ++nt) {
    int n = nt * 16 + m;
    bWe1[nt] = *(const short8*)(We1T + n * 32 + q * 8);
    bW25[nt][0] = *(const short8*)(W25T + n * 64 + q * 8);
    bW25[nt][1] = *(const short8*)(W25T + n * 64 + 32 + q * 8);
    cv[nt] = cvec[n];
    wo2v[nt] = Wo2[n];
    be1v[nt] = be1[n];
  }
  const float b_out = bo2[0];

  // zero EA pad region (cols 16..31) once; only own wave touches it
  {
    int r = lane >> 2, cc = (lane & 3) * 4;
    uint2 z; z.x = 0u; z.y = 0u;
    *(uint2*)(sEA + r * EA_STRIDE + 16 + cc) = z;
  }

  for (int t = blockIdx.x * 4 + wid; t < nT; t += nWaves) {
    const int base = t * 16;
    // ---- stage EA (16 edges x 16 f32 -> bf16) + endpoint indices
    int er = base + (lane >> 2); if (er >= E) er = E - 1;
    float4 ev = *(const float4*)(eattr + (size_t)er * 16 + (lane & 3) * 4);
    int il = base + m; if (il >= E) il = E - 1;
    int my_idx = (lane < 16) ? src[il] : ((lane < 32) ? tgt[il] : 0);
    {
      uint2 pk;
      pk.x = (unsigned int)f2bf(ev.x) | ((unsigned int)f2bf(ev.y) << 16);
      pk.y = (unsigned int)f2bf(ev.z) | ((unsigned int)f2bf(ev.w) << 16);
      *(uint2*)(sEA + (lane >> 2) * EA_STRIDE + (lane & 3) * 4) = pk;
    }
    // ---- gather G rows, init acc = cvec + G[src]+G[tgt]  (C layout)
    int rs[4], rt[4];
#pragma unroll
    for (int r = 0; r < 4; ++r) {
      rs[r] = __shfl(my_idx, q * 4 + r, 64);
      rt[r] = __shfl(my_idx, 16 + q * 4 + r, 64);
    }
    f32x4 acc[4];
#pragma unroll
    for (int nt = 0; nt < 4; ++nt) {
      int c = nt * 16 + m;
#pragma unroll
      for (int r = 0; r < 4; ++r)
        acc[nt][r] = cv[nt] + G[(size_t)rs[r] * 64 + c] + G[(size_t)rt[r] * 64 + c];
    }
    // ---- GEMM1: t1 = relu(EA @ We1 + be1)
    short8 aEA = *(short8*)(sEA + m * EA_STRIDE + q * 8);
    f32x4 t1[4];
#pragma unroll
    for (int nt = 0; nt < 4; ++nt) {
      f32x4 cinit; cinit[0] = be1v[nt]; cinit[1] = be1v[nt];
      cinit[2] = be1v[nt]; cinit[3] = be1v[nt];
      t1[nt] = __builtin_amdgcn_mfma_f32_16x16x32_bf16(aEA, bWe1[nt], cinit, 0, 0, 0);
    }
    // relu + cvt + write to sT1 (C layout -> memory row-major [edge][feat])
#pragma unroll
    for (int nt = 0; nt < 4; ++nt)
#pragma unroll
      for (int r = 0; r < 4; ++r)
        sT1[(q * 4 + r) * T1_STRIDE + nt * 16 + m] = f2bf(fmaxf(t1[nt][r], 0.f));
    // ---- GEMM2: acc += t1 @ W25   (A frags from sT1, K=64 in 2 halves)
    short8 aT0 = *(short8*)(sT1 + m * T1_STRIDE + q * 8);
    short8 aT1 = *(short8*)(sT1 + m * T1_STRIDE + 32 + q * 8);
#pragma unroll
    for (int nt = 0; nt < 4; ++nt) {
      acc[nt] = __builtin_amdgcn_mfma_f32_16x16x32_bf16(aT0, bW25[nt][0], acc[nt], 0, 0, 0);
      acc[nt] = __builtin_amdgcn_mfma_f32_16x16x32_bf16(aT1, bW25[nt][1], acc[nt], 0, 0, 0);
    }
    // ---- epilogue: p[r] = sum_c relu(acc)*Wo2[c]; reduce across 16 lanes
    float p[4];
#pragma unroll
    for (int r = 0; r < 4; ++r) {
      p[r] = fmaxf(acc[0][r], 0.f) * wo2v[0] + fmaxf(acc[1][r], 0.f) * wo2v[1] +
             fmaxf(acc[2][r], 0.f) * wo2v[2] + fmaxf(acc[3][r], 0.f) * wo2v[3];
    }
#pragma unroll
    for (int msk = 1; msk <= 8; msk <<= 1) {
#pragma unroll
      for (int r = 0; r < 4; ++r) p[r] += __shfl_xor(p[r], msk, 64);
    }
    if (m == 0) {
#pragma unroll
      for (int r = 0; r < 4; ++r) {
        int row = base + q * 4 + r;
        if (row < E) out[row] = 1.f / (1.f + __expf(-(p[r] + b_out)));
      }
    }
  }
}

// ---------------------------------------------------------------------------
extern "C" void kernel_launch(void* const* d_in, const int* in_sizes, int n_in,
                              void* d_out, int out_size, void* d_ws, size_t ws_size,
                              hipStream_t stream) {
  const float* x     = (const float*)d_in[0];
  const unsigned int* eidx = (const unsigned int*)d_in[1];
  const float* eattr = (const float*)d_in[2];
  const float* We1 = (const float*)d_in[3];
  const float* be1 = (const float*)d_in[4];
  const float* We2 = (const float*)d_in[5];
  const float* be2 = (const float*)d_in[6];
  const float* Wl0 = (const float*)d_in[7];
  const float* bl0 = (const float*)d_in[8];
  const float* Wr0 = (const float*)d_in[9];
  const float* Wl1 = (const float*)d_in[10];
  const float* bl1 = (const float*)d_in[11];
  const float* Wr1 = (const float*)d_in[12];
  const float* Wo1 = (const float*)d_in[13];
  const float* bo1 = (const float*)d_in[14];
  const float* Wo2 = (const float*)d_in[15];
  const float* bo2 = (const float*)d_in[16];

  const int N = in_sizes[0] / 128;   // 100000
  const int E = in_sizes[2] / 16;    // 1000000
  float* out = (float*)d_out;

  char* ws = (char*)d_ws;
  size_t off = 0;
  auto alloc = [&](size_t bytes) {
    char* p = ws + off;
    off += (bytes + 255) & ~(size_t)255;
    return p;
  };
  unsigned int* flag = (unsigned int*)alloc(256);
  int* src    = (int*)alloc((size_t)E * 4);
  int* tgt    = (int*)alloc((size_t)E * 4);
  int* deg    = (int*)alloc((size_t)N * 4);
  int* rowptr = (int*)alloc((size_t)(N + 1) * 4);
  int* cursor = (int*)alloc((size_t)N * 4);
  int* csrc   = (int*)alloc((size_t)E * 4);
  float* Hb   = (float*)alloc((size_t)N * 64 * 4);
  float* Yl   = (float*)alloc((size_t)N * 64 * 4);
  float* Yr   = (float*)alloc((size_t)N * 64 * 4);
  float* G    = (float*)alloc((size_t)N * 64 * 4);
  unsigned short* W25T = (unsigned short*)alloc(64 * 64 * 2);
  unsigned short* We1T = (unsigned short*)alloc(64 * 32 * 2);
  float* cvec = (float*)alloc(64 * 4);
  (void)ws_size; (void)n_in; (void)out_size;

  hipMemsetAsync(deg, 0, (size_t)N * 4, stream);

  k_flag<<<1, 256, 0, stream>>>(eidx, 8192, flag);
  k_decode<<<(E + 255) / 256, 256, 0, stream>>>(eidx, flag, E, src, tgt, deg);
  k_scan<<<1, 1024, 0, stream>>>(deg, rowptr, cursor, N);
  k_fill<<<(E + 255) / 256, 256, 0, stream>>>(src, tgt, cursor, csrc, E);
  k_prep<<<1, 256, 0, stream>>>(We2, Wo1, be2, bo1, We1, W25T, We1T, cvec);

  // Layer 0 (project-then-aggregate: mean is linear)
  k_gemm<128><<<N / 32, 256, 0, stream>>>(x, Wl0, Wr0, Yl, Yr, N);
  k_agg<<<(N + 3) / 4, 256, 0, stream>>>(Yl, rowptr, csrc, bl0, Yr, Hb, N);

  // Layer 1
  k_gemm<64><<<N / 32, 256, 0, stream>>>(Hb, Wl1, Wr1, Yl, Yr, N);
  k_agg<<<(N + 3) / 4, 256, 0, stream>>>(Yl, rowptr, csrc, bl1, Yr, Hb, N);

  // G = H2 @ Wo1
  k_gemm1<<<(N + 63) / 64, 256, 0, stream>>>(Hb, Wo1, G, N);

  // MFMA edge pipeline: wave-independent 16-edge tiles
  const int nT = (E + 15) / 16;
  const int blocks = 1024;
  k_edge3<<<blocks, 256, 0, stream>>>(eattr, src, tgt, G, We1T, W25T, cvec,
                                      be1, Wo2, bo2, out, E, nT, blocks * 4);
}

// Round 6
// 614.236 us; speedup vs baseline: 1.9939x; 1.3634x over previous
//
#include <hip/hip_runtime.h>
#include <math.h>

typedef __attribute__((ext_vector_type(8))) short short8;
typedef __attribute__((ext_vector_type(4))) float f32x4;

static __device__ __forceinline__ unsigned short f2bf(float f) {
  union { float f; unsigned int u; } x; x.f = f;
  unsigned int r = x.u + 0x7fffu + ((x.u >> 16) & 1u);  // RNE
  return (unsigned short)(r >> 16);
}

// ---------------------------------------------------------------------------
// int64-vs-int32 edge_index detection: OR of odd words of the first 8192
// elements. int64 (little-endian) => hi words all zero => flag==0.
__global__ void k_flag(const unsigned int* __restrict__ w, int nSample,
                       unsigned int* __restrict__ flag) {
  __shared__ unsigned int red[256];
  unsigned int v = 0;
  for (int i = threadIdx.x; i < nSample; i += 256) v |= w[2 * i + 1];
  red[threadIdx.x] = v;
  __syncthreads();
  for (int s = 128; s > 0; s >>= 1) {
    if (threadIdx.x < s) red[threadIdx.x] |= red[threadIdx.x + s];
    __syncthreads();
  }
  if (threadIdx.x == 0) flag[0] = red[0];  // nonzero => int32 layout
}

// Decode edge_index into int32 src/tgt and accumulate in-degree (int).
__global__ void k_decode(const unsigned int* __restrict__ w,
                         const unsigned int* __restrict__ flag, int E,
                         int* __restrict__ src, int* __restrict__ tgt,
                         int* __restrict__ deg) {
  int e = blockIdx.x * 256 + threadIdx.x;
  if (e >= E) return;
  int s, t;
  if (flag[0]) {          // int32: [src[0..E), tgt[0..E)]
    s = (int)w[e];
    t = (int)w[E + e];
  } else {                // int64: low words at 2*elem
    s = (int)w[2 * e];
    t = (int)w[2 * (E + e)];
  }
  src[e] = s;
  tgt[e] = t;
  atomicAdd(deg + t, 1);
}

// ---------------------------------------------------------------------------
// Hierarchical exclusive scan of deg[padN] (padN multiple of 2048, pad=0).
// Phase 1: per-block (2048-chunk) sums.
__global__ __launch_bounds__(256) void k_scan1(const int* __restrict__ deg,
                                               int* __restrict__ bsum) {
  __shared__ int wsum[4];
  const int tid = threadIdx.x, lane = tid & 63, wid = tid >> 6;
  const int base = blockIdx.x * 2048 + tid * 8;
  int4 v0 = *(const int4*)(deg + base);
  int4 v1 = *(const int4*)(deg + base + 4);
  int s = v0.x + v0.y + v0.z + v0.w + v1.x + v1.y + v1.z + v1.w;
#pragma unroll
  for (int off = 1; off < 64; off <<= 1) s += __shfl_xor(s, off, 64);
  if (lane == 0) wsum[wid] = s;
  __syncthreads();
  if (tid == 0) bsum[blockIdx.x] = wsum[0] + wsum[1] + wsum[2] + wsum[3];
}

// Phase 2: exclusive scan of block sums (nB <= 64), one wave.
__global__ void k_scan2(const int* __restrict__ bsum, int* __restrict__ boff,
                        int nB, int* __restrict__ rowptrN) {
  int lane = threadIdx.x;
  int v = (lane < nB) ? bsum[lane] : 0;
  int incl = v;
#pragma unroll
  for (int off = 1; off < 64; off <<= 1) {
    int t = __shfl_up(incl, off, 64);
    if (lane >= off) incl += t;
  }
  if (lane < nB) boff[lane] = incl - v;
  if (lane == 63) *rowptrN = incl;   // total = E
}

// Phase 3: per-block exclusive scan + block offset -> rowptr AND cursor.
__global__ __launch_bounds__(256) void k_scan3(const int* __restrict__ deg,
                                               const int* __restrict__ boff,
                                               int* __restrict__ rowptr,
                                               int* __restrict__ cursor) {
  __shared__ int wsum[4];
  const int tid = threadIdx.x, lane = tid & 63, wid = tid >> 6;
  const int base = blockIdx.x * 2048 + tid * 8;
  int4 v0 = *(const int4*)(deg + base);
  int4 v1 = *(const int4*)(deg + base + 4);
  int e[8] = {v0.x, v0.y, v0.z, v0.w, v1.x, v1.y, v1.z, v1.w};
  int s = e[0] + e[1] + e[2] + e[3] + e[4] + e[5] + e[6] + e[7];
  int incl = s;
#pragma unroll
  for (int off = 1; off < 64; off <<= 1) {
    int t = __shfl_up(incl, off, 64);
    if (lane >= off) incl += t;
  }
  if (lane == 63) wsum[wid] = incl;
  __syncthreads();
  int run = boff[blockIdx.x] + (incl - s);
  for (int w = 0; w < wid; ++w) run += wsum[w];
  int o[8];
#pragma unroll
  for (int i = 0; i < 8; ++i) { o[i] = run; run += e[i]; }
  int4 a = make_int4(o[0], o[1], o[2], o[3]);
  int4 b = make_int4(o[4], o[5], o[6], o[7]);
  *(int4*)(rowptr + base) = a;  *(int4*)(rowptr + base + 4) = b;
  *(int4*)(cursor + base) = a;  *(int4*)(cursor + base + 4) = b;
}

// CSR fill: cursor pre-initialized to rowptr.
__global__ void k_fill(const int* __restrict__ src, const int* __restrict__ tgt,
                       int* __restrict__ cursor, int* __restrict__ csrc, int E) {
  int e = blockIdx.x * 256 + threadIdx.x;
  if (e >= E) return;
  int pos = atomicAdd(cursor + tgt[e], 1);
  csrc[pos] = src[e];
}

// ---------------------------------------------------------------------------
// Y0 = X @ W0, Y1 = X @ W1.  X:[N,K], W0/W1:[K,64].  Block: 256 thr,
// 32 rows x 128 cols per block. Inner loop: float4-k4 form (all LDS reads
// are b128).
template <int K>
__global__ __launch_bounds__(256) void k_gemm(
    const float* __restrict__ X, const float* __restrict__ W0,
    const float* __restrict__ W1, float* __restrict__ Y0,
    float* __restrict__ Y1, int N) {
  __shared__ float Wl[64][128];   // 32 KB
  __shared__ float Xs[32][64];    // 8 KB
  const int tid = threadIdx.x;
  const int tx = tid & 31;        // col group: cols tx*4..tx*4+3
  const int ty = tid >> 5;        // row slot: rows ty + 8*i
  const int row0 = blockIdx.x * 32;

  float acc[4][4];
#pragma unroll
  for (int i = 0; i < 4; ++i)
#pragma unroll
    for (int c = 0; c < 4; ++c) acc[i][c] = 0.0f;

  for (int kc = 0; kc < K; kc += 64) {
#pragma unroll
    for (int q = 0; q < 8; ++q) {
      int f = tid + 256 * q;
      int kk = f >> 5, c4 = f & 31;
      const float* sw = (c4 < 16) ? (W0 + (size_t)(kc + kk) * 64 + c4 * 4)
                                  : (W1 + (size_t)(kc + kk) * 64 + (c4 - 16) * 4);
      float4 v = *(const float4*)sw;
      *(float4*)&Wl[kk][c4 * 4] = v;
    }
#pragma unroll
    for (int q = 0; q < 2; ++q) {
      int f = tid + 256 * q;
      int r = f >> 4, k4 = f & 15;
      float4 v = *(const float4*)(X + (size_t)(row0 + r) * K + kc + k4 * 4);
      *(float4*)&Xs[r][k4 * 4] = v;
    }
    __syncthreads();
    for (int k4 = 0; k4 < 64; k4 += 4) {
      float4 arow[4];
#pragma unroll
      for (int i = 0; i < 4; ++i) arow[i] = *(const float4*)&Xs[ty + 8 * i][k4];
#pragma unroll
      for (int kk = 0; kk < 4; ++kk) {
        float4 wv = *(const float4*)&Wl[k4 + kk][tx * 4];
#pragma unroll
        for (int i = 0; i < 4; ++i) {
          float a = (&arow[i].x)[kk];
          acc[i][0] = fmaf(a, wv.x, acc[i][0]);
          acc[i][1] = fmaf(a, wv.y, acc[i][1]);
          acc[i][2] = fmaf(a, wv.z, acc[i][2]);
          acc[i][3] = fmaf(a, wv.w, acc[i][3]);
        }
      }
    }
    __syncthreads();
  }
#pragma unroll
  for (int i = 0; i < 4; ++i) {
    int r = row0 + ty + 8 * i;
    float4 v = make_float4(acc[i][0], acc[i][1], acc[i][2], acc[i][3]);
    if (tx < 16)
      *(float4*)(Y0 + (size_t)r * 64 + tx * 4) = v;
    else
      *(float4*)(Y1 + (size_t)r * 64 + (tx - 16) * 4) = v;
  }
}

// Single-output GEMM: Y = X @ W.  X:[N,64], W:[64,64]. 64 rows/block.
__global__ __launch_bounds__(256) void k_gemm1(const float* __restrict__ X,
                                               const float* __restrict__ W,
                                               float* __restrict__ Y, int N) {
  __shared__ float sW[64][68];
  __shared__ float sX[64][68];
  const int tid = threadIdx.x;
  const int tx = tid & 15, ty = tid >> 4;
  const int row0 = blockIdx.x * 64;
#pragma unroll
  for (int q = 0; q < 4; ++q) {
    int f = tid + 256 * q;
    int r = f >> 4, c4 = f & 15;
    *(float4*)&sW[r][c4 * 4] = *(const float4*)(W + (size_t)r * 64 + c4 * 4);
    int xr = row0 + r; if (xr >= N) xr = N - 1;
    *(float4*)&sX[r][c4 * 4] = *(const float4*)(X + (size_t)xr * 64 + c4 * 4);
  }
  __syncthreads();
  float acc[4][4];
#pragma unroll
  for (int i = 0; i < 4; ++i)
#pragma unroll
    for (int c = 0; c < 4; ++c) acc[i][c] = 0.0f;
  for (int k4 = 0; k4 < 64; k4 += 4) {
    float4 arow[4];
#pragma unroll
    for (int i = 0; i < 4; ++i) arow[i] = *(const float4*)&sX[ty * 4 + i][k4];
#pragma unroll
    for (int kk = 0; kk < 4; ++kk) {
      float4 wv = *(const float4*)&sW[k4 + kk][tx * 4];
#pragma unroll
      for (int i = 0; i < 4; ++i) {
        float a = (&arow[i].x)[kk];
        acc[i][0] = fmaf(a, wv.x, acc[i][0]);
        acc[i][1] = fmaf(a, wv.y, acc[i][1]);
        acc[i][2] = fmaf(a, wv.z, acc[i][2]);
        acc[i][3] = fmaf(a, wv.w, acc[i][3]);
      }
    }
  }
#pragma unroll
  for (int i = 0; i < 4; ++i) {
    int r = row0 + ty * 4 + i;
    if (r < N)
      *(float4*)(Y + (size_t)r * 64 + tx * 4) =
          make_float4(acc[i][0], acc[i][1], acc[i][2], acc[i][3]);
  }
}

// W25T (bf16, [n][k]) = (We2 @ Wo1)^T; We1T (bf16, [n][k], K pad 16->32);
// cvec = be2 @ Wo1 + bo1. One block; inputs staged in LDS (was global-read
// latency-bound as a single block).
__global__ __launch_bounds__(256) void k_prep(
    const float* __restrict__ We2, const float* __restrict__ Wo1,
    const float* __restrict__ be2, const float* __restrict__ bo1,
    const float* __restrict__ We1,
    unsigned short* __restrict__ W25T, unsigned short* __restrict__ We1T,
    float* __restrict__ cvec) {
  __shared__ float sA[4096];  // We2
  __shared__ float sB[4096];  // Wo1
  int tid = threadIdx.x;
  for (int i = tid; i < 1024; i += 256) {
    *(float4*)&sA[i * 4] = *(const float4*)(We2 + i * 4);
    *(float4*)&sB[i * 4] = *(const float4*)(Wo1 + i * 4);
  }
  __syncthreads();
  for (int idx = tid; idx < 4096; idx += 256) {
    int n = idx >> 6, k = idx & 63;
    float s = 0.f;
#pragma unroll 8
    for (int m = 0; m < 64; ++m) s = fmaf(sA[k * 64 + m], sB[m * 64 + n], s);
    W25T[n * 64 + k] = f2bf(s);
  }
  for (int idx = tid; idx < 2048; idx += 256) {
    int n = idx >> 5, k = idx & 31;
    We1T[n * 32 + k] = (k < 16) ? f2bf(We1[k * 64 + n]) : (unsigned short)0;
  }
  if (tid < 64) {
    float s = bo1[tid];
#pragma unroll 8
    for (int m = 0; m < 64; ++m) s = fmaf(be2[m], sB[m * 64 + tid], s);
    cvec[tid] = s;
  }
}

// CSR aggregate fused with epilogue: H = relu(sum/deg + bias + Yr).
// Wave per node, lane = feature; 4-way unroll.
__global__ __launch_bounds__(256) void k_agg(
    const float* __restrict__ Y, const int* __restrict__ rowptr,
    const int* __restrict__ csrc, const float* __restrict__ bias,
    const float* __restrict__ Yr, float* __restrict__ H, int N) {
  int node = (blockIdx.x * 256 + threadIdx.x) >> 6;
  int j = threadIdx.x & 63;
  if (node >= N) return;
  int beg = rowptr[node], end = rowptr[node + 1];
  float a0 = 0.f, a1 = 0.f, a2 = 0.f, a3 = 0.f;
  int e = beg;
  for (; e + 4 <= end; e += 4) {
    int s0 = csrc[e], s1 = csrc[e + 1], s2 = csrc[e + 2], s3 = csrc[e + 3];
    a0 += Y[(size_t)s0 * 64 + j];
    a1 += Y[(size_t)s1 * 64 + j];
    a2 += Y[(size_t)s2 * 64 + j];
    a3 += Y[(size_t)s3 * 64 + j];
  }
  for (; e < end; ++e) a0 += Y[(size_t)csrc[e] * 64 + j];
  float cdeg = (float)(end - beg);
  if (cdeg < 1.f) cdeg = 1.f;
  float v = ((a0 + a1) + (a2 + a3)) / cdeg + bias[j] + Yr[(size_t)node * 64 + j];
  H[(size_t)node * 64 + j] = fmaxf(v, 0.f);
}

// ---------------------------------------------------------------------------
// MFMA edge pipeline. Each WAVE independently processes 16-edge tiles.
// MFMA layouts (gfx950, verified): A[m=lane&15][k=(lane>>4)*8+j],
// B[k=(lane>>4)*8+j][n=lane&15], C/D col=lane&15, row=(lane>>4)*4+reg.
#define T1_STRIDE 72
#define EA_STRIDE 40
#define WAVE_LDS (EA_STRIDE * 16 + T1_STRIDE * 16)
__global__ __launch_bounds__(256) void k_edge3(
    const float* __restrict__ eattr, const int* __restrict__ src,
    const int* __restrict__ tgt, const float* __restrict__ G,
    const unsigned short* __restrict__ We1T,
    const unsigned short* __restrict__ W25T,
    const float* __restrict__ cvec, const float* __restrict__ be1,
    const float* __restrict__ Wo2, const float* __restrict__ bo2,
    float* __restrict__ out, int E, int nT, int nWaves) {
  __shared__ unsigned short lds[4 * WAVE_LDS];
  const int tid = threadIdx.x;
  const int wid = tid >> 6, lane = tid & 63;
  const int m = lane & 15, q = lane >> 4;
  unsigned short* sEA = lds + wid * WAVE_LDS;
  unsigned short* sT1 = sEA + EA_STRIDE * 16;

  short8 bWe1[4], bW25[4][2];
  float cv[4], wo2v[4], be1v[4];
#pragma unroll
  for (int nt = 0; nt < 4; ++nt) {
    int n = nt * 16 + m;
    bWe1[nt] = *(const short8*)(We1T + n * 32 + q * 8);
    bW25[nt][0] = *(const short8*)(W25T + n * 64 + q * 8);
    bW25[nt][1] = *(const short8*)(W25T + n * 64 + 32 + q * 8);
    cv[nt] = cvec[n];
    wo2v[nt] = Wo2[n];
    be1v[nt] = be1[n];
  }
  const float b_out = bo2[0];

  {
    int r = lane >> 2, cc = (lane & 3) * 4;
    uint2 z; z.x = 0u; z.y = 0u;
    *(uint2*)(sEA + r * EA_STRIDE + 16 + cc) = z;
  }

  for (int t = blockIdx.x * 4 + wid; t < nT; t += nWaves) {
    const int base = t * 16;
    int er = base + (lane >> 2); if (er >= E) er = E - 1;
    float4 ev = *(const float4*)(eattr + (size_t)er * 16 + (lane & 3) * 4);
    int il = base + m; if (il >= E) il = E - 1;
    int my_idx = (lane < 16) ? src[il] : ((lane < 32) ? tgt[il] : 0);
    {
      uint2 pk;
      pk.x = (unsigned int)f2bf(ev.x) | ((unsigned int)f2bf(ev.y) << 16);
      pk.y = (unsigned int)f2bf(ev.z) | ((unsigned int)f2bf(ev.w) << 16);
      *(uint2*)(sEA + (lane >> 2) * EA_STRIDE + (lane & 3) * 4) = pk;
    }
    int rs[4], rt[4];
#pragma unroll
    for (int r = 0; r < 4; ++r) {
      rs[r] = __shfl(my_idx, q * 4 + r, 64);
      rt[r] = __shfl(my_idx, 16 + q * 4 + r, 64);
    }
    f32x4 acc[4];
#pragma unroll
    for (int nt = 0; nt < 4; ++nt) {
      int c = nt * 16 + m;
#pragma unroll
      for (int r = 0; r < 4; ++r)
        acc[nt][r] = cv[nt] + G[(size_t)rs[r] * 64 + c] + G[(size_t)rt[r] * 64 + c];
    }
    short8 aEA = *(short8*)(sEA + m * EA_STRIDE + q * 8);
    f32x4 t1[4];
#pragma unroll
    for (int nt = 0; nt < 4; ++nt) {
      f32x4 cinit; cinit[0] = be1v[nt]; cinit[1] = be1v[nt];
      cinit[2] = be1v[nt]; cinit[3] = be1v[nt];
      t1[nt] = __builtin_amdgcn_mfma_f32_16x16x32_bf16(aEA, bWe1[nt], cinit, 0, 0, 0);
    }
#pragma unroll
    for (int nt = 0; nt < 4; ++nt)
#pragma unroll
      for (int r = 0; r < 4; ++r)
        sT1[(q * 4 + r) * T1_STRIDE + nt * 16 + m] = f2bf(fmaxf(t1[nt][r], 0.f));
    short8 aT0 = *(short8*)(sT1 + m * T1_STRIDE + q * 8);
    short8 aT1 = *(short8*)(sT1 + m * T1_STRIDE + 32 + q * 8);
#pragma unroll
    for (int nt = 0; nt < 4; ++nt) {
      acc[nt] = __builtin_amdgcn_mfma_f32_16x16x32_bf16(aT0, bW25[nt][0], acc[nt], 0, 0, 0);
      acc[nt] = __builtin_amdgcn_mfma_f32_16x16x32_bf16(aT1, bW25[nt][1], acc[nt], 0, 0, 0);
    }
    float p[4];
#pragma unroll
    for (int r = 0; r < 4; ++r) {
      p[r] = fmaxf(acc[0][r], 0.f) * wo2v[0] + fmaxf(acc[1][r], 0.f) * wo2v[1] +
             fmaxf(acc[2][r], 0.f) * wo2v[2] + fmaxf(acc[3][r], 0.f) * wo2v[3];
    }
#pragma unroll
    for (int msk = 1; msk <= 8; msk <<= 1) {
#pragma unroll
      for (int r = 0; r < 4; ++r) p[r] += __shfl_xor(p[r], msk, 64);
    }
    if (m == 0) {
#pragma unroll
      for (int r = 0; r < 4; ++r) {
        int row = base + q * 4 + r;
        if (row < E) out[row] = 1.f / (1.f + __expf(-(p[r] + b_out)));
      }
    }
  }
}

// ---------------------------------------------------------------------------
extern "C" void kernel_launch(void* const* d_in, const int* in_sizes, int n_in,
                              void* d_out, int out_size, void* d_ws, size_t ws_size,
                              hipStream_t stream) {
  const float* x     = (const float*)d_in[0];
  const unsigned int* eidx = (const unsigned int*)d_in[1];
  const float* eattr = (const float*)d_in[2];
  const float* We1 = (const float*)d_in[3];
  const float* be1 = (const float*)d_in[4];
  const float* We2 = (const float*)d_in[5];
  const float* be2 = (const float*)d_in[6];
  const float* Wl0 = (const float*)d_in[7];
  const float* bl0 = (const float*)d_in[8];
  const float* Wr0 = (const float*)d_in[9];
  const float* Wl1 = (const float*)d_in[10];
  const float* bl1 = (const float*)d_in[11];
  const float* Wr1 = (const float*)d_in[12];
  const float* Wo1 = (const float*)d_in[13];
  const float* bo1 = (const float*)d_in[14];
  const float* Wo2 = (const float*)d_in[15];
  const float* bo2 = (const float*)d_in[16];

  const int N = in_sizes[0] / 128;   // 100000
  const int E = in_sizes[2] / 16;    // 1000000
  const int padN = (N + 2047) & ~2047;
  const int nB = padN / 2048;
  float* out = (float*)d_out;

  char* ws = (char*)d_ws;
  size_t off = 0;
  auto alloc = [&](size_t bytes) {
    char* p = ws + off;
    off += (bytes + 255) & ~(size_t)255;
    return p;
  };
  unsigned int* flag = (unsigned int*)alloc(256);
  int* src    = (int*)alloc((size_t)E * 4);
  int* tgt    = (int*)alloc((size_t)E * 4);
  int* deg    = (int*)alloc((size_t)padN * 4);
  int* rowptr = (int*)alloc((size_t)(padN + 64) * 4);
  int* cursor = (int*)alloc((size_t)padN * 4);
  int* bsum   = (int*)alloc(64 * 4);
  int* boff   = (int*)alloc(64 * 4);
  int* csrc   = (int*)alloc((size_t)E * 4);
  float* Hb   = (float*)alloc((size_t)N * 64 * 4);
  float* Yl   = (float*)alloc((size_t)N * 64 * 4);
  float* Yr   = (float*)alloc((size_t)N * 64 * 4);
  float* G    = (float*)alloc((size_t)N * 64 * 4);
  unsigned short* W25T = (unsigned short*)alloc(64 * 64 * 2);
  unsigned short* We1T = (unsigned short*)alloc(64 * 32 * 2);
  float* cvec = (float*)alloc(64 * 4);
  (void)ws_size; (void)n_in; (void)out_size;

  hipMemsetAsync(deg, 0, (size_t)padN * 4, stream);

  k_flag<<<1, 256, 0, stream>>>(eidx, 8192, flag);
  k_decode<<<(E + 255) / 256, 256, 0, stream>>>(eidx, flag, E, src, tgt, deg);
  k_scan1<<<nB, 256, 0, stream>>>(deg, bsum);
  k_scan2<<<1, 64, 0, stream>>>(bsum, boff, nB, rowptr + N);
  k_scan3<<<nB, 256, 0, stream>>>(deg, boff, rowptr, cursor);
  k_fill<<<(E + 255) / 256, 256, 0, stream>>>(src, tgt, cursor, csrc, E);
  k_prep<<<1, 256, 0, stream>>>(We2, Wo1, be2, bo1, We1, W25T, We1T, cvec);

  // Layer 0 (project-then-aggregate: mean is linear)
  k_gemm<128><<<N / 32, 256, 0, stream>>>(x, Wl0, Wr0, Yl, Yr, N);
  k_agg<<<(N + 3) / 4, 256, 0, stream>>>(Yl, rowptr, csrc, bl0, Yr, Hb, N);

  // Layer 1
  k_gemm<64><<<N / 32, 256, 0, stream>>>(Hb, Wl1, Wr1, Yl, Yr, N);
  k_agg<<<(N + 3) / 4, 256, 0, stream>>>(Yl, rowptr, csrc, bl1, Yr, Hb, N);

  // G = H2 @ Wo1
  k_gemm1<<<(N + 63) / 64, 256, 0, stream>>>(Hb, Wo1, G, N);

  // MFMA edge pipeline: wave-independent 16-edge tiles
  const int nT = (E + 15) / 16;
  const int blocks = 1024;
  k_edge3<<<blocks, 256, 0, stream>>>(eattr, src, tgt, G, We1T, W25T, cvec,
                                      be1, Wo2, bo2, out, E, nT, blocks * 4);
}

// Round 7
// 591.627 us; speedup vs baseline: 2.0701x; 1.0382x over previous
//
#include <hip/hip_runtime.h>
#include <math.h>

typedef __attribute__((ext_vector_type(8))) short short8;
typedef __attribute__((ext_vector_type(4))) float f32x4;

static __device__ __forceinline__ unsigned short f2bf(float f) {
  union { float f; unsigned int u; } x; x.f = f;
  unsigned int r = x.u + 0x7fffu + ((x.u >> 16) & 1u);  // RNE
  return (unsigned short)(r >> 16);
}
static __device__ __forceinline__ float bf2f(unsigned int u) {
  union { unsigned int u; float f; } x; x.u = u << 16; return x.f;
}

// ---------------------------------------------------------------------------
// int64-vs-int32 edge_index detection: OR of odd words of the first 8192
// elements. int64 (little-endian) => hi words all zero => flag==0.
__global__ void k_flag(const unsigned int* __restrict__ w, int nSample,
                       unsigned int* __restrict__ flag) {
  __shared__ unsigned int red[256];
  unsigned int v = 0;
  for (int i = threadIdx.x; i < nSample; i += 256) v |= w[2 * i + 1];
  red[threadIdx.x] = v;
  __syncthreads();
  for (int s = 128; s > 0; s >>= 1) {
    if (threadIdx.x < s) red[threadIdx.x] |= red[threadIdx.x + s];
    __syncthreads();
  }
  if (threadIdx.x == 0) flag[0] = red[0];  // nonzero => int32 layout
}

// Decode edge_index into int32 src/tgt and accumulate in-degree (int).
__global__ void k_decode(const unsigned int* __restrict__ w,
                         const unsigned int* __restrict__ flag, int E,
                         int* __restrict__ src, int* __restrict__ tgt,
                         int* __restrict__ deg) {
  int e = blockIdx.x * 256 + threadIdx.x;
  if (e >= E) return;
  int s, t;
  if (flag[0]) {          // int32: [src[0..E), tgt[0..E)]
    s = (int)w[e];
    t = (int)w[E + e];
  } else {                // int64: low words at 2*elem
    s = (int)w[2 * e];
    t = (int)w[2 * (E + e)];
  }
  src[e] = s;
  tgt[e] = t;
  atomicAdd(deg + t, 1);
}

// ---------------------------------------------------------------------------
// Hierarchical exclusive scan of deg[padN] (padN multiple of 2048, pad=0).
__global__ __launch_bounds__(256) void k_scan1(const int* __restrict__ deg,
                                               int* __restrict__ bsum) {
  __shared__ int wsum[4];
  const int tid = threadIdx.x, lane = tid & 63, wid = tid >> 6;
  const int base = blockIdx.x * 2048 + tid * 8;
  int4 v0 = *(const int4*)(deg + base);
  int4 v1 = *(const int4*)(deg + base + 4);
  int s = v0.x + v0.y + v0.z + v0.w + v1.x + v1.y + v1.z + v1.w;
#pragma unroll
  for (int off = 1; off < 64; off <<= 1) s += __shfl_xor(s, off, 64);
  if (lane == 0) wsum[wid] = s;
  __syncthreads();
  if (tid == 0) bsum[blockIdx.x] = wsum[0] + wsum[1] + wsum[2] + wsum[3];
}

__global__ void k_scan2(const int* __restrict__ bsum, int* __restrict__ boff,
                        int nB, int* __restrict__ rowptrN) {
  int lane = threadIdx.x;
  int v = (lane < nB) ? bsum[lane] : 0;
  int incl = v;
#pragma unroll
  for (int off = 1; off < 64; off <<= 1) {
    int t = __shfl_up(incl, off, 64);
    if (lane >= off) incl += t;
  }
  if (lane < nB) boff[lane] = incl - v;
  if (lane == 63) *rowptrN = incl;   // total = E
}

__global__ __launch_bounds__(256) void k_scan3(const int* __restrict__ deg,
                                               const int* __restrict__ boff,
                                               int* __restrict__ rowptr,
                                               int* __restrict__ cursor) {
  __shared__ int wsum[4];
  const int tid = threadIdx.x, lane = tid & 63, wid = tid >> 6;
  const int base = blockIdx.x * 2048 + tid * 8;
  int4 v0 = *(const int4*)(deg + base);
  int4 v1 = *(const int4*)(deg + base + 4);
  int e[8] = {v0.x, v0.y, v0.z, v0.w, v1.x, v1.y, v1.z, v1.w};
  int s = e[0] + e[1] + e[2] + e[3] + e[4] + e[5] + e[6] + e[7];
  int incl = s;
#pragma unroll
  for (int off = 1; off < 64; off <<= 1) {
    int t = __shfl_up(incl, off, 64);
    if (lane >= off) incl += t;
  }
  if (lane == 63) wsum[wid] = incl;
  __syncthreads();
  int run = boff[blockIdx.x] + (incl - s);
  for (int w = 0; w < wid; ++w) run += wsum[w];
  int o[8];
#pragma unroll
  for (int i = 0; i < 8; ++i) { o[i] = run; run += e[i]; }
  int4 a = make_int4(o[0], o[1], o[2], o[3]);
  int4 b = make_int4(o[4], o[5], o[6], o[7]);
  *(int4*)(rowptr + base) = a;  *(int4*)(rowptr + base + 4) = b;
  *(int4*)(cursor + base) = a;  *(int4*)(cursor + base + 4) = b;
}

// CSR fill: cursor pre-initialized to rowptr.
__global__ void k_fill(const int* __restrict__ src, const int* __restrict__ tgt,
                       int* __restrict__ cursor, int* __restrict__ csrc, int E) {
  int e = blockIdx.x * 256 + threadIdx.x;
  if (e >= E) return;
  int pos = atomicAdd(cursor + tgt[e], 1);
  csrc[pos] = src[e];
}

// ---------------------------------------------------------------------------
// Y0 = X @ W0, Y1 = X @ W1.  X:[N,K], W0/W1:[K,64].  32 rows x 128 cols/block.
template <int K>
__global__ __launch_bounds__(256) void k_gemm(
    const float* __restrict__ X, const float* __restrict__ W0,
    const float* __restrict__ W1, float* __restrict__ Y0,
    float* __restrict__ Y1, int N) {
  __shared__ float Wl[64][128];
  __shared__ float Xs[32][64];
  const int tid = threadIdx.x;
  const int tx = tid & 31;
  const int ty = tid >> 5;
  const int row0 = blockIdx.x * 32;

  float acc[4][4];
#pragma unroll
  for (int i = 0; i < 4; ++i)
#pragma unroll
    for (int c = 0; c < 4; ++c) acc[i][c] = 0.0f;

  for (int kc = 0; kc < K; kc += 64) {
#pragma unroll
    for (int q = 0; q < 8; ++q) {
      int f = tid + 256 * q;
      int kk = f >> 5, c4 = f & 31;
      const float* sw = (c4 < 16) ? (W0 + (size_t)(kc + kk) * 64 + c4 * 4)
                                  : (W1 + (size_t)(kc + kk) * 64 + (c4 - 16) * 4);
      float4 v = *(const float4*)sw;
      *(float4*)&Wl[kk][c4 * 4] = v;
    }
#pragma unroll
    for (int q = 0; q < 2; ++q) {
      int f = tid + 256 * q;
      int r = f >> 4, k4 = f & 15;
      float4 v = *(const float4*)(X + (size_t)(row0 + r) * K + kc + k4 * 4);
      *(float4*)&Xs[r][k4 * 4] = v;
    }
    __syncthreads();
    for (int k4 = 0; k4 < 64; k4 += 4) {
      float4 arow[4];
#pragma unroll
      for (int i = 0; i < 4; ++i) arow[i] = *(const float4*)&Xs[ty + 8 * i][k4];
#pragma unroll
      for (int kk = 0; kk < 4; ++kk) {
        float4 wv = *(const float4*)&Wl[k4 + kk][tx * 4];
#pragma unroll
        for (int i = 0; i < 4; ++i) {
          float a = (&arow[i].x)[kk];
          acc[i][0] = fmaf(a, wv.x, acc[i][0]);
          acc[i][1] = fmaf(a, wv.y, acc[i][1]);
          acc[i][2] = fmaf(a, wv.z, acc[i][2]);
          acc[i][3] = fmaf(a, wv.w, acc[i][3]);
        }
      }
    }
    __syncthreads();
  }
#pragma unroll
  for (int i = 0; i < 4; ++i) {
    int r = row0 + ty + 8 * i;
    float4 v = make_float4(acc[i][0], acc[i][1], acc[i][2], acc[i][3]);
    if (tx < 16)
      *(float4*)(Y0 + (size_t)r * 64 + tx * 4) = v;
    else
      *(float4*)(Y1 + (size_t)r * 64 + (tx - 16) * 4) = v;
  }
}

// G = X @ W in bf16.  X:[N,64] f32, W:[64,64] f32, G:[N,64] bf16.
__global__ __launch_bounds__(256) void k_gemm1(const float* __restrict__ X,
                                               const float* __restrict__ W,
                                               unsigned short* __restrict__ Gb,
                                               int N) {
  __shared__ float sW[64][68];
  __shared__ float sX[64][68];
  const int tid = threadIdx.x;
  const int tx = tid & 15, ty = tid >> 4;
  const int row0 = blockIdx.x * 64;
#pragma unroll
  for (int q = 0; q < 4; ++q) {
    int f = tid + 256 * q;
    int r = f >> 4, c4 = f & 15;
    *(float4*)&sW[r][c4 * 4] = *(const float4*)(W + (size_t)r * 64 + c4 * 4);
    int xr = row0 + r; if (xr >= N) xr = N - 1;
    *(float4*)&sX[r][c4 * 4] = *(const float4*)(X + (size_t)xr * 64 + c4 * 4);
  }
  __syncthreads();
  float acc[4][4];
#pragma unroll
  for (int i = 0; i < 4; ++i)
#pragma unroll
    for (int c = 0; c < 4; ++c) acc[i][c] = 0.0f;
  for (int k4 = 0; k4 < 64; k4 += 4) {
    float4 arow[4];
#pragma unroll
    for (int i = 0; i < 4; ++i) arow[i] = *(const float4*)&sX[ty * 4 + i][k4];
#pragma unroll
    for (int kk = 0; kk < 4; ++kk) {
      float4 wv = *(const float4*)&sW[k4 + kk][tx * 4];
#pragma unroll
      for (int i = 0; i < 4; ++i) {
        float a = (&arow[i].x)[kk];
        acc[i][0] = fmaf(a, wv.x, acc[i][0]);
        acc[i][1] = fmaf(a, wv.y, acc[i][1]);
        acc[i][2] = fmaf(a, wv.z, acc[i][2]);
        acc[i][3] = fmaf(a, wv.w, acc[i][3]);
      }
    }
  }
#pragma unroll
  for (int i = 0; i < 4; ++i) {
    int r = row0 + ty * 4 + i;
    if (r < N) {
      uint2 pk;
      pk.x = (unsigned int)f2bf(acc[i][0]) | ((unsigned int)f2bf(acc[i][1]) << 16);
      pk.y = (unsigned int)f2bf(acc[i][2]) | ((unsigned int)f2bf(acc[i][3]) << 16);
      *(uint2*)(Gb + (size_t)r * 64 + tx * 4) = pk;
    }
  }
}

// W25T (bf16, [n][k]) = (We2 @ Wo1)^T; We1T (bf16, [n][k], K pad 16->32);
// cvec = be2 @ Wo1 + bo1. One block; inputs staged in LDS.
__global__ __launch_bounds__(256) void k_prep(
    const float* __restrict__ We2, const float* __restrict__ Wo1,
    const float* __restrict__ be2, const float* __restrict__ bo1,
    const float* __restrict__ We1,
    unsigned short* __restrict__ W25T, unsigned short* __restrict__ We1T,
    float* __restrict__ cvec) {
  __shared__ float sA[4096];  // We2
  __shared__ float sB[4096];  // Wo1
  int tid = threadIdx.x;
  for (int i = tid; i < 1024; i += 256) {
    *(float4*)&sA[i * 4] = *(const float4*)(We2 + i * 4);
    *(float4*)&sB[i * 4] = *(const float4*)(Wo1 + i * 4);
  }
  __syncthreads();
  for (int idx = tid; idx < 4096; idx += 256) {
    int n = idx >> 6, k = idx & 63;
    float s = 0.f;
#pragma unroll 8
    for (int m = 0; m < 64; ++m) s = fmaf(sA[k * 64 + m], sB[m * 64 + n], s);
    W25T[n * 64 + k] = f2bf(s);
  }
  for (int idx = tid; idx < 2048; idx += 256) {
    int n = idx >> 5, k = idx & 31;
    We1T[n * 32 + k] = (k < 16) ? f2bf(We1[k * 64 + n]) : (unsigned short)0;
  }
  if (tid < 64) {
    float s = bo1[tid];
#pragma unroll 8
    for (int m = 0; m < 64; ++m) s = fmaf(be2[m], sB[m * 64 + tid], s);
    cvec[tid] = s;
  }
}

// CSR aggregate fused with epilogue: H = relu(sum/deg + bias + Yr).
// Wave per node; lane = (rowslot rr 0..3, colgroup c4 0..15); 8 rows in
// flight per iteration (float4 loads), butterfly reduce over rr.
__global__ __launch_bounds__(256) void k_agg(
    const float* __restrict__ Y, const int* __restrict__ rowptr,
    const int* __restrict__ csrc, const float* __restrict__ bias,
    const float* __restrict__ Yr, float* __restrict__ H, int N) {
  int node = (blockIdx.x * 256 + threadIdx.x) >> 6;
  if (node >= N) return;
  const int lane = threadIdx.x & 63;
  const int c4 = lane & 15, rr = lane >> 4;
  int beg = rowptr[node], end = rowptr[node + 1];
  float a0 = 0.f, a1 = 0.f, a2 = 0.f, a3 = 0.f;
  float b0 = 0.f, b1 = 0.f, b2 = 0.f, b3 = 0.f;
  for (int e = beg; e < end; e += 8) {
    int e0 = e + rr, e1 = e + 4 + rr;
    if (e0 < end) {
      int s = csrc[e0];
      float4 v = *(const float4*)(Y + (size_t)s * 64 + c4 * 4);
      a0 += v.x; a1 += v.y; a2 += v.z; a3 += v.w;
    }
    if (e1 < end) {
      int s = csrc[e1];
      float4 v = *(const float4*)(Y + (size_t)s * 64 + c4 * 4);
      b0 += v.x; b1 += v.y; b2 += v.z; b3 += v.w;
    }
  }
  a0 += b0; a1 += b1; a2 += b2; a3 += b3;
  // reduce over rr (lane bits 4,5)
#pragma unroll
  for (int msk = 16; msk <= 32; msk <<= 1) {
    a0 += __shfl_xor(a0, msk, 64);
    a1 += __shfl_xor(a1, msk, 64);
    a2 += __shfl_xor(a2, msk, 64);
    a3 += __shfl_xor(a3, msk, 64);
  }
  if (rr == 0) {
    float cdeg = (float)(end - beg);
    if (cdeg < 1.f) cdeg = 1.f;
    float inv = 1.f / cdeg;
    float4 bv = *(const float4*)(bias + c4 * 4);
    float4 yv = *(const float4*)(Yr + (size_t)node * 64 + c4 * 4);
    float4 o;
    o.x = fmaxf(a0 * inv + bv.x + yv.x, 0.f);
    o.y = fmaxf(a1 * inv + bv.y + yv.y, 0.f);
    o.z = fmaxf(a2 * inv + bv.z + yv.z, 0.f);
    o.w = fmaxf(a3 * inv + bv.w + yv.w, 0.f);
    *(float4*)(H + (size_t)node * 64 + c4 * 4) = o;
  }
}

// ---------------------------------------------------------------------------
// MFMA edge pipeline. Wave-independent 16-edge tiles; software-pipelined:
// next tile's src/tgt/eattr prefetched during current compute; G (bf16)
// gathers issued BEFORE MFMA1 so the t1 roundtrip hides their latency.
// MFMA layouts (gfx950, verified): A[m=lane&15][k=(lane>>4)*8+j],
// B[k=(lane>>4)*8+j][n=lane&15], C/D col=lane&15, row=(lane>>4)*4+reg.
#define T1_STRIDE 72
#define EA_STRIDE 40
#define WAVE_LDS (EA_STRIDE * 16 + T1_STRIDE * 16)
__global__ __launch_bounds__(256) void k_edge3(
    const float* __restrict__ eattr, const int* __restrict__ src,
    const int* __restrict__ tgt, const unsigned short* __restrict__ Gb,
    const unsigned short* __restrict__ We1T,
    const unsigned short* __restrict__ W25T,
    const float* __restrict__ cvec, const float* __restrict__ be1,
    const float* __restrict__ Wo2, const float* __restrict__ bo2,
    float* __restrict__ out, int E, int nT, int nWaves) {
  __shared__ unsigned short lds[4 * WAVE_LDS];
  const int tid = threadIdx.x;
  const int wid = tid >> 6, lane = tid & 63;
  const int m = lane & 15, q = lane >> 4;
  unsigned short* sEA = lds + wid * WAVE_LDS;
  unsigned short* sT1 = sEA + EA_STRIDE * 16;

  short8 bWe1[4], bW25[4][2];
  float cv[4], wo2v[4], be1v[4];
#pragma unroll
  for (int nt = 0; nt < 4; ++nt) {
    int n = nt * 16 + m;
    bWe1[nt] = *(const short8*)(We1T + n * 32 + q * 8);
    bW25[nt][0] = *(const short8*)(W25T + n * 64 + q * 8);
    bW25[nt][1] = *(const short8*)(W25T + n * 64 + 32 + q * 8);
    cv[nt] = cvec[n];
    wo2v[nt] = Wo2[n];
    be1v[nt] = be1[n];
  }
  const float b_out = bo2[0];

  {
    int r = lane >> 2, cc = (lane & 3) * 4;
    uint2 z; z.x = 0u; z.y = 0u;
    *(uint2*)(sEA + r * EA_STRIDE + 16 + cc) = z;
  }

  int t = blockIdx.x * 4 + wid;
  if (t >= nT) return;

  // prologue loads for first tile
  int er = t * 16 + (lane >> 2); if (er >= E) er = E - 1;
  float4 ev = *(const float4*)(eattr + (size_t)er * 16 + (lane & 3) * 4);
  int il = t * 16 + m; if (il >= E) il = E - 1;
  int my_idx = (lane < 16) ? src[il] : ((lane < 32) ? tgt[il] : 0);

  while (true) {
    const int base = t * 16;
    const int tn = t + nWaves;
    const bool last = (tn >= nT);
    const int tc = last ? t : tn;

    // ---- prefetch next tile's eattr + indices
    int er_n = tc * 16 + (lane >> 2); if (er_n >= E) er_n = E - 1;
    float4 ev_n = *(const float4*)(eattr + (size_t)er_n * 16 + (lane & 3) * 4);
    int il_n = tc * 16 + m; if (il_n >= E) il_n = E - 1;
    int idx_n = (lane < 16) ? src[il_n] : ((lane < 32) ? tgt[il_n] : 0);

    // ---- distribute rows + issue all 32 G gathers (bf16)
    int rs[4], rt[4];
#pragma unroll
    for (int r = 0; r < 4; ++r) {
      rs[r] = __shfl(my_idx, q * 4 + r, 64);
      rt[r] = __shfl(my_idx, 16 + q * 4 + r, 64);
    }
    unsigned short gsv[4][4], gtv[4][4];
#pragma unroll
    for (int nt = 0; nt < 4; ++nt) {
      int c = nt * 16 + m;
#pragma unroll
      for (int r = 0; r < 4; ++r) {
        gsv[nt][r] = Gb[(size_t)rs[r] * 64 + c];
        gtv[nt][r] = Gb[(size_t)rt[r] * 64 + c];
      }
    }

    // ---- stage EA, MFMA1 (independent of G loads -> hides their latency)
    {
      uint2 pk;
      pk.x = (unsigned int)f2bf(ev.x) | ((unsigned int)f2bf(ev.y) << 16);
      pk.y = (unsigned int)f2bf(ev.z) | ((unsigned int)f2bf(ev.w) << 16);
      *(uint2*)(sEA + (lane >> 2) * EA_STRIDE + (lane & 3) * 4) = pk;
    }
    short8 aEA = *(short8*)(sEA + m * EA_STRIDE + q * 8);
    f32x4 t1[4];
#pragma unroll
    for (int nt = 0; nt < 4; ++nt) {
      f32x4 cinit; cinit[0] = be1v[nt]; cinit[1] = be1v[nt];
      cinit[2] = be1v[nt]; cinit[3] = be1v[nt];
      t1[nt] = __builtin_amdgcn_mfma_f32_16x16x32_bf16(aEA, bWe1[nt], cinit, 0, 0, 0);
    }
#pragma unroll
    for (int nt = 0; nt < 4; ++nt)
#pragma unroll
      for (int r = 0; r < 4; ++r)
        sT1[(q * 4 + r) * T1_STRIDE + nt * 16 + m] = f2bf(fmaxf(t1[nt][r], 0.f));
    short8 aT0 = *(short8*)(sT1 + m * T1_STRIDE + q * 8);
    short8 aT1 = *(short8*)(sT1 + m * T1_STRIDE + 32 + q * 8);

    // ---- acc init from arrived G values, then MFMA2
    f32x4 acc[4];
#pragma unroll
    for (int nt = 0; nt < 4; ++nt)
#pragma unroll
      for (int r = 0; r < 4; ++r)
        acc[nt][r] = cv[nt] + bf2f(gsv[nt][r]) + bf2f(gtv[nt][r]);
#pragma unroll
    for (int nt = 0; nt < 4; ++nt) {
      acc[nt] = __builtin_amdgcn_mfma_f32_16x16x32_bf16(aT0, bW25[nt][0], acc[nt], 0, 0, 0);
      acc[nt] = __builtin_amdgcn_mfma_f32_16x16x32_bf16(aT1, bW25[nt][1], acc[nt], 0, 0, 0);
    }

    // ---- epilogue
    float p[4];
#pragma unroll
    for (int r = 0; r < 4; ++r) {
      p[r] = fmaxf(acc[0][r], 0.f) * wo2v[0] + fmaxf(acc[1][r], 0.f) * wo2v[1] +
             fmaxf(acc[2][r], 0.f) * wo2v[2] + fmaxf(acc[3][r], 0.f) * wo2v[3];
    }
#pragma unroll
    for (int msk = 1; msk <= 8; msk <<= 1) {
#pragma unroll
      for (int r = 0; r < 4; ++r) p[r] += __shfl_xor(p[r], msk, 64);
    }
    if (m == 0) {
#pragma unroll
      for (int r = 0; r < 4; ++r) {
        int row = base + q * 4 + r;
        if (row < E) out[row] = 1.f / (1.f + __expf(-(p[r] + b_out)));
      }
    }

    if (last) break;
    t = tn; ev = ev_n; my_idx = idx_n;
  }
}

// ---------------------------------------------------------------------------
extern "C" void kernel_launch(void* const* d_in, const int* in_sizes, int n_in,
                              void* d_out, int out_size, void* d_ws, size_t ws_size,
                              hipStream_t stream) {
  const float* x     = (const float*)d_in[0];
  const unsigned int* eidx = (const unsigned int*)d_in[1];
  const float* eattr = (const float*)d_in[2];
  const float* We1 = (const float*)d_in[3];
  const float* be1 = (const float*)d_in[4];
  const float* We2 = (const float*)d_in[5];
  const float* be2 = (const float*)d_in[6];
  const float* Wl0 = (const float*)d_in[7];
  const float* bl0 = (const float*)d_in[8];
  const float* Wr0 = (const float*)d_in[9];
  const float* Wl1 = (const float*)d_in[10];
  const float* bl1 = (const float*)d_in[11];
  const float* Wr1 = (const float*)d_in[12];
  const float* Wo1 = (const float*)d_in[13];
  const float* bo1 = (const float*)d_in[14];
  const float* Wo2 = (const float*)d_in[15];
  const float* bo2 = (const float*)d_in[16];

  const int N = in_sizes[0] / 128;   // 100000
  const int E = in_sizes[2] / 16;    // 1000000
  const int padN = (N + 2047) & ~2047;
  const int nB = padN / 2048;
  float* out = (float*)d_out;

  char* ws = (char*)d_ws;
  size_t off = 0;
  auto alloc = [&](size_t bytes) {
    char* p = ws + off;
    off += (bytes + 255) & ~(size_t)255;
    return p;
  };
  unsigned int* flag = (unsigned int*)alloc(256);
  int* src    = (int*)alloc((size_t)E * 4);
  int* tgt    = (int*)alloc((size_t)E * 4);
  int* deg    = (int*)alloc((size_t)padN * 4);
  int* rowptr = (int*)alloc((size_t)(padN + 64) * 4);
  int* cursor = (int*)alloc((size_t)padN * 4);
  int* bsum   = (int*)alloc(64 * 4);
  int* boff   = (int*)alloc(64 * 4);
  int* csrc   = (int*)alloc((size_t)E * 4);
  float* Hb   = (float*)alloc((size_t)N * 64 * 4);
  float* Yl   = (float*)alloc((size_t)N * 64 * 4);
  float* Yr   = (float*)alloc((size_t)N * 64 * 4);
  unsigned short* Gb = (unsigned short*)alloc((size_t)N * 64 * 2);
  unsigned short* W25T = (unsigned short*)alloc(64 * 64 * 2);
  unsigned short* We1T = (unsigned short*)alloc(64 * 32 * 2);
  float* cvec = (float*)alloc(64 * 4);
  (void)ws_size; (void)n_in; (void)out_size;

  hipMemsetAsync(deg, 0, (size_t)padN * 4, stream);

  k_flag<<<1, 256, 0, stream>>>(eidx, 8192, flag);
  k_decode<<<(E + 255) / 256, 256, 0, stream>>>(eidx, flag, E, src, tgt, deg);
  k_scan1<<<nB, 256, 0, stream>>>(deg, bsum);
  k_scan2<<<1, 64, 0, stream>>>(bsum, boff, nB, rowptr + N);
  k_scan3<<<nB, 256, 0, stream>>>(deg, boff, rowptr, cursor);
  k_fill<<<(E + 255) / 256, 256, 0, stream>>>(src, tgt, cursor, csrc, E);
  k_prep<<<1, 256, 0, stream>>>(We2, Wo1, be2, bo1, We1, W25T, We1T, cvec);

  // Layer 0 (project-then-aggregate: mean is linear)
  k_gemm<128><<<N / 32, 256, 0, stream>>>(x, Wl0, Wr0, Yl, Yr, N);
  k_agg<<<(N + 3) / 4, 256, 0, stream>>>(Yl, rowptr, csrc, bl0, Yr, Hb, N);

  // Layer 1
  k_gemm<64><<<N / 32, 256, 0, stream>>>(Hb, Wl1, Wr1, Yl, Yr, N);
  k_agg<<<(N + 3) / 4, 256, 0, stream>>>(Yl, rowptr, csrc, bl1, Yr, Hb, N);

  // G = H2 @ Wo1 (bf16 output: halves edge-kernel gather traffic)
  k_gemm1<<<(N + 63) / 64, 256, 0, stream>>>(Hb, Wo1, Gb, N);

  // MFMA edge pipeline
  const int nT = (E + 15) / 16;
  const int blocks = 2048;
  k_edge3<<<blocks, 256, 0, stream>>>(eattr, src, tgt, Gb, We1T, W25T, cvec,
                                      be1, Wo2, bo2, out, E, nT, blocks * 4);
}

// Round 8
// 539.078 us; speedup vs baseline: 2.2719x; 1.0975x over previous
//
#include <hip/hip_runtime.h>
#include <math.h>

typedef __attribute__((ext_vector_type(8))) short short8;
typedef __attribute__((ext_vector_type(4))) float f32x4;

static __device__ __forceinline__ unsigned short f2bf(float f) {
  union { float f; unsigned int u; } x; x.f = f;
  unsigned int r = x.u + 0x7fffu + ((x.u >> 16) & 1u);  // RNE
  return (unsigned short)(r >> 16);
}
static __device__ __forceinline__ float bf2f(unsigned int u) {
  union { unsigned int u; float f; } x; x.u = u << 16; return x.f;
}

// ---------------------------------------------------------------------------
// int64-vs-int32 edge_index detection.
__global__ void k_flag(const unsigned int* __restrict__ w, int nSample,
                       unsigned int* __restrict__ flag) {
  __shared__ unsigned int red[256];
  unsigned int v = 0;
  for (int i = threadIdx.x; i < nSample; i += 256) v |= w[2 * i + 1];
  red[threadIdx.x] = v;
  __syncthreads();
  for (int s = 128; s > 0; s >>= 1) {
    if (threadIdx.x < s) red[threadIdx.x] |= red[threadIdx.x + s];
    __syncthreads();
  }
  if (threadIdx.x == 0) flag[0] = red[0];  // nonzero => int32 layout
}

__global__ void k_decode(const unsigned int* __restrict__ w,
                         const unsigned int* __restrict__ flag, int E,
                         int* __restrict__ src, int* __restrict__ tgt,
                         int* __restrict__ deg) {
  int e = blockIdx.x * 256 + threadIdx.x;
  if (e >= E) return;
  int s, t;
  if (flag[0]) { s = (int)w[e]; t = (int)w[E + e]; }
  else         { s = (int)w[2 * e]; t = (int)w[2 * (E + e)]; }
  src[e] = s;
  tgt[e] = t;
  atomicAdd(deg + t, 1);
}

// ---------------------------------------------------------------------------
// Hierarchical exclusive scan of deg[padN] (padN multiple of 2048, pad=0).
__global__ __launch_bounds__(256) void k_scan1(const int* __restrict__ deg,
                                               int* __restrict__ bsum) {
  __shared__ int wsum[4];
  const int tid = threadIdx.x, lane = tid & 63, wid = tid >> 6;
  const int base = blockIdx.x * 2048 + tid * 8;
  int4 v0 = *(const int4*)(deg + base);
  int4 v1 = *(const int4*)(deg + base + 4);
  int s = v0.x + v0.y + v0.z + v0.w + v1.x + v1.y + v1.z + v1.w;
#pragma unroll
  for (int off = 1; off < 64; off <<= 1) s += __shfl_xor(s, off, 64);
  if (lane == 0) wsum[wid] = s;
  __syncthreads();
  if (tid == 0) bsum[blockIdx.x] = wsum[0] + wsum[1] + wsum[2] + wsum[3];
}

__global__ void k_scan2(const int* __restrict__ bsum, int* __restrict__ boff,
                        int nB, int* __restrict__ rowptrN) {
  int lane = threadIdx.x;
  int v = (lane < nB) ? bsum[lane] : 0;
  int incl = v;
#pragma unroll
  for (int off = 1; off < 64; off <<= 1) {
    int t = __shfl_up(incl, off, 64);
    if (lane >= off) incl += t;
  }
  if (lane < nB) boff[lane] = incl - v;
  if (lane == 63) *rowptrN = incl;   // total = E
}

__global__ __launch_bounds__(256) void k_scan3(const int* __restrict__ deg,
                                               const int* __restrict__ boff,
                                               int* __restrict__ rowptr,
                                               int* __restrict__ cursor) {
  __shared__ int wsum[4];
  const int tid = threadIdx.x, lane = tid & 63, wid = tid >> 6;
  const int base = blockIdx.x * 2048 + tid * 8;
  int4 v0 = *(const int4*)(deg + base);
  int4 v1 = *(const int4*)(deg + base + 4);
  int e[8] = {v0.x, v0.y, v0.z, v0.w, v1.x, v1.y, v1.z, v1.w};
  int s = e[0] + e[1] + e[2] + e[3] + e[4] + e[5] + e[6] + e[7];
  int incl = s;
#pragma unroll
  for (int off = 1; off < 64; off <<= 1) {
    int t = __shfl_up(incl, off, 64);
    if (lane >= off) incl += t;
  }
  if (lane == 63) wsum[wid] = incl;
  __syncthreads();
  int run = boff[blockIdx.x] + (incl - s);
  for (int w = 0; w < wid; ++w) run += wsum[w];
  int o[8];
#pragma unroll
  for (int i = 0; i < 8; ++i) { o[i] = run; run += e[i]; }
  int4 a = make_int4(o[0], o[1], o[2], o[3]);
  int4 b = make_int4(o[4], o[5], o[6], o[7]);
  *(int4*)(rowptr + base) = a;  *(int4*)(rowptr + base + 4) = b;
  *(int4*)(cursor + base) = a;  *(int4*)(cursor + base + 4) = b;
}

__global__ void k_fill(const int* __restrict__ src, const int* __restrict__ tgt,
                       int* __restrict__ cursor, int* __restrict__ csrc, int E) {
  int e = blockIdx.x * 256 + threadIdx.x;
  if (e >= E) return;
  int pos = atomicAdd(cursor + tgt[e], 1);
  csrc[pos] = src[e];
}

// ---------------------------------------------------------------------------
// Weight transpose for MFMA node GEMM: WnT[n][k] bf16, n in [0,128) over
// [W0|W1] (each [K,64]).
template <int K>
__global__ void k_prep2(const float* __restrict__ W0,
                        const float* __restrict__ W1,
                        unsigned short* __restrict__ WnT) {
  int idx = blockIdx.x * 256 + threadIdx.x;
  if (idx >= 128 * K) return;
  int n = idx / K, k = idx % K;
  float v = (n < 64) ? W0[(size_t)k * 64 + n] : W1[(size_t)k * 64 + (n - 64)];
  WnT[idx] = f2bf(v);
}

// MFMA node GEMM: [Y0|Y1] = X @ [W0|W1] with bf16 inputs, f32 out.
// Block 256 = 4 waves; 64 rows x 128 cols; wave w covers cols w*32..+32.
// MFMA layouts (gfx950, verified): A[m=lane&15][k=(lane>>4)*8+j],
// B[k][n=lane&15] (frag = WnT[n][k] contiguous in k), C/D col=lane&15,
// row=(lane>>4)*4+reg.
template <int K>
__global__ __launch_bounds__(256) void k_ngemm(
    const float* __restrict__ X, const unsigned short* __restrict__ WnT,
    float* __restrict__ Y0, float* __restrict__ Y1, int N) {
  constexpr int STR = K + 8;   // +16B pad: banks spread, b128 stays aligned
  constexpr int NC = K / 32;
  __shared__ unsigned short sX[64 * STR];
  const int tid = threadIdx.x;
  const int wv = tid >> 6, lane = tid & 63;
  const int m = lane & 15, q = lane >> 4;
  const int row0 = blockIdx.x * 64;

  // persistent B fragments (2 col-tiles x NC k-chunks)
  short8 bB[2][NC];
#pragma unroll
  for (int ct = 0; ct < 2; ++ct)
#pragma unroll
    for (int c = 0; c < NC; ++c) {
      int n = wv * 32 + ct * 16 + m;
      bB[ct][c] = *(const short8*)(WnT + (size_t)n * K + c * 32 + q * 8);
    }

  // stage X rows (f32 -> bf16)
#pragma unroll
  for (int i = 0; i < K / 16; ++i) {
    int f = tid + 256 * i;
    int r = f / (K / 4);
    int c4 = f % (K / 4);
    int rr = row0 + r; if (rr >= N) rr = N - 1;
    float4 v = *(const float4*)(X + (size_t)rr * K + c4 * 4);
    uint2 pk;
    pk.x = (unsigned int)f2bf(v.x) | ((unsigned int)f2bf(v.y) << 16);
    pk.y = (unsigned int)f2bf(v.z) | ((unsigned int)f2bf(v.w) << 16);
    *(uint2*)(sX + r * STR + c4 * 4) = pk;
  }
  __syncthreads();

  f32x4 acc[4][2];
#pragma unroll
  for (int rt = 0; rt < 4; ++rt)
#pragma unroll
    for (int ct = 0; ct < 2; ++ct)
#pragma unroll
      for (int r = 0; r < 4; ++r) acc[rt][ct][r] = 0.f;

#pragma unroll
  for (int c = 0; c < NC; ++c) {
    short8 a[4];
#pragma unroll
    for (int rt = 0; rt < 4; ++rt)
      a[rt] = *(const short8*)(sX + (rt * 16 + m) * STR + c * 32 + q * 8);
#pragma unroll
    for (int rt = 0; rt < 4; ++rt) {
      acc[rt][0] = __builtin_amdgcn_mfma_f32_16x16x32_bf16(a[rt], bB[0][c], acc[rt][0], 0, 0, 0);
      acc[rt][1] = __builtin_amdgcn_mfma_f32_16x16x32_bf16(a[rt], bB[1][c], acc[rt][1], 0, 0, 0);
    }
  }

  float* Yw = (wv < 2) ? Y0 : Y1;
  const int nb = (wv & 1) * 32;
#pragma unroll
  for (int rt = 0; rt < 4; ++rt)
#pragma unroll
    for (int ct = 0; ct < 2; ++ct) {
      int n = nb + ct * 16 + m;
#pragma unroll
      for (int reg = 0; reg < 4; ++reg) {
        int row = row0 + rt * 16 + q * 4 + reg;
        if (row < N) Yw[(size_t)row * 64 + n] = acc[rt][ct][reg];
      }
    }
}

// G = X @ W in bf16.  X:[N,64] f32, W:[64,64] f32, G:[N,64] bf16.
__global__ __launch_bounds__(256) void k_gemm1(const float* __restrict__ X,
                                               const float* __restrict__ W,
                                               unsigned short* __restrict__ Gb,
                                               int N) {
  __shared__ float sW[64][68];
  __shared__ float sX[64][68];
  const int tid = threadIdx.x;
  const int tx = tid & 15, ty = tid >> 4;
  const int row0 = blockIdx.x * 64;
#pragma unroll
  for (int qq = 0; qq < 4; ++qq) {
    int f = tid + 256 * qq;
    int r = f >> 4, c4 = f & 15;
    *(float4*)&sW[r][c4 * 4] = *(const float4*)(W + (size_t)r * 64 + c4 * 4);
    int xr = row0 + r; if (xr >= N) xr = N - 1;
    *(float4*)&sX[r][c4 * 4] = *(const float4*)(X + (size_t)xr * 64 + c4 * 4);
  }
  __syncthreads();
  float acc[4][4];
#pragma unroll
  for (int i = 0; i < 4; ++i)
#pragma unroll
    for (int c = 0; c < 4; ++c) acc[i][c] = 0.0f;
  for (int k4 = 0; k4 < 64; k4 += 4) {
    float4 arow[4];
#pragma unroll
    for (int i = 0; i < 4; ++i) arow[i] = *(const float4*)&sX[ty * 4 + i][k4];
#pragma unroll
    for (int kk = 0; kk < 4; ++kk) {
      float4 wv = *(const float4*)&sW[k4 + kk][tx * 4];
#pragma unroll
      for (int i = 0; i < 4; ++i) {
        float a = (&arow[i].x)[kk];
        acc[i][0] = fmaf(a, wv.x, acc[i][0]);
        acc[i][1] = fmaf(a, wv.y, acc[i][1]);
        acc[i][2] = fmaf(a, wv.z, acc[i][2]);
        acc[i][3] = fmaf(a, wv.w, acc[i][3]);
      }
    }
  }
#pragma unroll
  for (int i = 0; i < 4; ++i) {
    int r = row0 + ty * 4 + i;
    if (r < N) {
      uint2 pk;
      pk.x = (unsigned int)f2bf(acc[i][0]) | ((unsigned int)f2bf(acc[i][1]) << 16);
      pk.y = (unsigned int)f2bf(acc[i][2]) | ((unsigned int)f2bf(acc[i][3]) << 16);
      *(uint2*)(Gb + (size_t)r * 64 + tx * 4) = pk;
    }
  }
}

// W25T (bf16, [n][k]) = (We2 @ Wo1)^T; We1T (bf16, [n][k], K pad 16->32);
// cvec = be2 @ Wo1 + bo1. One block; inputs staged in LDS.
__global__ __launch_bounds__(256) void k_prep(
    const float* __restrict__ We2, const float* __restrict__ Wo1,
    const float* __restrict__ be2, const float* __restrict__ bo1,
    const float* __restrict__ We1,
    unsigned short* __restrict__ W25T, unsigned short* __restrict__ We1T,
    float* __restrict__ cvec) {
  __shared__ float sA[4096];  // We2
  __shared__ float sB[4096];  // Wo1
  int tid = threadIdx.x;
  for (int i = tid; i < 1024; i += 256) {
    *(float4*)&sA[i * 4] = *(const float4*)(We2 + i * 4);
    *(float4*)&sB[i * 4] = *(const float4*)(Wo1 + i * 4);
  }
  __syncthreads();
  for (int idx = tid; idx < 4096; idx += 256) {
    int n = idx >> 6, k = idx & 63;
    float s = 0.f;
#pragma unroll 8
    for (int mm = 0; mm < 64; ++mm) s = fmaf(sA[k * 64 + mm], sB[mm * 64 + n], s);
    W25T[n * 64 + k] = f2bf(s);
  }
  for (int idx = tid; idx < 2048; idx += 256) {
    int n = idx >> 5, k = idx & 31;
    We1T[n * 32 + k] = (k < 16) ? f2bf(We1[k * 64 + n]) : (unsigned short)0;
  }
  if (tid < 64) {
    float s = bo1[tid];
#pragma unroll 8
    for (int mm = 0; mm < 64; ++mm) s = fmaf(be2[mm], sB[mm * 64 + tid], s);
    cvec[tid] = s;
  }
}

// CSR aggregate fused with epilogue: H = relu(sum/deg + bias + Yr).
__global__ __launch_bounds__(256) void k_agg(
    const float* __restrict__ Y, const int* __restrict__ rowptr,
    const int* __restrict__ csrc, const float* __restrict__ bias,
    const float* __restrict__ Yr, float* __restrict__ H, int N) {
  int node = (blockIdx.x * 256 + threadIdx.x) >> 6;
  if (node >= N) return;
  const int lane = threadIdx.x & 63;
  const int c4 = lane & 15, rr = lane >> 4;
  int beg = rowptr[node], end = rowptr[node + 1];
  float a0 = 0.f, a1 = 0.f, a2 = 0.f, a3 = 0.f;
  float b0 = 0.f, b1 = 0.f, b2 = 0.f, b3 = 0.f;
  for (int e = beg; e < end; e += 8) {
    int e0 = e + rr, e1 = e + 4 + rr;
    if (e0 < end) {
      int s = csrc[e0];
      float4 v = *(const float4*)(Y + (size_t)s * 64 + c4 * 4);
      a0 += v.x; a1 += v.y; a2 += v.z; a3 += v.w;
    }
    if (e1 < end) {
      int s = csrc[e1];
      float4 v = *(const float4*)(Y + (size_t)s * 64 + c4 * 4);
      b0 += v.x; b1 += v.y; b2 += v.z; b3 += v.w;
    }
  }
  a0 += b0; a1 += b1; a2 += b2; a3 += b3;
#pragma unroll
  for (int msk = 16; msk <= 32; msk <<= 1) {
    a0 += __shfl_xor(a0, msk, 64);
    a1 += __shfl_xor(a1, msk, 64);
    a2 += __shfl_xor(a2, msk, 64);
    a3 += __shfl_xor(a3, msk, 64);
  }
  if (rr == 0) {
    float cdeg = (float)(end - beg);
    if (cdeg < 1.f) cdeg = 1.f;
    float inv = 1.f / cdeg;
    float4 bv = *(const float4*)(bias + c4 * 4);
    float4 yv = *(const float4*)(Yr + (size_t)node * 64 + c4 * 4);
    float4 o;
    o.x = fmaxf(a0 * inv + bv.x + yv.x, 0.f);
    o.y = fmaxf(a1 * inv + bv.y + yv.y, 0.f);
    o.z = fmaxf(a2 * inv + bv.z + yv.z, 0.f);
    o.w = fmaxf(a3 * inv + bv.w + yv.w, 0.f);
    *(float4*)(H + (size_t)node * 64 + c4 * 4) = o;
  }
}

// ---------------------------------------------------------------------------
// MFMA edge pipeline v2. Wave-independent 16-edge tiles.
//  - EA A-fragment loaded DIRECTLY from global (A[m][k=q*8+j] = 8 contiguous
//    floats of edge m's attr; q>=2 lanes are the K-pad zeros). No LDS stage.
//  - G gathers are COALESCED row loads: quad q loads full 128B bf16 rows of
//    its 4 edges (lane m reads uint2 at 4m); C-layout redistribution via
//    per-wave f32 LDS buffer sG (stride 68: all patterns <=2-way banks).
// MFMA layouts (gfx950, verified): A[m=lane&15][k=(lane>>4)*8+j],
// B[k=(lane>>4)*8+j][n=lane&15], C/D col=lane&15, row=(lane>>4)*4+reg.
#define T1_STRIDE 72
#define G_STRIDE 68
__global__ __launch_bounds__(256) void k_edge3(
    const float* __restrict__ eattr, const int* __restrict__ src,
    const int* __restrict__ tgt, const unsigned short* __restrict__ Gb,
    const unsigned short* __restrict__ We1T,
    const unsigned short* __restrict__ W25T,
    const float* __restrict__ cvec, const float* __restrict__ be1,
    const float* __restrict__ Wo2, const float* __restrict__ bo2,
    float* __restrict__ out, int E, int nT, int nWaves) {
  __shared__ unsigned short sT1a[4][16 * T1_STRIDE];
  __shared__ float sGa[4][16 * G_STRIDE];
  const int tid = threadIdx.x;
  const int wid = tid >> 6, lane = tid & 63;
  const int m = lane & 15, q = lane >> 4;
  unsigned short* sT1 = sT1a[wid];
  float* sG = sGa[wid];

  short8 bWe1[4], bW25[4][2];
  float cv[4], wo2v[4], be1v[4];
#pragma unroll
  for (int nt = 0; nt < 4; ++nt) {
    int n = nt * 16 + m;
    bWe1[nt] = *(const short8*)(We1T + n * 32 + q * 8);
    bW25[nt][0] = *(const short8*)(W25T + n * 64 + q * 8);
    bW25[nt][1] = *(const short8*)(W25T + n * 64 + 32 + q * 8);
    cv[nt] = cvec[n];
    wo2v[nt] = Wo2[n];
    be1v[nt] = be1[n];
  }
  const float b_out = bo2[0];
  const short8 zfrag = {};

  int t = blockIdx.x * 4 + wid;
  if (t >= nT) return;
  int il = t * 16 + m; if (il >= E) il = E - 1;
  int my_idx = (lane < 16) ? src[il] : ((lane < 32) ? tgt[il] : 0);

  while (true) {
    const int base = t * 16;
    const int tn = t + nWaves;
    const bool last = (tn >= nT);
    const int tc = last ? t : tn;

    // prefetch next tile's endpoint indices
    int il_n = tc * 16 + m; if (il_n >= E) il_n = E - 1;
    int idx_n = (lane < 16) ? src[il_n] : ((lane < 32) ? tgt[il_n] : 0);

    // ---- coalesced G row gathers: quad q owns edges q*4..q*4+3
    int rs[4], rt[4];
#pragma unroll
    for (int r = 0; r < 4; ++r) {
      rs[r] = __shfl(my_idx, q * 4 + r, 64);
      rt[r] = __shfl(my_idx, 16 + q * 4 + r, 64);
    }
    uint2 sv[4], tv[4];
#pragma unroll
    for (int r = 0; r < 4; ++r) {
      sv[r] = *(const uint2*)(Gb + (size_t)rs[r] * 64 + m * 4);
      tv[r] = *(const uint2*)(Gb + (size_t)rt[r] * 64 + m * 4);
    }

    // ---- EA A-fragment direct from global
    int er = base + m; if (er >= E) er = E - 1;
    const float* ep = eattr + (size_t)er * 16 + (q & 1) * 8;
    float4 e0 = *(const float4*)ep;
    float4 e1 = *(const float4*)(ep + 4);
    short8 aEA;
    {
      union { short8 s; unsigned int u[4]; } ua;
      ua.u[0] = (unsigned int)f2bf(e0.x) | ((unsigned int)f2bf(e0.y) << 16);
      ua.u[1] = (unsigned int)f2bf(e0.z) | ((unsigned int)f2bf(e0.w) << 16);
      ua.u[2] = (unsigned int)f2bf(e1.x) | ((unsigned int)f2bf(e1.y) << 16);
      ua.u[3] = (unsigned int)f2bf(e1.z) | ((unsigned int)f2bf(e1.w) << 16);
      aEA = (q < 2) ? ua.s : zfrag;
    }

    // ---- MFMA1: t1 = relu(EA @ We1 + be1)
    f32x4 t1[4];
#pragma unroll
    for (int nt = 0; nt < 4; ++nt) {
      f32x4 cinit; cinit[0] = be1v[nt]; cinit[1] = be1v[nt];
      cinit[2] = be1v[nt]; cinit[3] = be1v[nt];
      t1[nt] = __builtin_amdgcn_mfma_f32_16x16x32_bf16(aEA, bWe1[nt], cinit, 0, 0, 0);
    }
#pragma unroll
    for (int nt = 0; nt < 4; ++nt)
#pragma unroll
      for (int r = 0; r < 4; ++r)
        sT1[(q * 4 + r) * T1_STRIDE + nt * 16 + m] = f2bf(fmaxf(t1[nt][r], 0.f));
    short8 aT0 = *(short8*)(sT1 + m * T1_STRIDE + q * 8);
    short8 aT1 = *(short8*)(sT1 + m * T1_STRIDE + 32 + q * 8);

    // ---- Gsum -> sG (f32): lane holds feats 4m..4m+3 of edge q*4+r
#pragma unroll
    for (int r = 0; r < 4; ++r) {
      f32x4 g;
      g[0] = bf2f(sv[r].x & 0xffffu) + bf2f(tv[r].x & 0xffffu);
      g[1] = bf2f(sv[r].x >> 16)     + bf2f(tv[r].x >> 16);
      g[2] = bf2f(sv[r].y & 0xffffu) + bf2f(tv[r].y & 0xffffu);
      g[3] = bf2f(sv[r].y >> 16)     + bf2f(tv[r].y >> 16);
      *(f32x4*)(sG + (q * 4 + r) * G_STRIDE + m * 4) = g;
    }

    // ---- acc init (C layout) + MFMA2
    f32x4 acc[4];
#pragma unroll
    for (int nt = 0; nt < 4; ++nt)
#pragma unroll
      for (int r = 0; r < 4; ++r)
        acc[nt][r] = cv[nt] + sG[(q * 4 + r) * G_STRIDE + nt * 16 + m];
#pragma unroll
    for (int nt = 0; nt < 4; ++nt) {
      acc[nt] = __builtin_amdgcn_mfma_f32_16x16x32_bf16(aT0, bW25[nt][0], acc[nt], 0, 0, 0);
      acc[nt] = __builtin_amdgcn_mfma_f32_16x16x32_bf16(aT1, bW25[nt][1], acc[nt], 0, 0, 0);
    }

    // ---- epilogue
    float p[4];
#pragma unroll
    for (int r = 0; r < 4; ++r) {
      p[r] = fmaxf(acc[0][r], 0.f) * wo2v[0] + fmaxf(acc[1][r], 0.f) * wo2v[1] +
             fmaxf(acc[2][r], 0.f) * wo2v[2] + fmaxf(acc[3][r], 0.f) * wo2v[3];
    }
#pragma unroll
    for (int msk = 1; msk <= 8; msk <<= 1) {
#pragma unroll
      for (int r = 0; r < 4; ++r) p[r] += __shfl_xor(p[r], msk, 64);
    }
    if (m == 0) {
#pragma unroll
      for (int r = 0; r < 4; ++r) {
        int row = base + q * 4 + r;
        if (row < E) out[row] = 1.f / (1.f + __expf(-(p[r] + b_out)));
      }
    }

    if (last) break;
    t = tn; my_idx = idx_n;
  }
}

// ---------------------------------------------------------------------------
extern "C" void kernel_launch(void* const* d_in, const int* in_sizes, int n_in,
                              void* d_out, int out_size, void* d_ws, size_t ws_size,
                              hipStream_t stream) {
  const float* x     = (const float*)d_in[0];
  const unsigned int* eidx = (const unsigned int*)d_in[1];
  const float* eattr = (const float*)d_in[2];
  const float* We1 = (const float*)d_in[3];
  const float* be1 = (const float*)d_in[4];
  const float* We2 = (const float*)d_in[5];
  const float* be2 = (const float*)d_in[6];
  const float* Wl0 = (const float*)d_in[7];
  const float* bl0 = (const float*)d_in[8];
  const float* Wr0 = (const float*)d_in[9];
  const float* Wl1 = (const float*)d_in[10];
  const float* bl1 = (const float*)d_in[11];
  const float* Wr1 = (const float*)d_in[12];
  const float* Wo1 = (const float*)d_in[13];
  const float* bo1 = (const float*)d_in[14];
  const float* Wo2 = (const float*)d_in[15];
  const float* bo2 = (const float*)d_in[16];

  const int N = in_sizes[0] / 128;   // 100000
  const int E = in_sizes[2] / 16;    // 1000000
  const int padN = (N + 2047) & ~2047;
  const int nB = padN / 2048;
  float* out = (float*)d_out;

  char* ws = (char*)d_ws;
  size_t off = 0;
  auto alloc = [&](size_t bytes) {
    char* p = ws + off;
    off += (bytes + 255) & ~(size_t)255;
    return p;
  };
  unsigned int* flag = (unsigned int*)alloc(256);
  int* src    = (int*)alloc((size_t)E * 4);
  int* tgt    = (int*)alloc((size_t)E * 4);
  int* deg    = (int*)alloc((size_t)padN * 4);
  int* rowptr = (int*)alloc((size_t)(padN + 64) * 4);
  int* cursor = (int*)alloc((size_t)padN * 4);
  int* bsum   = (int*)alloc(64 * 4);
  int* boff   = (int*)alloc(64 * 4);
  int* csrc   = (int*)alloc((size_t)E * 4);
  float* Hb   = (float*)alloc((size_t)N * 64 * 4);
  float* Yl   = (float*)alloc((size_t)N * 64 * 4);
  float* Yr   = (float*)alloc((size_t)N * 64 * 4);
  unsigned short* Gb = (unsigned short*)alloc((size_t)N * 64 * 2);
  unsigned short* W25T = (unsigned short*)alloc(64 * 64 * 2);
  unsigned short* We1T = (unsigned short*)alloc(64 * 32 * 2);
  unsigned short* WnT0 = (unsigned short*)alloc(128 * 128 * 2);
  unsigned short* WnT1 = (unsigned short*)alloc(128 * 64 * 2);
  float* cvec = (float*)alloc(64 * 4);
  (void)ws_size; (void)n_in; (void)out_size;

  hipMemsetAsync(deg, 0, (size_t)padN * 4, stream);

  k_flag<<<1, 256, 0, stream>>>(eidx, 8192, flag);
  k_decode<<<(E + 255) / 256, 256, 0, stream>>>(eidx, flag, E, src, tgt, deg);
  k_scan1<<<nB, 256, 0, stream>>>(deg, bsum);
  k_scan2<<<1, 64, 0, stream>>>(bsum, boff, nB, rowptr + N);
  k_scan3<<<nB, 256, 0, stream>>>(deg, boff, rowptr, cursor);
  k_fill<<<(E + 255) / 256, 256, 0, stream>>>(src, tgt, cursor, csrc, E);
  k_prep<<<1, 256, 0, stream>>>(We2, Wo1, be2, bo1, We1, W25T, We1T, cvec);
  k_prep2<128><<<64, 256, 0, stream>>>(Wl0, Wr0, WnT0);
  k_prep2<64><<<32, 256, 0, stream>>>(Wl1, Wr1, WnT1);

  // Layer 0 (project-then-aggregate: mean is linear) — MFMA
  k_ngemm<128><<<(N + 63) / 64, 256, 0, stream>>>(x, WnT0, Yl, Yr, N);
  k_agg<<<(N + 3) / 4, 256, 0, stream>>>(Yl, rowptr, csrc, bl0, Yr, Hb, N);

  // Layer 1 — MFMA
  k_ngemm<64><<<(N + 63) / 64, 256, 0, stream>>>(Hb, WnT1, Yl, Yr, N);
  k_agg<<<(N + 3) / 4, 256, 0, stream>>>(Yl, rowptr, csrc, bl1, Yr, Hb, N);

  // G = H2 @ Wo1 (bf16 output)
  k_gemm1<<<(N + 63) / 64, 256, 0, stream>>>(Hb, Wo1, Gb, N);

  // MFMA edge pipeline v2
  const int nT = (E + 15) / 16;
  const int blocks = 2048;
  k_edge3<<<blocks, 256, 0, stream>>>(eattr, src, tgt, Gb, We1T, W25T, cvec,
                                      be1, Wo2, bo2, out, E, nT, blocks * 4);
}

// Round 9
// 510.026 us; speedup vs baseline: 2.4013x; 1.0570x over previous
//
#include <hip/hip_runtime.h>
#include <math.h>

typedef __attribute__((ext_vector_type(8))) short short8;
typedef __attribute__((ext_vector_type(4))) float f32x4;

static __device__ __forceinline__ unsigned short f2bf(float f) {
  union { float f; unsigned int u; } x; x.f = f;
  unsigned int r = x.u + 0x7fffu + ((x.u >> 16) & 1u);  // RNE
  return (unsigned short)(r >> 16);
}
static __device__ __forceinline__ float bf2f(unsigned int u) {
  union { unsigned int u; float f; } x; x.u = u << 16; return x.f;
}

// ---------------------------------------------------------------------------
// int64-vs-int32 edge_index detection.
__global__ void k_flag(const unsigned int* __restrict__ w, int nSample,
                       unsigned int* __restrict__ flag) {
  __shared__ unsigned int red[256];
  unsigned int v = 0;
  for (int i = threadIdx.x; i < nSample; i += 256) v |= w[2 * i + 1];
  red[threadIdx.x] = v;
  __syncthreads();
  for (int s = 128; s > 0; s >>= 1) {
    if (threadIdx.x < s) red[threadIdx.x] |= red[threadIdx.x + s];
    __syncthreads();
  }
  if (threadIdx.x == 0) flag[0] = red[0];  // nonzero => int32 layout
}

__global__ void k_decode(const unsigned int* __restrict__ w,
                         const unsigned int* __restrict__ flag, int E,
                         int* __restrict__ src, int* __restrict__ tgt,
                         int* __restrict__ deg) {
  int e = blockIdx.x * 256 + threadIdx.x;
  if (e >= E) return;
  int s, t;
  if (flag[0]) { s = (int)w[e]; t = (int)w[E + e]; }
  else         { s = (int)w[2 * e]; t = (int)w[2 * (E + e)]; }
  src[e] = s;
  tgt[e] = t;
  atomicAdd(deg + t, 1);
}

// ---------------------------------------------------------------------------
// Hierarchical exclusive scan of deg[padN] (padN multiple of 2048, pad=0).
__global__ __launch_bounds__(256) void k_scan1(const int* __restrict__ deg,
                                               int* __restrict__ bsum) {
  __shared__ int wsum[4];
  const int tid = threadIdx.x, lane = tid & 63, wid = tid >> 6;
  const int base = blockIdx.x * 2048 + tid * 8;
  int4 v0 = *(const int4*)(deg + base);
  int4 v1 = *(const int4*)(deg + base + 4);
  int s = v0.x + v0.y + v0.z + v0.w + v1.x + v1.y + v1.z + v1.w;
#pragma unroll
  for (int off = 1; off < 64; off <<= 1) s += __shfl_xor(s, off, 64);
  if (lane == 0) wsum[wid] = s;
  __syncthreads();
  if (tid == 0) bsum[blockIdx.x] = wsum[0] + wsum[1] + wsum[2] + wsum[3];
}

__global__ void k_scan2(const int* __restrict__ bsum, int* __restrict__ boff,
                        int nB, int* __restrict__ rowptrN) {
  int lane = threadIdx.x;
  int v = (lane < nB) ? bsum[lane] : 0;
  int incl = v;
#pragma unroll
  for (int off = 1; off < 64; off <<= 1) {
    int t = __shfl_up(incl, off, 64);
    if (lane >= off) incl += t;
  }
  if (lane < nB) boff[lane] = incl - v;
  if (lane == 63) *rowptrN = incl;   // total = E
}

__global__ __launch_bounds__(256) void k_scan3(const int* __restrict__ deg,
                                               const int* __restrict__ boff,
                                               int* __restrict__ rowptr,
                                               int* __restrict__ cursor) {
  __shared__ int wsum[4];
  const int tid = threadIdx.x, lane = tid & 63, wid = tid >> 6;
  const int base = blockIdx.x * 2048 + tid * 8;
  int4 v0 = *(const int4*)(deg + base);
  int4 v1 = *(const int4*)(deg + base + 4);
  int e[8] = {v0.x, v0.y, v0.z, v0.w, v1.x, v1.y, v1.z, v1.w};
  int s = e[0] + e[1] + e[2] + e[3] + e[4] + e[5] + e[6] + e[7];
  int incl = s;
#pragma unroll
  for (int off = 1; off < 64; off <<= 1) {
    int t = __shfl_up(incl, off, 64);
    if (lane >= off) incl += t;
  }
  if (lane == 63) wsum[wid] = incl;
  __syncthreads();
  int run = boff[blockIdx.x] + (incl - s);
  for (int w = 0; w < wid; ++w) run += wsum[w];
  int o[8];
#pragma unroll
  for (int i = 0; i < 8; ++i) { o[i] = run; run += e[i]; }
  int4 a = make_int4(o[0], o[1], o[2], o[3]);
  int4 b = make_int4(o[4], o[5], o[6], o[7]);
  *(int4*)(rowptr + base) = a;  *(int4*)(rowptr + base + 4) = b;
  *(int4*)(cursor + base) = a;  *(int4*)(cursor + base + 4) = b;
}

__global__ void k_fill(const int* __restrict__ src, const int* __restrict__ tgt,
                       int* __restrict__ cursor, int* __restrict__ csrc, int E) {
  int e = blockIdx.x * 256 + threadIdx.x;
  if (e >= E) return;
  int pos = atomicAdd(cursor + tgt[e], 1);
  csrc[pos] = src[e];
}

// ---------------------------------------------------------------------------
// Weight transpose for MFMA node GEMM: WnT[n][k] bf16, n in [0,128) over
// [W0|W1] (each [K,64]).
template <int K>
__global__ void k_prep2(const float* __restrict__ W0,
                        const float* __restrict__ W1,
                        unsigned short* __restrict__ WnT) {
  int idx = blockIdx.x * 256 + threadIdx.x;
  if (idx >= 128 * K) return;
  int n = idx / K, k = idx % K;
  float v = (n < 64) ? W0[(size_t)k * 64 + n] : W1[(size_t)k * 64 + (n - 64)];
  WnT[idx] = f2bf(v);
}

// MFMA node GEMM, bf16 output. BF16IN: X is bf16 [N,K] else f32 [N,K].
// NTILES=2: cols [W0|W1]=128, wave wv covers cols wv*32..+32, writes Y0/Y1.
// NTILES=1: 64 cols, wave wv covers cols wv*16..+16, writes Y0.
// MFMA layouts (gfx950, verified): A[m=lane&15][k=(lane>>4)*8+j],
// B[k][n=lane&15] (frag = WnT[n][k] contig in k), C/D col=lane&15,
// row=(lane>>4)*4+reg.
template <int K, bool BF16IN, int NTILES>
__global__ __launch_bounds__(256) void k_ngemm(
    const void* __restrict__ Xv, const unsigned short* __restrict__ WnT,
    unsigned short* __restrict__ Y0, unsigned short* __restrict__ Y1, int N) {
  constexpr int STR = K + 8;   // +16B pad: 2-way banks max, b128 aligned
  constexpr int NC = K / 32;
  __shared__ unsigned short sX[64 * STR];
  const int tid = threadIdx.x;
  const int wv = tid >> 6, lane = tid & 63;
  const int m = lane & 15, q = lane >> 4;
  const int row0 = blockIdx.x * 64;

  // persistent B fragments
  short8 bB[NTILES][NC];
#pragma unroll
  for (int ct = 0; ct < NTILES; ++ct)
#pragma unroll
    for (int c = 0; c < NC; ++c) {
      int n = (NTILES == 2) ? (wv * 32 + ct * 16 + m) : (wv * 16 + m);
      bB[ct][c] = *(const short8*)(WnT + (size_t)n * K + c * 32 + q * 8);
    }

  // stage X rows into LDS as bf16
#pragma unroll
  for (int i = 0; i < K / 16; ++i) {
    int f = tid + 256 * i;
    int r = f / (K / 4);
    int c4 = f % (K / 4);
    int rr = row0 + r; if (rr >= N) rr = N - 1;
    uint2 pk;
    if constexpr (BF16IN) {
      pk = *(const uint2*)((const unsigned short*)Xv + (size_t)rr * K + c4 * 4);
    } else {
      float4 v = *(const float4*)((const float*)Xv + (size_t)rr * K + c4 * 4);
      pk.x = (unsigned int)f2bf(v.x) | ((unsigned int)f2bf(v.y) << 16);
      pk.y = (unsigned int)f2bf(v.z) | ((unsigned int)f2bf(v.w) << 16);
    }
    *(uint2*)(sX + r * STR + c4 * 4) = pk;
  }
  __syncthreads();

  f32x4 acc[4][NTILES];
#pragma unroll
  for (int rt = 0; rt < 4; ++rt)
#pragma unroll
    for (int ct = 0; ct < NTILES; ++ct)
#pragma unroll
      for (int r = 0; r < 4; ++r) acc[rt][ct][r] = 0.f;

#pragma unroll
  for (int c = 0; c < NC; ++c) {
    short8 a[4];
#pragma unroll
    for (int rt = 0; rt < 4; ++rt)
      a[rt] = *(const short8*)(sX + (rt * 16 + m) * STR + c * 32 + q * 8);
#pragma unroll
    for (int rt = 0; rt < 4; ++rt)
#pragma unroll
      for (int ct = 0; ct < NTILES; ++ct)
        acc[rt][ct] = __builtin_amdgcn_mfma_f32_16x16x32_bf16(a[rt], bB[ct][c], acc[rt][ct], 0, 0, 0);
  }

#pragma unroll
  for (int rt = 0; rt < 4; ++rt)
#pragma unroll
    for (int ct = 0; ct < NTILES; ++ct) {
      unsigned short* Yw;
      int n;
      if constexpr (NTILES == 2) {
        Yw = (wv < 2) ? Y0 : Y1;
        n = (wv & 1) * 32 + ct * 16 + m;
      } else {
        Yw = Y0;
        n = wv * 16 + m;
      }
#pragma unroll
      for (int reg = 0; reg < 4; ++reg) {
        int row = row0 + rt * 16 + q * 4 + reg;
        if (row < N) Yw[(size_t)row * 64 + n] = f2bf(acc[rt][ct][reg]);
      }
    }
}

// W25T (bf16,[n][k]) = (We2@Wo1)^T; We1T (bf16,[n][k],K pad 16->32);
// Wo1T (bf16,[n][k]); cvec = be2@Wo1 + bo1. One block, inputs in LDS.
__global__ __launch_bounds__(256) void k_prep(
    const float* __restrict__ We2, const float* __restrict__ Wo1,
    const float* __restrict__ be2, const float* __restrict__ bo1,
    const float* __restrict__ We1,
    unsigned short* __restrict__ W25T, unsigned short* __restrict__ We1T,
    unsigned short* __restrict__ Wo1T, float* __restrict__ cvec) {
  __shared__ float sA[4096];  // We2
  __shared__ float sB[4096];  // Wo1
  int tid = threadIdx.x;
  for (int i = tid; i < 1024; i += 256) {
    *(float4*)&sA[i * 4] = *(const float4*)(We2 + i * 4);
    *(float4*)&sB[i * 4] = *(const float4*)(Wo1 + i * 4);
  }
  __syncthreads();
  for (int idx = tid; idx < 4096; idx += 256) {
    int n = idx >> 6, k = idx & 63;
    float s = 0.f;
#pragma unroll 8
    for (int mm = 0; mm < 64; ++mm) s = fmaf(sA[k * 64 + mm], sB[mm * 64 + n], s);
    W25T[idx] = f2bf(s);
    Wo1T[idx] = f2bf(sB[k * 64 + n]);
  }
  for (int idx = tid; idx < 2048; idx += 256) {
    int n = idx >> 5, k = idx & 31;
    We1T[n * 32 + k] = (k < 16) ? f2bf(We1[k * 64 + n]) : (unsigned short)0;
  }
  if (tid < 64) {
    float s = bo1[tid];
#pragma unroll 8
    for (int mm = 0; mm < 64; ++mm) s = fmaf(be2[mm], sB[mm * 64 + tid], s);
    cvec[tid] = s;
  }
}

// CSR aggregate fused with epilogue: H = relu(sum/deg + bias + Yr).
// All node features bf16 (rows 128B); f32 accumulation.
__global__ __launch_bounds__(256) void k_agg(
    const unsigned short* __restrict__ Y, const int* __restrict__ rowptr,
    const int* __restrict__ csrc, const float* __restrict__ bias,
    const unsigned short* __restrict__ Yr, unsigned short* __restrict__ H,
    int N) {
  int node = (blockIdx.x * 256 + threadIdx.x) >> 6;
  if (node >= N) return;
  const int lane = threadIdx.x & 63;
  const int c4 = lane & 15, rr = lane >> 4;
  int beg = rowptr[node], end = rowptr[node + 1];
  float a0 = 0.f, a1 = 0.f, a2 = 0.f, a3 = 0.f;
  float b0 = 0.f, b1 = 0.f, b2 = 0.f, b3 = 0.f;
  for (int e = beg; e < end; e += 8) {
    int e0 = e + rr, e1 = e + 4 + rr;
    if (e0 < end) {
      int s = csrc[e0];
      uint2 v = *(const uint2*)(Y + (size_t)s * 64 + c4 * 4);
      a0 += bf2f(v.x & 0xffffu); a1 += bf2f(v.x >> 16);
      a2 += bf2f(v.y & 0xffffu); a3 += bf2f(v.y >> 16);
    }
    if (e1 < end) {
      int s = csrc[e1];
      uint2 v = *(const uint2*)(Y + (size_t)s * 64 + c4 * 4);
      b0 += bf2f(v.x & 0xffffu); b1 += bf2f(v.x >> 16);
      b2 += bf2f(v.y & 0xffffu); b3 += bf2f(v.y >> 16);
    }
  }
  a0 += b0; a1 += b1; a2 += b2; a3 += b3;
#pragma unroll
  for (int msk = 16; msk <= 32; msk <<= 1) {
    a0 += __shfl_xor(a0, msk, 64);
    a1 += __shfl_xor(a1, msk, 64);
    a2 += __shfl_xor(a2, msk, 64);
    a3 += __shfl_xor(a3, msk, 64);
  }
  if (rr == 0) {
    float cdeg = (float)(end - beg);
    if (cdeg < 1.f) cdeg = 1.f;
    float inv = 1.f / cdeg;
    float4 bv = *(const float4*)(bias + c4 * 4);
    uint2 yv = *(const uint2*)(Yr + (size_t)node * 64 + c4 * 4);
    float o0 = fmaxf(a0 * inv + bv.x + bf2f(yv.x & 0xffffu), 0.f);
    float o1 = fmaxf(a1 * inv + bv.y + bf2f(yv.x >> 16), 0.f);
    float o2 = fmaxf(a2 * inv + bv.z + bf2f(yv.y & 0xffffu), 0.f);
    float o3 = fmaxf(a3 * inv + bv.w + bf2f(yv.y >> 16), 0.f);
    uint2 pk;
    pk.x = (unsigned int)f2bf(o0) | ((unsigned int)f2bf(o1) << 16);
    pk.y = (unsigned int)f2bf(o2) | ((unsigned int)f2bf(o3) << 16);
    *(uint2*)(H + (size_t)node * 64 + c4 * 4) = pk;
  }
}

// ---------------------------------------------------------------------------
// MFMA edge pipeline v2 (unchanged from R8). Wave-independent 16-edge tiles.
#define T1_STRIDE 72
#define G_STRIDE 68
__global__ __launch_bounds__(256) void k_edge3(
    const float* __restrict__ eattr, const int* __restrict__ src,
    const int* __restrict__ tgt, const unsigned short* __restrict__ Gb,
    const unsigned short* __restrict__ We1T,
    const unsigned short* __restrict__ W25T,
    const float* __restrict__ cvec, const float* __restrict__ be1,
    const float* __restrict__ Wo2, const float* __restrict__ bo2,
    float* __restrict__ out, int E, int nT, int nWaves) {
  __shared__ unsigned short sT1a[4][16 * T1_STRIDE];
  __shared__ float sGa[4][16 * G_STRIDE];
  const int tid = threadIdx.x;
  const int wid = tid >> 6, lane = tid & 63;
  const int m = lane & 15, q = lane >> 4;
  unsigned short* sT1 = sT1a[wid];
  float* sG = sGa[wid];

  short8 bWe1[4], bW25[4][2];
  float cv[4], wo2v[4], be1v[4];
#pragma unroll
  for (int nt = 0; nt < 4; ++nt) {
    int n = nt * 16 + m;
    bWe1[nt] = *(const short8*)(We1T + n * 32 + q * 8);
    bW25[nt][0] = *(const short8*)(W25T + n * 64 + q * 8);
    bW25[nt][1] = *(const short8*)(W25T + n * 64 + 32 + q * 8);
    cv[nt] = cvec[n];
    wo2v[nt] = Wo2[n];
    be1v[nt] = be1[n];
  }
  const float b_out = bo2[0];
  const short8 zfrag = {};

  int t = blockIdx.x * 4 + wid;
  if (t >= nT) return;
  int il = t * 16 + m; if (il >= E) il = E - 1;
  int my_idx = (lane < 16) ? src[il] : ((lane < 32) ? tgt[il] : 0);

  while (true) {
    const int base = t * 16;
    const int tn = t + nWaves;
    const bool last = (tn >= nT);
    const int tc = last ? t : tn;

    int il_n = tc * 16 + m; if (il_n >= E) il_n = E - 1;
    int idx_n = (lane < 16) ? src[il_n] : ((lane < 32) ? tgt[il_n] : 0);

    // coalesced G row gathers: quad q owns edges q*4..q*4+3
    int rs[4], rt[4];
#pragma unroll
    for (int r = 0; r < 4; ++r) {
      rs[r] = __shfl(my_idx, q * 4 + r, 64);
      rt[r] = __shfl(my_idx, 16 + q * 4 + r, 64);
    }
    uint2 sv[4], tv[4];
#pragma unroll
    for (int r = 0; r < 4; ++r) {
      sv[r] = *(const uint2*)(Gb + (size_t)rs[r] * 64 + m * 4);
      tv[r] = *(const uint2*)(Gb + (size_t)rt[r] * 64 + m * 4);
    }

    // EA A-fragment direct from global
    int er = base + m; if (er >= E) er = E - 1;
    const float* ep = eattr + (size_t)er * 16 + (q & 1) * 8;
    float4 e0 = *(const float4*)ep;
    float4 e1 = *(const float4*)(ep + 4);
    short8 aEA;
    {
      union { short8 s; unsigned int u[4]; } ua;
      ua.u[0] = (unsigned int)f2bf(e0.x) | ((unsigned int)f2bf(e0.y) << 16);
      ua.u[1] = (unsigned int)f2bf(e0.z) | ((unsigned int)f2bf(e0.w) << 16);
      ua.u[2] = (unsigned int)f2bf(e1.x) | ((unsigned int)f2bf(e1.y) << 16);
      ua.u[3] = (unsigned int)f2bf(e1.z) | ((unsigned int)f2bf(e1.w) << 16);
      aEA = (q < 2) ? ua.s : zfrag;
    }

    // MFMA1: t1 = relu(EA @ We1 + be1)
    f32x4 t1[4];
#pragma unroll
    for (int nt = 0; nt < 4; ++nt) {
      f32x4 cinit; cinit[0] = be1v[nt]; cinit[1] = be1v[nt];
      cinit[2] = be1v[nt]; cinit[3] = be1v[nt];
      t1[nt] = __builtin_amdgcn_mfma_f32_16x16x32_bf16(aEA, bWe1[nt], cinit, 0, 0, 0);
    }
#pragma unroll
    for (int nt = 0; nt < 4; ++nt)
#pragma unroll
      for (int r = 0; r < 4; ++r)
        sT1[(q * 4 + r) * T1_STRIDE + nt * 16 + m] = f2bf(fmaxf(t1[nt][r], 0.f));
    short8 aT0 = *(short8*)(sT1 + m * T1_STRIDE + q * 8);
    short8 aT1 = *(short8*)(sT1 + m * T1_STRIDE + 32 + q * 8);

    // Gsum -> sG (f32): lane holds feats 4m..4m+3 of edge q*4+r
#pragma unroll
    for (int r = 0; r < 4; ++r) {
      f32x4 g;
      g[0] = bf2f(sv[r].x & 0xffffu) + bf2f(tv[r].x & 0xffffu);
      g[1] = bf2f(sv[r].x >> 16)     + bf2f(tv[r].x >> 16);
      g[2] = bf2f(sv[r].y & 0xffffu) + bf2f(tv[r].y & 0xffffu);
      g[3] = bf2f(sv[r].y >> 16)     + bf2f(tv[r].y >> 16);
      *(f32x4*)(sG + (q * 4 + r) * G_STRIDE + m * 4) = g;
    }

    // acc init (C layout) + MFMA2
    f32x4 acc[4];
#pragma unroll
    for (int nt = 0; nt < 4; ++nt)
#pragma unroll
      for (int r = 0; r < 4; ++r)
        acc[nt][r] = cv[nt] + sG[(q * 4 + r) * G_STRIDE + nt * 16 + m];
#pragma unroll
    for (int nt = 0; nt < 4; ++nt) {
      acc[nt] = __builtin_amdgcn_mfma_f32_16x16x32_bf16(aT0, bW25[nt][0], acc[nt], 0, 0, 0);
      acc[nt] = __builtin_amdgcn_mfma_f32_16x16x32_bf16(aT1, bW25[nt][1], acc[nt], 0, 0, 0);
    }

    // epilogue
    float p[4];
#pragma unroll
    for (int r = 0; r < 4; ++r) {
      p[r] = fmaxf(acc[0][r], 0.f) * wo2v[0] + fmaxf(acc[1][r], 0.f) * wo2v[1] +
             fmaxf(acc[2][r], 0.f) * wo2v[2] + fmaxf(acc[3][r], 0.f) * wo2v[3];
    }
#pragma unroll
    for (int msk = 1; msk <= 8; msk <<= 1) {
#pragma unroll
      for (int r = 0; r < 4; ++r) p[r] += __shfl_xor(p[r], msk, 64);
    }
    if (m == 0) {
#pragma unroll
      for (int r = 0; r < 4; ++r) {
        int row = base + q * 4 + r;
        if (row < E) out[row] = 1.f / (1.f + __expf(-(p[r] + b_out)));
      }
    }

    if (last) break;
    t = tn; my_idx = idx_n;
  }
}

// ---------------------------------------------------------------------------
extern "C" void kernel_launch(void* const* d_in, const int* in_sizes, int n_in,
                              void* d_out, int out_size, void* d_ws, size_t ws_size,
                              hipStream_t stream) {
  const float* x     = (const float*)d_in[0];
  const unsigned int* eidx = (const unsigned int*)d_in[1];
  const float* eattr = (const float*)d_in[2];
  const float* We1 = (const float*)d_in[3];
  const float* be1 = (const float*)d_in[4];
  const float* We2 = (const float*)d_in[5];
  const float* be2 = (const float*)d_in[6];
  const float* Wl0 = (const float*)d_in[7];
  const float* bl0 = (const float*)d_in[8];
  const float* Wr0 = (const float*)d_in[9];
  const float* Wl1 = (const float*)d_in[10];
  const float* bl1 = (const float*)d_in[11];
  const float* Wr1 = (const float*)d_in[12];
  const float* Wo1 = (const float*)d_in[13];
  const float* bo1 = (const float*)d_in[14];
  const float* Wo2 = (const float*)d_in[15];
  const float* bo2 = (const float*)d_in[16];

  const int N = in_sizes[0] / 128;   // 100000
  const int E = in_sizes[2] / 16;    // 1000000
  const int padN = (N + 2047) & ~2047;
  const int nB = padN / 2048;
  float* out = (float*)d_out;

  char* ws = (char*)d_ws;
  size_t off = 0;
  auto alloc = [&](size_t bytes) {
    char* p = ws + off;
    off += (bytes + 255) & ~(size_t)255;
    return p;
  };
  unsigned int* flag = (unsigned int*)alloc(256);
  int* src    = (int*)alloc((size_t)E * 4);
  int* tgt    = (int*)alloc((size_t)E * 4);
  int* deg    = (int*)alloc((size_t)padN * 4);
  int* rowptr = (int*)alloc((size_t)(padN + 64) * 4);
  int* cursor = (int*)alloc((size_t)padN * 4);
  int* bsum   = (int*)alloc(64 * 4);
  int* boff   = (int*)alloc(64 * 4);
  int* csrc   = (int*)alloc((size_t)E * 4);
  unsigned short* Hb = (unsigned short*)alloc((size_t)N * 64 * 2);
  unsigned short* Yl = (unsigned short*)alloc((size_t)N * 64 * 2);
  unsigned short* Yr = (unsigned short*)alloc((size_t)N * 64 * 2);
  unsigned short* Gb = (unsigned short*)alloc((size_t)N * 64 * 2);
  unsigned short* W25T = (unsigned short*)alloc(64 * 64 * 2);
  unsigned short* We1T = (unsigned short*)alloc(64 * 32 * 2);
  unsigned short* Wo1T = (unsigned short*)alloc(64 * 64 * 2);
  unsigned short* WnT0 = (unsigned short*)alloc(128 * 128 * 2);
  unsigned short* WnT1 = (unsigned short*)alloc(128 * 64 * 2);
  float* cvec = (float*)alloc(64 * 4);
  (void)ws_size; (void)n_in; (void)out_size;

  hipMemsetAsync(deg, 0, (size_t)padN * 4, stream);

  k_flag<<<1, 256, 0, stream>>>(eidx, 8192, flag);
  k_decode<<<(E + 255) / 256, 256, 0, stream>>>(eidx, flag, E, src, tgt, deg);
  k_scan1<<<nB, 256, 0, stream>>>(deg, bsum);
  k_scan2<<<1, 64, 0, stream>>>(bsum, boff, nB, rowptr + N);
  k_scan3<<<nB, 256, 0, stream>>>(deg, boff, rowptr, cursor);
  k_fill<<<(E + 255) / 256, 256, 0, stream>>>(src, tgt, cursor, csrc, E);
  k_prep<<<1, 256, 0, stream>>>(We2, Wo1, be2, bo1, We1, W25T, We1T, Wo1T, cvec);
  k_prep2<128><<<64, 256, 0, stream>>>(Wl0, Wr0, WnT0);
  k_prep2<64><<<32, 256, 0, stream>>>(Wl1, Wr1, WnT1);

  const int gB = (N + 63) / 64;
  // Layer 0 (project-then-aggregate: mean is linear) — MFMA, bf16 out
  k_ngemm<128, false, 2><<<gB, 256, 0, stream>>>(x, WnT0, Yl, Yr, N);
  k_agg<<<(N + 3) / 4, 256, 0, stream>>>(Yl, rowptr, csrc, bl0, Yr, Hb, N);

  // Layer 1 — MFMA, bf16 in/out
  k_ngemm<64, true, 2><<<gB, 256, 0, stream>>>(Hb, WnT1, Yl, Yr, N);
  k_agg<<<(N + 3) / 4, 256, 0, stream>>>(Yl, rowptr, csrc, bl1, Yr, Hb, N);

  // G = H2 @ Wo1 — MFMA, bf16 in/out
  k_ngemm<64, true, 1><<<gB, 256, 0, stream>>>(Hb, Wo1T, Gb, nullptr, N);

  // MFMA edge pipeline
  const int nT = (E + 15) / 16;
  const int blocks = 2048;
  k_edge3<<<blocks, 256, 0, stream>>>(eattr, src, tgt, Gb, We1T, W25T, cvec,
                                      be1, Wo2, bo2, out, E, nT, blocks * 4);
}

// Round 10
// 455.829 us; speedup vs baseline: 2.6868x; 1.1189x over previous
//
#include <hip/hip_runtime.h>
#include <math.h>

typedef __attribute__((ext_vector_type(8))) short short8;
typedef __attribute__((ext_vector_type(4))) float f32x4;

static __device__ __forceinline__ unsigned short f2bf(float f) {
  union { float f; unsigned int u; } x; x.f = f;
  unsigned int r = x.u + 0x7fffu + ((x.u >> 16) & 1u);  // RNE
  return (unsigned short)(r >> 16);
}
static __device__ __forceinline__ float bf2f(unsigned int u) {
  union { unsigned int u; float f; } x; x.u = u << 16; return x.f;
}

// ---------------------------------------------------------------------------
// int64-vs-int32 edge_index detection.
__global__ void k_flag(const unsigned int* __restrict__ w, int nSample,
                       unsigned int* __restrict__ flag) {
  __shared__ unsigned int red[256];
  unsigned int v = 0;
  for (int i = threadIdx.x; i < nSample; i += 256) v |= w[2 * i + 1];
  red[threadIdx.x] = v;
  __syncthreads();
  for (int s = 128; s > 0; s >>= 1) {
    if (threadIdx.x < s) red[threadIdx.x] |= red[threadIdx.x + s];
    __syncthreads();
  }
  if (threadIdx.x == 0) flag[0] = red[0];  // nonzero => int32 layout
}

// Decode + degree count + PER-EDGE RANK (atomic return) so the CSR fill
// needs no atomics (R9: k_fill was 77us of pure atomic-return latency).
__global__ void k_decode(const unsigned int* __restrict__ w,
                         const unsigned int* __restrict__ flag, int E,
                         int* __restrict__ src, int* __restrict__ tgt,
                         int* __restrict__ posin, int* __restrict__ deg) {
  int e = blockIdx.x * 256 + threadIdx.x;
  if (e >= E) return;
  int s, t;
  if (flag[0]) { s = (int)w[e]; t = (int)w[E + e]; }
  else         { s = (int)w[2 * e]; t = (int)w[2 * (E + e)]; }
  src[e] = s;
  tgt[e] = t;
  posin[e] = atomicAdd(deg + t, 1);
}

// ---------------------------------------------------------------------------
// Hierarchical exclusive scan of deg[padN] (padN multiple of 2048, pad=0).
__global__ __launch_bounds__(256) void k_scan1(const int* __restrict__ deg,
                                               int* __restrict__ bsum) {
  __shared__ int wsum[4];
  const int tid = threadIdx.x, lane = tid & 63, wid = tid >> 6;
  const int base = blockIdx.x * 2048 + tid * 8;
  int4 v0 = *(const int4*)(deg + base);
  int4 v1 = *(const int4*)(deg + base + 4);
  int s = v0.x + v0.y + v0.z + v0.w + v1.x + v1.y + v1.z + v1.w;
#pragma unroll
  for (int off = 1; off < 64; off <<= 1) s += __shfl_xor(s, off, 64);
  if (lane == 0) wsum[wid] = s;
  __syncthreads();
  if (tid == 0) bsum[blockIdx.x] = wsum[0] + wsum[1] + wsum[2] + wsum[3];
}

__global__ void k_scan2(const int* __restrict__ bsum, int* __restrict__ boff,
                        int nB, int* __restrict__ rowptrN) {
  int lane = threadIdx.x;
  int v = (lane < nB) ? bsum[lane] : 0;
  int incl = v;
#pragma unroll
  for (int off = 1; off < 64; off <<= 1) {
    int t = __shfl_up(incl, off, 64);
    if (lane >= off) incl += t;
  }
  if (lane < nB) boff[lane] = incl - v;
  if (lane == 63) *rowptrN = incl;   // total = E
}

__global__ __launch_bounds__(256) void k_scan3(const int* __restrict__ deg,
                                               const int* __restrict__ boff,
                                               int* __restrict__ rowptr) {
  __shared__ int wsum[4];
  const int tid = threadIdx.x, lane = tid & 63, wid = tid >> 6;
  const int base = blockIdx.x * 2048 + tid * 8;
  int4 v0 = *(const int4*)(deg + base);
  int4 v1 = *(const int4*)(deg + base + 4);
  int e[8] = {v0.x, v0.y, v0.z, v0.w, v1.x, v1.y, v1.z, v1.w};
  int s = e[0] + e[1] + e[2] + e[3] + e[4] + e[5] + e[6] + e[7];
  int incl = s;
#pragma unroll
  for (int off = 1; off < 64; off <<= 1) {
    int t = __shfl_up(incl, off, 64);
    if (lane >= off) incl += t;
  }
  if (lane == 63) wsum[wid] = incl;
  __syncthreads();
  int run = boff[blockIdx.x] + (incl - s);
  for (int w = 0; w < wid; ++w) run += wsum[w];
  int o[8];
#pragma unroll
  for (int i = 0; i < 8; ++i) { o[i] = run; run += e[i]; }
  *(int4*)(rowptr + base) = make_int4(o[0], o[1], o[2], o[3]);
  *(int4*)(rowptr + base + 4) = make_int4(o[4], o[5], o[6], o[7]);
}

// Atomic-free CSR fill: position precomputed as rowptr[tgt] + rank.
__global__ void k_fill(const int* __restrict__ src, const int* __restrict__ tgt,
                       const int* __restrict__ posin,
                       const int* __restrict__ rowptr,
                       int* __restrict__ csrc, int E) {
  int e = blockIdx.x * 256 + threadIdx.x;
  if (e >= E) return;
  csrc[rowptr[tgt[e]] + posin[e]] = src[e];
}

// ---------------------------------------------------------------------------
// Weight transpose for MFMA node GEMM: WnT[n][k] bf16, n in [0,128) over
// [W0|W1] (each [K,64]).
template <int K>
__global__ void k_prep2(const float* __restrict__ W0,
                        const float* __restrict__ W1,
                        unsigned short* __restrict__ WnT) {
  int idx = blockIdx.x * 256 + threadIdx.x;
  if (idx >= 128 * K) return;
  int n = idx / K, k = idx % K;
  float v = (n < 64) ? W0[(size_t)k * 64 + n] : W1[(size_t)k * 64 + (n - 64)];
  WnT[idx] = f2bf(v);
}

// MFMA node GEMM, bf16 output. BF16IN: X is bf16 [N,K] else f32 [N,K].
// NTILES=2: cols [W0|W1]=128, wave wv covers cols wv*32..+32, writes Y0/Y1.
// NTILES=1: 64 cols, wave wv covers cols wv*16..+16, writes Y0.
// MFMA layouts (gfx950, verified): A[m=lane&15][k=(lane>>4)*8+j],
// B[k][n=lane&15] (frag = WnT[n][k] contig in k), C/D col=lane&15,
// row=(lane>>4)*4+reg.
template <int K, bool BF16IN, int NTILES>
__global__ __launch_bounds__(256) void k_ngemm(
    const void* __restrict__ Xv, const unsigned short* __restrict__ WnT,
    unsigned short* __restrict__ Y0, unsigned short* __restrict__ Y1, int N) {
  constexpr int STR = K + 8;   // +16B pad: 2-way banks max, b128 aligned
  constexpr int NC = K / 32;
  __shared__ unsigned short sX[64 * STR];
  const int tid = threadIdx.x;
  const int wv = tid >> 6, lane = tid & 63;
  const int m = lane & 15, q = lane >> 4;
  const int row0 = blockIdx.x * 64;

  short8 bB[NTILES][NC];
#pragma unroll
  for (int ct = 0; ct < NTILES; ++ct)
#pragma unroll
    for (int c = 0; c < NC; ++c) {
      int n = (NTILES == 2) ? (wv * 32 + ct * 16 + m) : (wv * 16 + m);
      bB[ct][c] = *(const short8*)(WnT + (size_t)n * K + c * 32 + q * 8);
    }

#pragma unroll
  for (int i = 0; i < K / 16; ++i) {
    int f = tid + 256 * i;
    int r = f / (K / 4);
    int c4 = f % (K / 4);
    int rr = row0 + r; if (rr >= N) rr = N - 1;
    uint2 pk;
    if constexpr (BF16IN) {
      pk = *(const uint2*)((const unsigned short*)Xv + (size_t)rr * K + c4 * 4);
    } else {
      float4 v = *(const float4*)((const float*)Xv + (size_t)rr * K + c4 * 4);
      pk.x = (unsigned int)f2bf(v.x) | ((unsigned int)f2bf(v.y) << 16);
      pk.y = (unsigned int)f2bf(v.z) | ((unsigned int)f2bf(v.w) << 16);
    }
    *(uint2*)(sX + r * STR + c4 * 4) = pk;
  }
  __syncthreads();

  f32x4 acc[4][NTILES];
#pragma unroll
  for (int rt = 0; rt < 4; ++rt)
#pragma unroll
    for (int ct = 0; ct < NTILES; ++ct)
#pragma unroll
      for (int r = 0; r < 4; ++r) acc[rt][ct][r] = 0.f;

#pragma unroll
  for (int c = 0; c < NC; ++c) {
    short8 a[4];
#pragma unroll
    for (int rt = 0; rt < 4; ++rt)
      a[rt] = *(const short8*)(sX + (rt * 16 + m) * STR + c * 32 + q * 8);
#pragma unroll
    for (int rt = 0; rt < 4; ++rt)
#pragma unroll
      for (int ct = 0; ct < NTILES; ++ct)
        acc[rt][ct] = __builtin_amdgcn_mfma_f32_16x16x32_bf16(a[rt], bB[ct][c], acc[rt][ct], 0, 0, 0);
  }

#pragma unroll
  for (int rt = 0; rt < 4; ++rt)
#pragma unroll
    for (int ct = 0; ct < NTILES; ++ct) {
      unsigned short* Yw;
      int n;
      if constexpr (NTILES == 2) {
        Yw = (wv < 2) ? Y0 : Y1;
        n = (wv & 1) * 32 + ct * 16 + m;
      } else {
        Yw = Y0;
        n = wv * 16 + m;
      }
#pragma unroll
      for (int reg = 0; reg < 4; ++reg) {
        int row = row0 + rt * 16 + q * 4 + reg;
        if (row < N) Yw[(size_t)row * 64 + n] = f2bf(acc[rt][ct][reg]);
      }
    }
}

// W25T (bf16,[n][k]) = (We2@Wo1)^T; We1T (bf16,[n][k],K pad 16->32);
// Wo1T (bf16,[n][k]); cvec = be2@Wo1 + bo1. One block, inputs in LDS.
__global__ __launch_bounds__(256) void k_prep(
    const float* __restrict__ We2, const float* __restrict__ Wo1,
    const float* __restrict__ be2, const float* __restrict__ bo1,
    const float* __restrict__ We1,
    unsigned short* __restrict__ W25T, unsigned short* __restrict__ We1T,
    unsigned short* __restrict__ Wo1T, float* __restrict__ cvec) {
  __shared__ float sA[4096];  // We2
  __shared__ float sB[4096];  // Wo1
  int tid = threadIdx.x;
  for (int i = tid; i < 1024; i += 256) {
    *(float4*)&sA[i * 4] = *(const float4*)(We2 + i * 4);
    *(float4*)&sB[i * 4] = *(const float4*)(Wo1 + i * 4);
  }
  __syncthreads();
  for (int idx = tid; idx < 4096; idx += 256) {
    int n = idx >> 6, k = idx & 63;
    float s = 0.f;
#pragma unroll 8
    for (int mm = 0; mm < 64; ++mm) s = fmaf(sA[k * 64 + mm], sB[mm * 64 + n], s);
    W25T[idx] = f2bf(s);
    Wo1T[idx] = f2bf(sB[k * 64 + n]);
  }
  for (int idx = tid; idx < 2048; idx += 256) {
    int n = idx >> 5, k = idx & 31;
    We1T[n * 32 + k] = (k < 16) ? f2bf(We1[k * 64 + n]) : (unsigned short)0;
  }
  if (tid < 64) {
    float s = bo1[tid];
#pragma unroll 8
    for (int mm = 0; mm < 64; ++mm) s = fmaf(be2[mm], sB[mm * 64 + tid], s);
    cvec[tid] = s;
  }
}

// CSR aggregate fused with epilogue: H = relu(sum/deg + bias + Yr).
// All node features bf16 (rows 128B); f32 accumulation.
__global__ __launch_bounds__(256) void k_agg(
    const unsigned short* __restrict__ Y, const int* __restrict__ rowptr,
    const int* __restrict__ csrc, const float* __restrict__ bias,
    const unsigned short* __restrict__ Yr, unsigned short* __restrict__ H,
    int N) {
  int node = (blockIdx.x * 256 + threadIdx.x) >> 6;
  if (node >= N) return;
  const int lane = threadIdx.x & 63;
  const int c4 = lane & 15, rr = lane >> 4;
  int beg = rowptr[node], end = rowptr[node + 1];
  float a0 = 0.f, a1 = 0.f, a2 = 0.f, a3 = 0.f;
  float b0 = 0.f, b1 = 0.f, b2 = 0.f, b3 = 0.f;
  for (int e = beg; e < end; e += 8) {
    int e0 = e + rr, e1 = e + 4 + rr;
    if (e0 < end) {
      int s = csrc[e0];
      uint2 v = *(const uint2*)(Y + (size_t)s * 64 + c4 * 4);
      a0 += bf2f(v.x & 0xffffu); a1 += bf2f(v.x >> 16);
      a2 += bf2f(v.y & 0xffffu); a3 += bf2f(v.y >> 16);
    }
    if (e1 < end) {
      int s = csrc[e1];
      uint2 v = *(const uint2*)(Y + (size_t)s * 64 + c4 * 4);
      b0 += bf2f(v.x & 0xffffu); b1 += bf2f(v.x >> 16);
      b2 += bf2f(v.y & 0xffffu); b3 += bf2f(v.y >> 16);
    }
  }
  a0 += b0; a1 += b1; a2 += b2; a3 += b3;
#pragma unroll
  for (int msk = 16; msk <= 32; msk <<= 1) {
    a0 += __shfl_xor(a0, msk, 64);
    a1 += __shfl_xor(a1, msk, 64);
    a2 += __shfl_xor(a2, msk, 64);
    a3 += __shfl_xor(a3, msk, 64);
  }
  if (rr == 0) {
    float cdeg = (float)(end - beg);
    if (cdeg < 1.f) cdeg = 1.f;
    float inv = 1.f / cdeg;
    float4 bv = *(const float4*)(bias + c4 * 4);
    uint2 yv = *(const uint2*)(Yr + (size_t)node * 64 + c4 * 4);
    float o0 = fmaxf(a0 * inv + bv.x + bf2f(yv.x & 0xffffu), 0.f);
    float o1 = fmaxf(a1 * inv + bv.y + bf2f(yv.x >> 16), 0.f);
    float o2 = fmaxf(a2 * inv + bv.z + bf2f(yv.y & 0xffffu), 0.f);
    float o3 = fmaxf(a3 * inv + bv.w + bf2f(yv.y >> 16), 0.f);
    uint2 pk;
    pk.x = (unsigned int)f2bf(o0) | ((unsigned int)f2bf(o1) << 16);
    pk.y = (unsigned int)f2bf(o2) | ((unsigned int)f2bf(o3) << 16);
    *(uint2*)(H + (size_t)node * 64 + c4 * 4) = pk;
  }
}

// ---------------------------------------------------------------------------
// MFMA edge pipeline v2 (unchanged from R8). Wave-independent 16-edge tiles.
#define T1_STRIDE 72
#define G_STRIDE 68
__global__ __launch_bounds__(256) void k_edge3(
    const float* __restrict__ eattr, const int* __restrict__ src,
    const int* __restrict__ tgt, const unsigned short* __restrict__ Gb,
    const unsigned short* __restrict__ We1T,
    const unsigned short* __restrict__ W25T,
    const float* __restrict__ cvec, const float* __restrict__ be1,
    const float* __restrict__ Wo2, const float* __restrict__ bo2,
    float* __restrict__ out, int E, int nT, int nWaves) {
  __shared__ unsigned short sT1a[4][16 * T1_STRIDE];
  __shared__ float sGa[4][16 * G_STRIDE];
  const int tid = threadIdx.x;
  const int wid = tid >> 6, lane = tid & 63;
  const int m = lane & 15, q = lane >> 4;
  unsigned short* sT1 = sT1a[wid];
  float* sG = sGa[wid];

  short8 bWe1[4], bW25[4][2];
  float cv[4], wo2v[4], be1v[4];
#pragma unroll
  for (int nt = 0; nt < 4; ++nt) {
    int n = nt * 16 + m;
    bWe1[nt] = *(const short8*)(We1T + n * 32 + q * 8);
    bW25[nt][0] = *(const short8*)(W25T + n * 64 + q * 8);
    bW25[nt][1] = *(const short8*)(W25T + n * 64 + 32 + q * 8);
    cv[nt] = cvec[n];
    wo2v[nt] = Wo2[n];
    be1v[nt] = be1[n];
  }
  const float b_out = bo2[0];
  const short8 zfrag = {};

  int t = blockIdx.x * 4 + wid;
  if (t >= nT) return;
  int il = t * 16 + m; if (il >= E) il = E - 1;
  int my_idx = (lane < 16) ? src[il] : ((lane < 32) ? tgt[il] : 0);

  while (true) {
    const int base = t * 16;
    const int tn = t + nWaves;
    const bool last = (tn >= nT);
    const int tc = last ? t : tn;

    int il_n = tc * 16 + m; if (il_n >= E) il_n = E - 1;
    int idx_n = (lane < 16) ? src[il_n] : ((lane < 32) ? tgt[il_n] : 0);

    // coalesced G row gathers: quad q owns edges q*4..q*4+3
    int rs[4], rt[4];
#pragma unroll
    for (int r = 0; r < 4; ++r) {
      rs[r] = __shfl(my_idx, q * 4 + r, 64);
      rt[r] = __shfl(my_idx, 16 + q * 4 + r, 64);
    }
    uint2 sv[4], tv[4];
#pragma unroll
    for (int r = 0; r < 4; ++r) {
      sv[r] = *(const uint2*)(Gb + (size_t)rs[r] * 64 + m * 4);
      tv[r] = *(const uint2*)(Gb + (size_t)rt[r] * 64 + m * 4);
    }

    // EA A-fragment direct from global
    int er = base + m; if (er >= E) er = E - 1;
    const float* ep = eattr + (size_t)er * 16 + (q & 1) * 8;
    float4 e0 = *(const float4*)ep;
    float4 e1 = *(const float4*)(ep + 4);
    short8 aEA;
    {
      union { short8 s; unsigned int u[4]; } ua;
      ua.u[0] = (unsigned int)f2bf(e0.x) | ((unsigned int)f2bf(e0.y) << 16);
      ua.u[1] = (unsigned int)f2bf(e0.z) | ((unsigned int)f2bf(e0.w) << 16);
      ua.u[2] = (unsigned int)f2bf(e1.x) | ((unsigned int)f2bf(e1.y) << 16);
      ua.u[3] = (unsigned int)f2bf(e1.z) | ((unsigned int)f2bf(e1.w) << 16);
      aEA = (q < 2) ? ua.s : zfrag;
    }

    // MFMA1: t1 = relu(EA @ We1 + be1)
    f32x4 t1[4];
#pragma unroll
    for (int nt = 0; nt < 4; ++nt) {
      f32x4 cinit; cinit[0] = be1v[nt]; cinit[1] = be1v[nt];
      cinit[2] = be1v[nt]; cinit[3] = be1v[nt];
      t1[nt] = __builtin_amdgcn_mfma_f32_16x16x32_bf16(aEA, bWe1[nt], cinit, 0, 0, 0);
    }
#pragma unroll
    for (int nt = 0; nt < 4; ++nt)
#pragma unroll
      for (int r = 0; r < 4; ++r)
        sT1[(q * 4 + r) * T1_STRIDE + nt * 16 + m] = f2bf(fmaxf(t1[nt][r], 0.f));
    short8 aT0 = *(short8*)(sT1 + m * T1_STRIDE + q * 8);
    short8 aT1 = *(short8*)(sT1 + m * T1_STRIDE + 32 + q * 8);

    // Gsum -> sG (f32): lane holds feats 4m..4m+3 of edge q*4+r
#pragma unroll
    for (int r = 0; r < 4; ++r) {
      f32x4 g;
      g[0] = bf2f(sv[r].x & 0xffffu) + bf2f(tv[r].x & 0xffffu);
      g[1] = bf2f(sv[r].x >> 16)     + bf2f(tv[r].x >> 16);
      g[2] = bf2f(sv[r].y & 0xffffu) + bf2f(tv[r].y & 0xffffu);
      g[3] = bf2f(sv[r].y >> 16)     + bf2f(tv[r].y >> 16);
      *(f32x4*)(sG + (q * 4 + r) * G_STRIDE + m * 4) = g;
    }

    // acc init (C layout) + MFMA2
    f32x4 acc[4];
#pragma unroll
    for (int nt = 0; nt < 4; ++nt)
#pragma unroll
      for (int r = 0; r < 4; ++r)
        acc[nt][r] = cv[nt] + sG[(q * 4 + r) * G_STRIDE + nt * 16 + m];
#pragma unroll
    for (int nt = 0; nt < 4; ++nt) {
      acc[nt] = __builtin_amdgcn_mfma_f32_16x16x32_bf16(aT0, bW25[nt][0], acc[nt], 0, 0, 0);
      acc[nt] = __builtin_amdgcn_mfma_f32_16x16x32_bf16(aT1, bW25[nt][1], acc[nt], 0, 0, 0);
    }

    // epilogue
    float p[4];
#pragma unroll
    for (int r = 0; r < 4; ++r) {
      p[r] = fmaxf(acc[0][r], 0.f) * wo2v[0] + fmaxf(acc[1][r], 0.f) * wo2v[1] +
             fmaxf(acc[2][r], 0.f) * wo2v[2] + fmaxf(acc[3][r], 0.f) * wo2v[3];
    }
#pragma unroll
    for (int msk = 1; msk <= 8; msk <<= 1) {
#pragma unroll
      for (int r = 0; r < 4; ++r) p[r] += __shfl_xor(p[r], msk, 64);
    }
    if (m == 0) {
#pragma unroll
      for (int r = 0; r < 4; ++r) {
        int row = base + q * 4 + r;
        if (row < E) out[row] = 1.f / (1.f + __expf(-(p[r] + b_out)));
      }
    }

    if (last) break;
    t = tn; my_idx = idx_n;
  }
}

// ---------------------------------------------------------------------------
extern "C" void kernel_launch(void* const* d_in, const int* in_sizes, int n_in,
                              void* d_out, int out_size, void* d_ws, size_t ws_size,
                              hipStream_t stream) {
  const float* x     = (const float*)d_in[0];
  const unsigned int* eidx = (const unsigned int*)d_in[1];
  const float* eattr = (const float*)d_in[2];
  const float* We1 = (const float*)d_in[3];
  const float* be1 = (const float*)d_in[4];
  const float* We2 = (const float*)d_in[5];
  const float* be2 = (const float*)d_in[6];
  const float* Wl0 = (const float*)d_in[7];
  const float* bl0 = (const float*)d_in[8];
  const float* Wr0 = (const float*)d_in[9];
  const float* Wl1 = (const float*)d_in[10];
  const float* bl1 = (const float*)d_in[11];
  const float* Wr1 = (const float*)d_in[12];
  const float* Wo1 = (const float*)d_in[13];
  const float* bo1 = (const float*)d_in[14];
  const float* Wo2 = (const float*)d_in[15];
  const float* bo2 = (const float*)d_in[16];

  const int N = in_sizes[0] / 128;   // 100000
  const int E = in_sizes[2] / 16;    // 1000000
  const int padN = (N + 2047) & ~2047;
  const int nB = padN / 2048;
  float* out = (float*)d_out;

  char* ws = (char*)d_ws;
  size_t off = 0;
  auto alloc = [&](size_t bytes) {
    char* p = ws + off;
    off += (bytes + 255) & ~(size_t)255;
    return p;
  };
  unsigned int* flag = (unsigned int*)alloc(256);
  int* src    = (int*)alloc((size_t)E * 4);
  int* tgt    = (int*)alloc((size_t)E * 4);
  int* posin  = (int*)alloc((size_t)E * 4);
  int* deg    = (int*)alloc((size_t)padN * 4);
  int* rowptr = (int*)alloc((size_t)(padN + 64) * 4);
  int* bsum   = (int*)alloc(64 * 4);
  int* boff   = (int*)alloc(64 * 4);
  int* csrc   = (int*)alloc((size_t)E * 4);
  unsigned short* Hb = (unsigned short*)alloc((size_t)N * 64 * 2);
  unsigned short* Yl = (unsigned short*)alloc((size_t)N * 64 * 2);
  unsigned short* Yr = (unsigned short*)alloc((size_t)N * 64 * 2);
  unsigned short* Gb = (unsigned short*)alloc((size_t)N * 64 * 2);
  unsigned short* W25T = (unsigned short*)alloc(64 * 64 * 2);
  unsigned short* We1T = (unsigned short*)alloc(64 * 32 * 2);
  unsigned short* Wo1T = (unsigned short*)alloc(64 * 64 * 2);
  unsigned short* WnT0 = (unsigned short*)alloc(128 * 128 * 2);
  unsigned short* WnT1 = (unsigned short*)alloc(128 * 64 * 2);
  float* cvec = (float*)alloc(64 * 4);
  (void)ws_size; (void)n_in; (void)out_size;

  hipMemsetAsync(deg, 0, (size_t)padN * 4, stream);

  k_flag<<<1, 256, 0, stream>>>(eidx, 8192, flag);
  k_decode<<<(E + 255) / 256, 256, 0, stream>>>(eidx, flag, E, src, tgt, posin, deg);
  k_scan1<<<nB, 256, 0, stream>>>(deg, bsum);
  k_scan2<<<1, 64, 0, stream>>>(bsum, boff, nB, rowptr + N);
  k_scan3<<<nB, 256, 0, stream>>>(deg, boff, rowptr);
  k_fill<<<(E + 255) / 256, 256, 0, stream>>>(src, tgt, posin, rowptr, csrc, E);
  k_prep<<<1, 256, 0, stream>>>(We2, Wo1, be2, bo1, We1, W25T, We1T, Wo1T, cvec);
  k_prep2<128><<<64, 256, 0, stream>>>(Wl0, Wr0, WnT0);
  k_prep2<64><<<32, 256, 0, stream>>>(Wl1, Wr1, WnT1);

  const int gB = (N + 63) / 64;
  // Layer 0 (project-then-aggregate: mean is linear) — MFMA, bf16 out
  k_ngemm<128, false, 2><<<gB, 256, 0, stream>>>(x, WnT0, Yl, Yr, N);
  k_agg<<<(N + 3) / 4, 256, 0, stream>>>(Yl, rowptr, csrc, bl0, Yr, Hb, N);

  // Layer 1 — MFMA, bf16 in/out
  k_ngemm<64, true, 2><<<gB, 256, 0, stream>>>(Hb, WnT1, Yl, Yr, N);
  k_agg<<<(N + 3) / 4, 256, 0, stream>>>(Yl, rowptr, csrc, bl1, Yr, Hb, N);

  // G = H2 @ Wo1 — MFMA, bf16 in/out
  k_ngemm<64, true, 1><<<gB, 256, 0, stream>>>(Hb, Wo1T, Gb, nullptr, N);

  // MFMA edge pipeline
  const int nT = (E + 15) / 16;
  const int blocks = 2048;
  k_edge3<<<blocks, 256, 0, stream>>>(eattr, src, tgt, Gb, We1T, W25T, cvec,
                                      be1, Wo2, bo2, out, E, nT, blocks * 4);
}